// Round 16
// baseline (91.837 us; speedup 1.0000x reference)
//
#include <hip/hip_runtime.h>
#include <hip/hip_bf16.h>
#include <cstddef>

// ---------------------------------------------------------------------------
// sparse_attn: transformer encoder block on levels 2 & 3.
// Round 16: split-K (2-way, disjoint partial buffers) for gemm_wo and
// gemm_fc2; following LN kernels sum the halves. Rest = R15 (90.5 anchor).
// Rows 0..2047 = level2 (S=1024), 2048..2559 = level3 (S=256). R=2560.
// ---------------------------------------------------------------------------

typedef __attribute__((ext_vector_type(8))) short s16x8;
typedef __attribute__((ext_vector_type(4))) short s16x4;
typedef __attribute__((ext_vector_type(4))) float f32x4;
typedef __attribute__((ext_vector_type(2))) unsigned int u32x2;
typedef unsigned short ushort_t;
typedef unsigned long long u64;

#define RTOT 2560
#define HALF 655360   // R*256 floats, one partial buffer

__device__ inline unsigned short f2bf(float x) {
    union { __hip_bfloat16 h; unsigned short u; } cv;
    cv.h = __float2bfloat16(x);
    return cv.u;
}
__device__ inline float bf2f(unsigned short u) {
    union { unsigned int i; float f; } cv;
    cv.i = ((unsigned int)u) << 16;
    return cv.f;
}

// ---------------------------------------------------------------------------
// prep (9280 blocks):
//   0..159     : f2/f3 NCHW -> [2560,256] fp32+bf16 (64x64 LDS tile, first)
//   160..4159  : f0/f1 pass-through copy (f32x4)
//   4160..4927 : weights fp32->bf16
//   4928..9279 : mask bits, interleaved words (4 u64 per 256-key chunk)
// ---------------------------------------------------------------------------
__global__ __launch_bounds__(256) void prep(const float* __restrict__ f0,
                                            const float* __restrict__ f1,
                                            float* __restrict__ outp,
                                            const float* __restrict__ wqkv,
                                            const float* __restrict__ wo,
                                            const float* __restrict__ wfc1,
                                            const float* __restrict__ wfc2,
                                            ushort_t* __restrict__ o1,
                                            ushort_t* __restrict__ o2,
                                            ushort_t* __restrict__ o3,
                                            ushort_t* __restrict__ o4,
                                            const float* __restrict__ u2,
                                            const float* __restrict__ u3,
                                            u64* __restrict__ ub,
                                            const float* __restrict__ f2,
                                            const float* __restrict__ f3,
                                            float* __restrict__ srcf,
                                            ushort_t* __restrict__ srcb) {
    __shared__ float tl[64][65];
    int bid = blockIdx.x;
    int t = threadIdx.x;
    if (bid < 160) {
        int b = bid;
        const float* src; int S, rowb, n, ct, ht;
        if (b < 128) {
            n = b >> 6; int rem = b & 63; ct = rem >> 4; ht = rem & 15;
            src = f2; S = 1024; rowb = 0;
        } else {
            int b2 = b - 128;
            n = b2 >> 4; int rem = b2 & 15; ct = rem >> 2; ht = rem & 3;
            src = f3; S = 256; rowb = 2048;
        }
        int c0 = ct * 64, hw0 = ht * 64;
        int i = t >> 6, lane = t & 63;
#pragma unroll
        for (int jj = 0; jj < 16; ++jj) {
            int cl = i * 16 + jj;
            tl[lane][cl] = src[(size_t)(n * 256 + c0 + cl) * S + hw0 + lane];
        }
        __syncthreads();
#pragma unroll
        for (int jj = 0; jj < 16; ++jj) {
            int hl = i * 16 + jj;
            int row = rowb + n * S + hw0 + hl;
            float v = tl[hl][lane];
            srcf[(size_t)row * 256 + c0 + lane] = v;
            srcb[(size_t)row * 256 + c0 + lane] = f2bf(v);
        }
    } else if (bid < 4160) {
        int idx = (bid - 160) * 256 + t;
        f32x4 v = (idx < 819200) ? ((const f32x4*)f0)[idx]
                                 : ((const f32x4*)f1)[idx - 819200];
        ((f32x4*)outp)[idx] = v;
    } else if (bid < 4928) {
        int i = (bid - 4160) * 256 + t;
        const float* src; ushort_t* dst; int li;
        if (i < 49152)       { src = wqkv; dst = o1; li = i; }
        else if (i < 65536)  { src = wo;   dst = o2; li = i - 49152; }
        else if (i < 131072) { src = wfc1; dst = o3; li = i - 65536; }
        else                 { src = wfc2; dst = o4; li = i - 131072; }
        f32x4 v = ((const f32x4*)src)[li];
        s16x4 r;
        r[0] = (short)f2bf(v[0]); r[1] = (short)f2bf(v[1]);
        r[2] = (short)f2bf(v[2]); r[3] = (short)f2bf(v[3]);
        ((s16x4*)dst)[li] = r;
    } else {
        int gw = ((bid - 4928) * 256 + t) >> 6;
        int lane = t & 63;
        const float* p;
        u64* dst;
        if (gw < 16384) {
            int row = gw >> 3, ch = gw & 7;
            p = &u2[(size_t)row * 2048 + ch * 256 + lane * 4];
            dst = &ub[(size_t)gw * 4];
        } else {
            int lw = gw - 16384;
            int row = lw >> 1, ch = lw & 1;
            p = &u3[(size_t)row * 512 + ch * 256 + lane * 4];
            dst = &ub[65536 + (size_t)lw * 4];
        }
        f32x4 v = *(const f32x4*)p;
        u64 b0 = __ballot(v[0] >= 0.1f);
        u64 b1 = __ballot(v[1] >= 0.1f);
        u64 b2 = __ballot(v[2] >= 0.1f);
        u64 b3 = __ballot(v[3] >= 0.1f);
        if (lane < 4) {
            u64 bb = (lane == 0) ? b0 : (lane == 1) ? b1 : (lane == 2) ? b2 : b3;
            dst[lane] = bb;
        }
    }
}

#define ASTR 72

// ---------------------------------------------------------------------------
// bf16 MFMA GEMM, tile 64x64, 256 threads (4 waves). For qkv / fc1.
// EPI: 1=bias+relu, 3=bias then q-scale (n<256). Output bf16.
// ---------------------------------------------------------------------------
template <int EPI>
__global__ __launch_bounds__(256) void gemm64(const ushort_t* __restrict__ A,
                                              const ushort_t* __restrict__ W,
                                              const float* __restrict__ bias,
                                              ushort_t* __restrict__ outb,
                                              int M, int N, int K) {
    __shared__ __align__(16) ushort_t As[2][64 * ASTR];
    __shared__ __align__(16) ushort_t Ws[2][64 * ASTR];

    const int t = threadIdx.x;
    const int w = t >> 6, l = t & 63;
    const int c = l & 15, g = l >> 4;
    const int mh = w >> 1, nh = w & 1;
    const int m0 = blockIdx.y * 64, n0 = blockIdx.x * 64;
    const int srow = t >> 3;
    const int cg8 = (t & 7) * 8;

    const ushort_t* Aip0 = &A[(size_t)(m0 + srow) * K + cg8];
    const ushort_t* Aip1 = &A[(size_t)(m0 + 32 + srow) * K + cg8];
    const ushort_t* Wip0 = &W[(size_t)(n0 + srow) * K + cg8];
    const ushort_t* Wip1 = &W[(size_t)(n0 + 32 + srow) * K + cg8];

    s16x8 ra0 = *(const s16x8*)Aip0;
    s16x8 ra1 = *(const s16x8*)Aip1;
    s16x8 rw0 = *(const s16x8*)Wip0;
    s16x8 rw1 = *(const s16x8*)Wip1;
    *(s16x8*)&As[0][srow * ASTR + cg8] = ra0;
    *(s16x8*)&As[0][(32 + srow) * ASTR + cg8] = ra1;
    *(s16x8*)&Ws[0][srow * ASTR + cg8] = rw0;
    *(s16x8*)&Ws[0][(32 + srow) * ASTR + cg8] = rw1;
    __syncthreads();

    f32x4 acc[2][2] = {{{0.f,0.f,0.f,0.f},{0.f,0.f,0.f,0.f}},
                       {{0.f,0.f,0.f,0.f},{0.f,0.f,0.f,0.f}}};
    const int nsteps = K >> 6;

    for (int ks = 0; ks < nsteps; ++ks) {
        const int b = ks & 1;
        const bool pf = (ks + 1 < nsteps);
        if (pf) {
            int ko = (ks + 1) << 6;
            ra0 = *(const s16x8*)(Aip0 + ko);
            ra1 = *(const s16x8*)(Aip1 + ko);
            rw0 = *(const s16x8*)(Wip0 + ko);
            rw1 = *(const s16x8*)(Wip1 + ko);
        }
#pragma unroll
        for (int sl = 0; sl < 2; ++sl) {
            s16x8 af0 = *(const s16x8*)&As[b][(32 * mh + c) * ASTR + sl * 32 + 8 * g];
            s16x8 af1 = *(const s16x8*)&As[b][(32 * mh + 16 + c) * ASTR + sl * 32 + 8 * g];
            s16x8 wf0 = *(const s16x8*)&Ws[b][(32 * nh + c) * ASTR + sl * 32 + 8 * g];
            s16x8 wf1 = *(const s16x8*)&Ws[b][(32 * nh + 16 + c) * ASTR + sl * 32 + 8 * g];
            acc[0][0] = __builtin_amdgcn_mfma_f32_16x16x32_bf16(af0, wf0, acc[0][0], 0, 0, 0);
            acc[0][1] = __builtin_amdgcn_mfma_f32_16x16x32_bf16(af0, wf1, acc[0][1], 0, 0, 0);
            acc[1][0] = __builtin_amdgcn_mfma_f32_16x16x32_bf16(af1, wf0, acc[1][0], 0, 0, 0);
            acc[1][1] = __builtin_amdgcn_mfma_f32_16x16x32_bf16(af1, wf1, acc[1][1], 0, 0, 0);
        }
        if (pf) {
            int nb = b ^ 1;
            *(s16x8*)&As[nb][srow * ASTR + cg8] = ra0;
            *(s16x8*)&As[nb][(32 + srow) * ASTR + cg8] = ra1;
            *(s16x8*)&Ws[nb][srow * ASTR + cg8] = rw0;
            *(s16x8*)&Ws[nb][(32 + srow) * ASTR + cg8] = rw1;
        }
        __syncthreads();
    }

#pragma unroll
    for (int i = 0; i < 2; ++i)
#pragma unroll
    for (int j = 0; j < 2; ++j) {
        int n = n0 + 32 * nh + 16 * j + c;
        float bv = bias[n];
        float sc = 1.f;
        if (EPI == 3) sc = (n < 256) ? 0.17677669529663687f : 1.f;
#pragma unroll
        for (int r = 0; r < 4; ++r) {
            int m = m0 + 32 * mh + 16 * i + 4 * g + r;
            float v = acc[i][j][r] + bv;
            if (EPI == 1) v = fmaxf(v, 0.f);
            if (EPI == 3) v *= sc;
            outb[(size_t)m * N + n] = f2bf(v);
        }
    }
}

// ---------------------------------------------------------------------------
// bf16 MFMA GEMM, tile 32x32, 128 threads. fc2 with 2-way split-K:
// blockIdx.z selects K-half; writes partial to outf + z*HALF; z==0 adds
// bias + residual. ln2 sums the halves.
// ---------------------------------------------------------------------------
__global__ __launch_bounds__(128) void gemm_fc2(const ushort_t* __restrict__ A,
                                                const ushort_t* __restrict__ W,
                                                const float* __restrict__ bias,
                                                const float* __restrict__ res,
                                                float* __restrict__ outf,
                                                int M, int N, int K) {
    __shared__ __align__(16) ushort_t As[2][32 * ASTR];
    __shared__ __align__(16) ushort_t Ws[2][32 * ASTR];

    const int t = threadIdx.x;
    const int w = t >> 6, l = t & 63;
    const int c = l & 15, g = l >> 4;
    const int m0 = blockIdx.y * 32, n0 = blockIdx.x * 32;
    const int z = blockIdx.z;
    const int koff = z * (K >> 1);
    const int srow = t >> 3;
    const int cg8 = (t & 7) * 8;

    const ushort_t* Aip0 = &A[(size_t)(m0 + srow) * K + koff + cg8];
    const ushort_t* Aip1 = &A[(size_t)(m0 + 16 + srow) * K + koff + cg8];
    const ushort_t* Wip0 = &W[(size_t)(n0 + srow) * K + koff + cg8];
    const ushort_t* Wip1 = &W[(size_t)(n0 + 16 + srow) * K + koff + cg8];

    s16x8 ra0 = *(const s16x8*)Aip0;
    s16x8 ra1 = *(const s16x8*)Aip1;
    s16x8 rw0 = *(const s16x8*)Wip0;
    s16x8 rw1 = *(const s16x8*)Wip1;
    *(s16x8*)&As[0][srow * ASTR + cg8] = ra0;
    *(s16x8*)&As[0][(16 + srow) * ASTR + cg8] = ra1;
    *(s16x8*)&Ws[0][srow * ASTR + cg8] = rw0;
    *(s16x8*)&Ws[0][(16 + srow) * ASTR + cg8] = rw1;
    __syncthreads();

    f32x4 acc[2] = {{0.f, 0.f, 0.f, 0.f}, {0.f, 0.f, 0.f, 0.f}};
    const int nsteps = K >> 7;          // half of K, /64

    for (int ks = 0; ks < nsteps; ++ks) {
        const int b = ks & 1;
        const bool pf = (ks + 1 < nsteps);
        if (pf) {
            int ko = (ks + 1) << 6;
            ra0 = *(const s16x8*)(Aip0 + ko);
            ra1 = *(const s16x8*)(Aip1 + ko);
            rw0 = *(const s16x8*)(Wip0 + ko);
            rw1 = *(const s16x8*)(Wip1 + ko);
        }
#pragma unroll
        for (int kt = 0; kt < 2; ++kt) {
            s16x8 af = *(const s16x8*)&As[b][(16 * w + c) * ASTR + kt * 32 + 8 * g];
            s16x8 wf0 = *(const s16x8*)&Ws[b][c * ASTR + kt * 32 + 8 * g];
            s16x8 wf1 = *(const s16x8*)&Ws[b][(16 + c) * ASTR + kt * 32 + 8 * g];
            acc[0] = __builtin_amdgcn_mfma_f32_16x16x32_bf16(af, wf0, acc[0], 0, 0, 0);
            acc[1] = __builtin_amdgcn_mfma_f32_16x16x32_bf16(af, wf1, acc[1], 0, 0, 0);
        }
        if (pf) {
            int nb = b ^ 1;
            *(s16x8*)&As[nb][srow * ASTR + cg8] = ra0;
            *(s16x8*)&As[nb][(16 + srow) * ASTR + cg8] = ra1;
            *(s16x8*)&Ws[nb][srow * ASTR + cg8] = rw0;
            *(s16x8*)&Ws[nb][(16 + srow) * ASTR + cg8] = rw1;
        }
        __syncthreads();
    }

    float* op = outf + (size_t)z * HALF;
#pragma unroll
    for (int nt = 0; nt < 2; ++nt) {
        int n = n0 + 16 * nt + c;
        float bv = (z == 0) ? bias[n] : 0.f;
#pragma unroll
        for (int r = 0; r < 4; ++r) {
            int m = m0 + 16 * w + 4 * g + r;
            float v = acc[nt][r] + bv;
            if (z == 0) v += res[(size_t)m * N + n];
            op[(size_t)m * N + n] = v;
        }
    }
}

// ---------------------------------------------------------------------------
// Wo GEMM with fused 4-split merge, 2-way split-K (blockIdx.z). Each z does
// K-half (2 k-steps); writes partial to outf + z*HALF; z==0 adds bias+res.
// ---------------------------------------------------------------------------
__global__ __launch_bounds__(128) void gemm_wo(const ushort_t* __restrict__ Opart,
                                               const float2* __restrict__ ml,
                                               const ushort_t* __restrict__ W,
                                               const float* __restrict__ bias,
                                               const float* __restrict__ res,
                                               float* __restrict__ outf) {
    const int K = 256, N = 256;
    __shared__ __align__(16) ushort_t As[2][32 * ASTR];
    __shared__ __align__(16) ushort_t Ws[2][32 * ASTR];

    const int t = threadIdx.x;
    const int w = t >> 6, l = t & 63;
    const int c = l & 15, g = l >> 4;
    const int m0 = blockIdx.y * 32, n0 = blockIdx.x * 32;
    const int z = blockIdx.z;
    const int koff = z * 128;
    const int srow = t >> 3;
    const int cg8 = (t & 7) * 8;

    auto loadA = [&](int row, int kcol) -> s16x8 {
        int head = kcol >> 5;
        float2 a0 = ml[((size_t)0 * RTOT + row) * 8 + head];
        float2 a1 = ml[((size_t)1 * RTOT + row) * 8 + head];
        float2 a2 = ml[((size_t)2 * RTOT + row) * 8 + head];
        float2 a3 = ml[((size_t)3 * RTOT + row) * 8 + head];
        float M = fmaxf(fmaxf(a0.x, a1.x), fmaxf(a2.x, a3.x));
        float w1 = __expf(a0.x - M), w2 = __expf(a1.x - M);
        float w3 = __expf(a2.x - M), w4 = __expf(a3.x - M);
        float inv = 1.f / (w1 * a0.y + w2 * a1.y + w3 * a2.y + w4 * a3.y);
        const size_t str = (size_t)RTOT * 256;
        size_t base = (size_t)row * 256 + kcol;
        s16x8 o1 = *(const s16x8*)&Opart[base];
        s16x8 o2 = *(const s16x8*)&Opart[base + str];
        s16x8 o3 = *(const s16x8*)&Opart[base + 2 * str];
        s16x8 o4 = *(const s16x8*)&Opart[base + 3 * str];
        s16x8 r;
#pragma unroll
        for (int e = 0; e < 8; ++e) {
            float v = w1 * bf2f((ushort_t)o1[e]) + w2 * bf2f((ushort_t)o2[e])
                    + w3 * bf2f((ushort_t)o3[e]) + w4 * bf2f((ushort_t)o4[e]);
            r[e] = (short)f2bf(v * inv);
        }
        return r;
    };

    const ushort_t* Wip0 = &W[(size_t)(n0 + srow) * K + koff + cg8];
    const ushort_t* Wip1 = &W[(size_t)(n0 + 16 + srow) * K + koff + cg8];

    s16x8 ra0 = loadA(m0 + srow, koff + cg8);
    s16x8 ra1 = loadA(m0 + 16 + srow, koff + cg8);
    s16x8 rw0 = *(const s16x8*)Wip0;
    s16x8 rw1 = *(const s16x8*)Wip1;
    *(s16x8*)&As[0][srow * ASTR + cg8] = ra0;
    *(s16x8*)&As[0][(16 + srow) * ASTR + cg8] = ra1;
    *(s16x8*)&Ws[0][srow * ASTR + cg8] = rw0;
    *(s16x8*)&Ws[0][(16 + srow) * ASTR + cg8] = rw1;
    __syncthreads();

    f32x4 acc[2] = {{0.f, 0.f, 0.f, 0.f}, {0.f, 0.f, 0.f, 0.f}};
    const int nsteps = 2;

    for (int ks = 0; ks < nsteps; ++ks) {
        const int b = ks & 1;
        const bool pf = (ks + 1 < nsteps);
        if (pf) {
            int ko = (ks + 1) << 6;
            ra0 = loadA(m0 + srow, koff + ko + cg8);
            ra1 = loadA(m0 + 16 + srow, koff + ko + cg8);
            rw0 = *(const s16x8*)(Wip0 + ko);
            rw1 = *(const s16x8*)(Wip1 + ko);
        }
#pragma unroll
        for (int kt = 0; kt < 2; ++kt) {
            s16x8 af = *(const s16x8*)&As[b][(16 * w + c) * ASTR + kt * 32 + 8 * g];
            s16x8 wf0 = *(const s16x8*)&Ws[b][c * ASTR + kt * 32 + 8 * g];
            s16x8 wf1 = *(const s16x8*)&Ws[b][(16 + c) * ASTR + kt * 32 + 8 * g];
            acc[0] = __builtin_amdgcn_mfma_f32_16x16x32_bf16(af, wf0, acc[0], 0, 0, 0);
            acc[1] = __builtin_amdgcn_mfma_f32_16x16x32_bf16(af, wf1, acc[1], 0, 0, 0);
        }
        if (pf) {
            int nb = b ^ 1;
            *(s16x8*)&As[nb][srow * ASTR + cg8] = ra0;
            *(s16x8*)&As[nb][(16 + srow) * ASTR + cg8] = ra1;
            *(s16x8*)&Ws[nb][srow * ASTR + cg8] = rw0;
            *(s16x8*)&Ws[nb][(16 + srow) * ASTR + cg8] = rw1;
        }
        __syncthreads();
    }

    float* op = outf + (size_t)z * HALF;
#pragma unroll
    for (int nt = 0; nt < 2; ++nt) {
        int n = n0 + 16 * nt + c;
        float bv = (z == 0) ? bias[n] : 0.f;
#pragma unroll
        for (int r = 0; r < 4; ++r) {
            int m = m0 + 16 * w + 4 * g + r;
            float v = acc[nt][r] + bv;
            if (z == 0) v += res[(size_t)m * 256 + n];
            op[(size_t)m * 256 + n] = v;
        }
    }
}

// ---------------------------------------------------------------------------
// Split-KV MFMA flash attention (R13/R15 form). Reg-direct Q; double-buffered
// K/V, ONE barrier per tile. LDS 27.9 KB -> 5 blocks/CU.
// lvl2: blocks 0..1023  = qt(32) x h(8) x split(4), tps=8
// lvl3: blocks 1024..1279 = qt(8) x h(8) x split(4), tps=2
// ---------------------------------------------------------------------------
#define KS 40
#define VS 66
#define PS 72
#define OS 68

__global__ __launch_bounds__(256) void flash_split(const ushort_t* __restrict__ qkvb,
                                                   const u64* __restrict__ ubits,
                                                   ushort_t* __restrict__ Opart,
                                                   float2* __restrict__ ml) {
    __shared__ __align__(16) ushort_t ks[2][64 * KS];
    __shared__ __align__(16) ushort_t vts[2][32 * VS];
    __shared__ __align__(16) char pso[64 * PS * 2];
    ushort_t* ps = (ushort_t*)pso;
    float* os = (float*)pso;

    const int bx = blockIdx.x;
    int qt, h, split, L, sshift, rowbase;
    const u64* ub;
    if (bx < 1024) {
        qt = bx & 31; h = (bx >> 5) & 7; split = bx >> 8;
        L = 2048; sshift = 10; rowbase = 0; ub = ubits;
    } else {
        int lo = bx - 1024;
        qt = lo & 7; h = (lo >> 3) & 7; split = lo >> 6;
        L = 512; sshift = 8; rowbase = 2048; ub = ubits + 65536;
    }
    const int tps = (L >> 6) >> 2;
    const int ts0 = split * tps;
    const int nch = L >> 8;

    const int t = threadIdx.x;
    const int w = t >> 6;
    const int l = t & 63;
    const int c = l & 15;
    const int g = l >> 4;
    const int smask = (1 << sshift) - 1;

    const int srow = t >> 2;
    const int sc8 = (t & 3) * 8;
    const int q0g = rowbase + qt * 64;

    const int ql = qt * 64 + 16 * w + c;
    const s16x8 qf = *(const s16x8*)&qkvb[(size_t)(rowbase + ql) * 768 + h * 32 + 8 * g];
    const int qp = ql & smask, qfr = ql >> sshift;
    const u64* ubq = &ub[(size_t)ql * nch * 4];

    s16x8 kreg, vreg;
    {
        size_t base = (size_t)(rowbase + ts0 * 64 + srow) * 768 + h * 32 + sc8;
        s16x8 k0r = *(const s16x8*)&qkvb[base + 256];
        s16x8 v0r = *(const s16x8*)&qkvb[base + 512];
        *(s16x8*)&ks[0][srow * KS + sc8] = k0r;
#pragma unroll
        for (int i = 0; i < 8; ++i)
            vts[0][(sc8 + i) * VS + srow] = (ushort_t)v0r[i];
        if (tps > 1) {
            kreg = *(const s16x8*)&qkvb[base + 64 * 768 + 256];
            vreg = *(const s16x8*)&qkvb[base + 64 * 768 + 512];
        }
    }
    __syncthreads();

    f32x4 oacc0 = {0.f, 0.f, 0.f, 0.f};
    f32x4 oacc1 = {0.f, 0.f, 0.f, 0.f};
    float mold = -3e38f, lrun = 0.f;
    const f32x4 zc = {0.f, 0.f, 0.f, 0.f};

    u64 wr0 = 0, wr1 = 0, wr2 = 0, wr3 = 0;
    int cur = 0;
    for (int kt = 0; kt < tps; ++kt) {
        const int nxt = cur ^ 1;
        const int gt = ts0 + kt;
        const int k0 = gt << 6;

        if (kt + 1 < tps) {
            *(s16x8*)&ks[nxt][srow * KS + sc8] = kreg;
#pragma unroll
            for (int i = 0; i < 8; ++i)
                vts[nxt][(sc8 + i) * VS + srow] = (ushort_t)vreg[i];
        }
        if (kt + 2 < tps) {
            size_t base = (size_t)(rowbase + (gt + 2) * 64 + srow) * 768 + h * 32 + sc8;
            kreg = *(const s16x8*)&qkvb[base + 256];
            vreg = *(const s16x8*)&qkvb[base + 512];
        }

        if ((gt & 3) == 0 || kt == 0) {
            const u64* bp = &ubq[(size_t)(gt >> 2) * 4];
            wr0 = bp[0]; wr1 = bp[1]; wr2 = bp[2]; wr3 = bp[3];
        }
        const unsigned shb = 16 * (gt & 3);

        f32x4 sacc[4];
#pragma unroll
        for (int nt = 0; nt < 4; ++nt) {
            s16x8 kf = *(const s16x8*)&ks[cur][(16 * nt + c) * KS + 8 * g];
            sacc[nt] = __builtin_amdgcn_mfma_f32_16x16x32_bf16(kf, qf, zc, 0, 0, 0);
        }

        float sv[4][4];
        float m = -3e38f;
#pragma unroll
        for (int nt = 0; nt < 4; ++nt) {
            unsigned sh = shb + 4 * nt + g;
#pragma unroll
            for (int r = 0; r < 4; ++r) {
                u64 wrd = (r == 0) ? wr0 : (r == 1) ? wr1 : (r == 2) ? wr2 : wr3;
                int kg = k0 + 16 * nt + 4 * g + r;
                float s = sacc[nt][r]
                        + ((wrd >> sh) & 1 ? 1.f : 0.f)
                        + ((kg & smask) == qp ? 1.f : 0.f)
                        + ((kg >> sshift) == qfr ? 1.f : 0.f);
                sv[nt][r] = s;
                m = fmaxf(m, s);
            }
        }
        m = fmaxf(m, __shfl_xor(m, 16));
        m = fmaxf(m, __shfl_xor(m, 32));
        float newm = fmaxf(mold, m);
        float fac = __expf(mold - newm);
        mold = newm;

        float sum = 0.f;
#pragma unroll
        for (int nt = 0; nt < 4; ++nt) {
            float p0 = __expf(sv[nt][0] - newm);
            float p1 = __expf(sv[nt][1] - newm);
            float p2 = __expf(sv[nt][2] - newm);
            float p3 = __expf(sv[nt][3] - newm);
            sum += (p0 + p1) + (p2 + p3);
            u32x2 pk;
            pk[0] = ((unsigned)f2bf(p1) << 16) | f2bf(p0);
            pk[1] = ((unsigned)f2bf(p3) << 16) | f2bf(p2);
            *(u32x2*)&ps[(16 * w + c) * PS + 16 * nt + 4 * g] = pk;
        }
        sum += __shfl_xor(sum, 16);
        sum += __shfl_xor(sum, 32);
        lrun = lrun * fac + sum;
        oacc0 *= fac;
        oacc1 *= fac;

#pragma unroll
        for (int kc = 0; kc < 2; ++kc) {
            s16x8 pfr = *(const s16x8*)&ps[(16 * w + c) * PS + 32 * kc + 8 * g];
            s16x8 vf0 = *(const s16x8*)&vts[cur][c * VS + 32 * kc + 8 * g];
            s16x8 vf1 = *(const s16x8*)&vts[cur][(16 + c) * VS + 32 * kc + 8 * g];
            oacc0 = __builtin_amdgcn_mfma_f32_16x16x32_bf16(vf0, pfr, oacc0, 0, 0, 0);
            oacc1 = __builtin_amdgcn_mfma_f32_16x16x32_bf16(vf1, pfr, oacc1, 0, 0, 0);
        }

        __syncthreads();
        cur = nxt;
    }

    if (g == 0) {
        int q = q0g + 16 * w + c;
        ml[((size_t)split * RTOT + q) * 8 + h] = make_float2(mold, lrun);
    }

#pragma unroll
    for (int r = 0; r < 4; ++r) {
        os[(4 * g + r) * OS + 16 * w + c] = oacc0[r];
        os[(16 + 4 * g + r) * OS + 16 * w + c] = oacc1[r];
    }
    __syncthreads();
    {
        int r = t >> 2, d0 = (t & 3) * 8;
        s16x8 pk;
#pragma unroll
        for (int i = 0; i < 8; ++i) pk[i] = (short)f2bf(os[(d0 + i) * OS + r]);
        *(s16x8*)&Opart[((size_t)split * RTOT + q0g + r) * 256 + h * 32 + d0] = pk;
    }
}

// LayerNorm over C=256; input = sum of two split-K partials. f32 + bf16 out.
__global__ __launch_bounds__(256) void ln1_kernel(const float* __restrict__ in,
                                                  const float* __restrict__ g,
                                                  const float* __restrict__ b,
                                                  float* __restrict__ outf,
                                                  ushort_t* __restrict__ outb) {
    __shared__ float red[256];
    int row = blockIdx.x, t = threadIdx.x;
    size_t idx = (size_t)row * 256 + t;
    float v = in[idx] + in[idx + HALF];
    red[t] = v;
    __syncthreads();
    for (int s = 128; s > 0; s >>= 1) {
        if (t < s) red[t] += red[t + s];
        __syncthreads();
    }
    float mean = red[0] * (1.f / 256.f);
    __syncthreads();
    float d = v - mean;
    red[t] = d * d;
    __syncthreads();
    for (int s = 128; s > 0; s >>= 1) {
        if (t < s) red[t] += red[t + s];
        __syncthreads();
    }
    float var = red[0] * (1.f / 256.f);
    float r = d * rsqrtf(var + 1e-5f) * g[t] + b[t];
    outf[idx] = r;
    outb[idx] = f2bf(r);
}

// LayerNorm (sum of two partials) + NCHW scatter
__global__ __launch_bounds__(256) void ln2_out(const float* __restrict__ in,
                                               const float* __restrict__ g,
                                               const float* __restrict__ b,
                                               float* __restrict__ out2,
                                               float* __restrict__ out3) {
    __shared__ float red[256];
    int row = blockIdx.x, t = threadIdx.x;
    size_t idx = (size_t)row * 256 + t;
    float v = in[idx] + in[idx + HALF];
    red[t] = v;
    __syncthreads();
    for (int s = 128; s > 0; s >>= 1) {
        if (t < s) red[t] += red[t + s];
        __syncthreads();
    }
    float mean = red[0] * (1.f / 256.f);
    __syncthreads();
    float d = v - mean;
    red[t] = d * d;
    __syncthreads();
    for (int s = 128; s > 0; s >>= 1) {
        if (t < s) red[t] += red[t + s];
        __syncthreads();
    }
    float var = red[0] * (1.f / 256.f);
    float r = d * rsqrtf(var + 1e-5f) * g[t] + b[t];
    if (row < 2048) {
        int n = row >> 10, hw = row & 1023;
        out2[((size_t)(n * 256 + t) << 10) + hw] = r;
    } else {
        int rl = row - 2048;
        int n = rl >> 8, hw = rl & 255;
        out3[((size_t)(n * 256 + t) << 8) + hw] = r;
    }
}

// ---------------------------------------------------------------------------

extern "C" void kernel_launch(void* const* d_in, const int* in_sizes, int n_in,
                              void* d_out, int out_size, void* d_ws, size_t ws_size,
                              hipStream_t stream) {
    const float* f0 = (const float*)d_in[0];
    const float* f1 = (const float*)d_in[1];
    const float* f2 = (const float*)d_in[2];
    const float* f3 = (const float*)d_in[3];
    const float* u2 = (const float*)d_in[4];
    const float* u3 = (const float*)d_in[5];
    const float* Wqkv = (const float*)d_in[6];
    const float* bqkv = (const float*)d_in[7];
    const float* Wo   = (const float*)d_in[8];
    const float* bo   = (const float*)d_in[9];
    const float* g1   = (const float*)d_in[10];
    const float* b1   = (const float*)d_in[11];
    const float* Wfc1 = (const float*)d_in[12];
    const float* bfc1 = (const float*)d_in[13];
    const float* Wfc2 = (const float*)d_in[14];
    const float* bfc2 = (const float*)d_in[15];
    const float* g2   = (const float*)d_in[16];
    const float* b2   = (const float*)d_in[17];

    float* out = (float*)d_out;
    float* ws = (float*)d_ws;

    // bf16 weights
    ushort_t* wqkv = (ushort_t*)ws;             // 196608 us
    ushort_t* wo   = (ushort_t*)(ws + 98304);   // 65536 us
    ushort_t* wfc1 = (ushort_t*)(ws + 131072);  // 262144 us
    ushort_t* wfc2 = (ushort_t*)(ws + 262144);  // 262144 us

    // scratch (floats)
    float* sc = ws + 393216;
    float*    src_f32 = sc;                          // 655360
    ushort_t* qkvb    = (ushort_t*)(sc + 655360);    // 2560*768 us -> 1638400
    ushort_t* src_bf  = (ushort_t*)(sc + 1638400);   // -> 1966080
    float*    t1      = sc + 1966080;                // 2*HALF -> 3276800
    float*    x_f32   = sc + 3276800;                // 655360 (ubits alias)
    u64*      ubits   = (u64*)x_f32;                 // 69632 u64
    ushort_t* x_bf    = (ushort_t*)(sc + 3932160);   // -> 4259840
    float2*   ml      = (float2*)(sc + 4259840);     // 4*2560*8 f2 -> 4423680
    ushort_t* Opart   = (ushort_t*)(sc + 4423680);   // 4*2560*256 us -> 5734400
    ushort_t* h_bf    = Opart;                       // alias post-wo
    float*    t2      = sc + 5734400;                // 2*HALF -> 7045120

    prep<<<9280, 256, 0, stream>>>(f0, f1, out,
                                   Wqkv, Wo, Wfc1, Wfc2, wqkv, wo, wfc1, wfc2,
                                   u2, u3, ubits, f2, f3, src_f32, src_bf);

    gemm64<3><<<dim3(12, 40), 256, 0, stream>>>(
        src_bf, wqkv, bqkv, qkvb, RTOT, 768, 256);
    flash_split<<<1280, 256, 0, stream>>>(qkvb, ubits, Opart, ml);
    gemm_wo<<<dim3(8, 80, 2), 128, 0, stream>>>(Opart, ml, wo, bo, src_f32, t1);
    ln1_kernel<<<2560, 256, 0, stream>>>(t1, g1, b1, x_f32, x_bf);
    gemm64<1><<<dim3(16, 40), 256, 0, stream>>>(
        x_bf, wfc1, bfc1, h_bf, RTOT, 1024, 256);
    gemm_fc2<<<dim3(8, 80, 2), 128, 0, stream>>>(
        h_bf, wfc2, bfc2, x_f32, t2, RTOT, 256, 1024);
    ln2_out<<<2560, 256, 0, stream>>>(t2, g2, b2, out + 4096000, out + 4620288);
}

// Round 17
// 88.130 us; speedup vs baseline: 1.0421x; 1.0421x over previous
//
#include <hip/hip_runtime.h>
#include <hip/hip_bf16.h>
#include <cstddef>

// ---------------------------------------------------------------------------
// sparse_attn: transformer encoder block on levels 2 & 3.
// Round 17: R15 base (90.5 anchor). Full mask (rand+pos+frame) folded into
// TWO precomputed bitplanes (values 0..3); flash inner loop has zero index
// math. s_setprio(1) around flash MFMA clusters.
// Rows 0..2047 = level2 (S=1024), 2048..2559 = level3 (S=256). R=2560.
// ---------------------------------------------------------------------------

typedef __attribute__((ext_vector_type(8))) short s16x8;
typedef __attribute__((ext_vector_type(4))) short s16x4;
typedef __attribute__((ext_vector_type(4))) float f32x4;
typedef __attribute__((ext_vector_type(2))) unsigned int u32x2;
typedef unsigned short ushort_t;
typedef unsigned long long u64;

#define RTOT 2560
#define HIPL 69632   // u64 offset of the hi bitplane

__device__ inline unsigned short f2bf(float x) {
    union { __hip_bfloat16 h; unsigned short u; } cv;
    cv.h = __float2bfloat16(x);
    return cv.u;
}
__device__ inline float bf2f(unsigned short u) {
    union { unsigned int i; float f; } cv;
    cv.i = ((unsigned int)u) << 16;
    return cv.f;
}

// ---------------------------------------------------------------------------
// prep (9280 blocks):
//   0..159     : f2/f3 NCHW -> [2560,256] fp32+bf16 (64x64 LDS tile, first)
//   160..4159  : f0/f1 pass-through copy (f32x4)
//   4160..4927 : weights fp32->bf16
//   4928..9279 : mask VALUE planes: val = rand + pos + frame (0..3);
//                lo bits at ub[..], hi bits at ub[HIPL + ..]; interleaved
//                words (4 u64 per 256-key chunk per plane).
// ---------------------------------------------------------------------------
__global__ __launch_bounds__(256) void prep(const float* __restrict__ f0,
                                            const float* __restrict__ f1,
                                            float* __restrict__ outp,
                                            const float* __restrict__ wqkv,
                                            const float* __restrict__ wo,
                                            const float* __restrict__ wfc1,
                                            const float* __restrict__ wfc2,
                                            ushort_t* __restrict__ o1,
                                            ushort_t* __restrict__ o2,
                                            ushort_t* __restrict__ o3,
                                            ushort_t* __restrict__ o4,
                                            const float* __restrict__ u2,
                                            const float* __restrict__ u3,
                                            u64* __restrict__ ub,
                                            const float* __restrict__ f2,
                                            const float* __restrict__ f3,
                                            float* __restrict__ srcf,
                                            ushort_t* __restrict__ srcb) {
    __shared__ float tl[64][65];
    int bid = blockIdx.x;
    int t = threadIdx.x;
    if (bid < 160) {
        int b = bid;
        const float* src; int S, rowb, n, ct, ht;
        if (b < 128) {
            n = b >> 6; int rem = b & 63; ct = rem >> 4; ht = rem & 15;
            src = f2; S = 1024; rowb = 0;
        } else {
            int b2 = b - 128;
            n = b2 >> 4; int rem = b2 & 15; ct = rem >> 2; ht = rem & 3;
            src = f3; S = 256; rowb = 2048;
        }
        int c0 = ct * 64, hw0 = ht * 64;
        int i = t >> 6, lane = t & 63;
#pragma unroll
        for (int jj = 0; jj < 16; ++jj) {
            int cl = i * 16 + jj;
            tl[lane][cl] = src[(size_t)(n * 256 + c0 + cl) * S + hw0 + lane];
        }
        __syncthreads();
#pragma unroll
        for (int jj = 0; jj < 16; ++jj) {
            int hl = i * 16 + jj;
            int row = rowb + n * S + hw0 + hl;
            float v = tl[hl][lane];
            srcf[(size_t)row * 256 + c0 + lane] = v;
            srcb[(size_t)row * 256 + c0 + lane] = f2bf(v);
        }
    } else if (bid < 4160) {
        int idx = (bid - 160) * 256 + t;
        f32x4 v = (idx < 819200) ? ((const f32x4*)f0)[idx]
                                 : ((const f32x4*)f1)[idx - 819200];
        ((f32x4*)outp)[idx] = v;
    } else if (bid < 4928) {
        int i = (bid - 4160) * 256 + t;
        const float* src; ushort_t* dst; int li;
        if (i < 49152)       { src = wqkv; dst = o1; li = i; }
        else if (i < 65536)  { src = wo;   dst = o2; li = i - 49152; }
        else if (i < 131072) { src = wfc1; dst = o3; li = i - 65536; }
        else                 { src = wfc2; dst = o4; li = i - 131072; }
        f32x4 v = ((const f32x4*)src)[li];
        s16x4 r;
        r[0] = (short)f2bf(v[0]); r[1] = (short)f2bf(v[1]);
        r[2] = (short)f2bf(v[2]); r[3] = (short)f2bf(v[3]);
        ((s16x4*)dst)[li] = r;
    } else {
        int gw = ((bid - 4928) * 256 + t) >> 6;   // chunk 0..17407
        int lane = t & 63;
        const float* p;
        u64* dstLo;
        int q, kb, smask, sshift;
        if (gw < 16384) {
            int row = gw >> 3, ch = gw & 7;
            p = &u2[(size_t)row * 2048 + ch * 256 + lane * 4];
            dstLo = &ub[(size_t)gw * 4];
            q = row; kb = ch * 256 + lane * 4; smask = 1023; sshift = 10;
        } else {
            int lw = gw - 16384;
            int row = lw >> 1, ch = lw & 1;
            p = &u3[(size_t)row * 512 + ch * 256 + lane * 4];
            dstLo = &ub[65536 + (size_t)lw * 4];
            q = row; kb = ch * 256 + lane * 4; smask = 255; sshift = 8;
        }
        u64* dstHi = dstLo + HIPL;
        f32x4 v = *(const f32x4*)p;
        int qp = q & smask, qf = q >> sshift;
        u64 bl[4], bh[4];
#pragma unroll
        for (int j = 0; j < 4; ++j) {
            int k = kb + j;
            int val = (v[j] >= 0.1f ? 1 : 0)
                    + ((k & smask) == qp ? 1 : 0)
                    + ((k >> sshift) == qf ? 1 : 0);
            bl[j] = __ballot((val & 1) != 0);
            bh[j] = __ballot((val & 2) != 0);
        }
        if (lane < 4) {
            u64 x = (lane == 0) ? bl[0] : (lane == 1) ? bl[1]
                  : (lane == 2) ? bl[2] : bl[3];
            dstLo[lane] = x;
        } else if (lane < 8) {
            int j = lane - 4;
            u64 x = (j == 0) ? bh[0] : (j == 1) ? bh[1]
                  : (j == 2) ? bh[2] : bh[3];
            dstHi[j] = x;
        }
    }
}

#define ASTR 72

// ---------------------------------------------------------------------------
// bf16 MFMA GEMM, tile 64x64, 256 threads (4 waves). For qkv / fc1.
// EPI: 1=bias+relu, 3=bias then q-scale (n<256). Output bf16.
// ---------------------------------------------------------------------------
template <int EPI>
__global__ __launch_bounds__(256) void gemm64(const ushort_t* __restrict__ A,
                                              const ushort_t* __restrict__ W,
                                              const float* __restrict__ bias,
                                              ushort_t* __restrict__ outb,
                                              int M, int N, int K) {
    __shared__ __align__(16) ushort_t As[2][64 * ASTR];
    __shared__ __align__(16) ushort_t Ws[2][64 * ASTR];

    const int t = threadIdx.x;
    const int w = t >> 6, l = t & 63;
    const int c = l & 15, g = l >> 4;
    const int mh = w >> 1, nh = w & 1;
    const int m0 = blockIdx.y * 64, n0 = blockIdx.x * 64;
    const int srow = t >> 3;
    const int cg8 = (t & 7) * 8;

    const ushort_t* Aip0 = &A[(size_t)(m0 + srow) * K + cg8];
    const ushort_t* Aip1 = &A[(size_t)(m0 + 32 + srow) * K + cg8];
    const ushort_t* Wip0 = &W[(size_t)(n0 + srow) * K + cg8];
    const ushort_t* Wip1 = &W[(size_t)(n0 + 32 + srow) * K + cg8];

    s16x8 ra0 = *(const s16x8*)Aip0;
    s16x8 ra1 = *(const s16x8*)Aip1;
    s16x8 rw0 = *(const s16x8*)Wip0;
    s16x8 rw1 = *(const s16x8*)Wip1;
    *(s16x8*)&As[0][srow * ASTR + cg8] = ra0;
    *(s16x8*)&As[0][(32 + srow) * ASTR + cg8] = ra1;
    *(s16x8*)&Ws[0][srow * ASTR + cg8] = rw0;
    *(s16x8*)&Ws[0][(32 + srow) * ASTR + cg8] = rw1;
    __syncthreads();

    f32x4 acc[2][2] = {{{0.f,0.f,0.f,0.f},{0.f,0.f,0.f,0.f}},
                       {{0.f,0.f,0.f,0.f},{0.f,0.f,0.f,0.f}}};
    const int nsteps = K >> 6;

    for (int ks = 0; ks < nsteps; ++ks) {
        const int b = ks & 1;
        const bool pf = (ks + 1 < nsteps);
        if (pf) {
            int ko = (ks + 1) << 6;
            ra0 = *(const s16x8*)(Aip0 + ko);
            ra1 = *(const s16x8*)(Aip1 + ko);
            rw0 = *(const s16x8*)(Wip0 + ko);
            rw1 = *(const s16x8*)(Wip1 + ko);
        }
#pragma unroll
        for (int sl = 0; sl < 2; ++sl) {
            s16x8 af0 = *(const s16x8*)&As[b][(32 * mh + c) * ASTR + sl * 32 + 8 * g];
            s16x8 af1 = *(const s16x8*)&As[b][(32 * mh + 16 + c) * ASTR + sl * 32 + 8 * g];
            s16x8 wf0 = *(const s16x8*)&Ws[b][(32 * nh + c) * ASTR + sl * 32 + 8 * g];
            s16x8 wf1 = *(const s16x8*)&Ws[b][(32 * nh + 16 + c) * ASTR + sl * 32 + 8 * g];
            acc[0][0] = __builtin_amdgcn_mfma_f32_16x16x32_bf16(af0, wf0, acc[0][0], 0, 0, 0);
            acc[0][1] = __builtin_amdgcn_mfma_f32_16x16x32_bf16(af0, wf1, acc[0][1], 0, 0, 0);
            acc[1][0] = __builtin_amdgcn_mfma_f32_16x16x32_bf16(af1, wf0, acc[1][0], 0, 0, 0);
            acc[1][1] = __builtin_amdgcn_mfma_f32_16x16x32_bf16(af1, wf1, acc[1][1], 0, 0, 0);
        }
        if (pf) {
            int nb = b ^ 1;
            *(s16x8*)&As[nb][srow * ASTR + cg8] = ra0;
            *(s16x8*)&As[nb][(32 + srow) * ASTR + cg8] = ra1;
            *(s16x8*)&Ws[nb][srow * ASTR + cg8] = rw0;
            *(s16x8*)&Ws[nb][(32 + srow) * ASTR + cg8] = rw1;
        }
        __syncthreads();
    }

#pragma unroll
    for (int i = 0; i < 2; ++i)
#pragma unroll
    for (int j = 0; j < 2; ++j) {
        int n = n0 + 32 * nh + 16 * j + c;
        float bv = bias[n];
        float sc = 1.f;
        if (EPI == 3) sc = (n < 256) ? 0.17677669529663687f : 1.f;
#pragma unroll
        for (int r = 0; r < 4; ++r) {
            int m = m0 + 32 * mh + 16 * i + 4 * g + r;
            float v = acc[i][j][r] + bv;
            if (EPI == 1) v = fmaxf(v, 0.f);
            if (EPI == 3) v *= sc;
            outb[(size_t)m * N + n] = f2bf(v);
        }
    }
}

// ---------------------------------------------------------------------------
// bf16 MFMA GEMM, tile 32x32, 128 threads (2 waves). fc2: K=1024, res, f32 out.
// ---------------------------------------------------------------------------
__global__ __launch_bounds__(128) void gemm_fc2(const ushort_t* __restrict__ A,
                                                const ushort_t* __restrict__ W,
                                                const float* __restrict__ bias,
                                                const float* __restrict__ res,
                                                float* __restrict__ outf,
                                                int M, int N, int K) {
    __shared__ __align__(16) ushort_t As[2][32 * ASTR];
    __shared__ __align__(16) ushort_t Ws[2][32 * ASTR];

    const int t = threadIdx.x;
    const int w = t >> 6, l = t & 63;
    const int c = l & 15, g = l >> 4;
    const int m0 = blockIdx.y * 32, n0 = blockIdx.x * 32;
    const int srow = t >> 3;
    const int cg8 = (t & 7) * 8;

    const ushort_t* Aip0 = &A[(size_t)(m0 + srow) * K + cg8];
    const ushort_t* Aip1 = &A[(size_t)(m0 + 16 + srow) * K + cg8];
    const ushort_t* Wip0 = &W[(size_t)(n0 + srow) * K + cg8];
    const ushort_t* Wip1 = &W[(size_t)(n0 + 16 + srow) * K + cg8];

    s16x8 ra0 = *(const s16x8*)Aip0;
    s16x8 ra1 = *(const s16x8*)Aip1;
    s16x8 rw0 = *(const s16x8*)Wip0;
    s16x8 rw1 = *(const s16x8*)Wip1;
    *(s16x8*)&As[0][srow * ASTR + cg8] = ra0;
    *(s16x8*)&As[0][(16 + srow) * ASTR + cg8] = ra1;
    *(s16x8*)&Ws[0][srow * ASTR + cg8] = rw0;
    *(s16x8*)&Ws[0][(16 + srow) * ASTR + cg8] = rw1;
    __syncthreads();

    f32x4 acc[2] = {{0.f, 0.f, 0.f, 0.f}, {0.f, 0.f, 0.f, 0.f}};
    const int nsteps = K >> 6;

    for (int ks = 0; ks < nsteps; ++ks) {
        const int b = ks & 1;
        const bool pf = (ks + 1 < nsteps);
        if (pf) {
            int ko = (ks + 1) << 6;
            ra0 = *(const s16x8*)(Aip0 + ko);
            ra1 = *(const s16x8*)(Aip1 + ko);
            rw0 = *(const s16x8*)(Wip0 + ko);
            rw1 = *(const s16x8*)(Wip1 + ko);
        }
#pragma unroll
        for (int kt = 0; kt < 2; ++kt) {
            s16x8 af = *(const s16x8*)&As[b][(16 * w + c) * ASTR + kt * 32 + 8 * g];
            s16x8 wf0 = *(const s16x8*)&Ws[b][c * ASTR + kt * 32 + 8 * g];
            s16x8 wf1 = *(const s16x8*)&Ws[b][(16 + c) * ASTR + kt * 32 + 8 * g];
            acc[0] = __builtin_amdgcn_mfma_f32_16x16x32_bf16(af, wf0, acc[0], 0, 0, 0);
            acc[1] = __builtin_amdgcn_mfma_f32_16x16x32_bf16(af, wf1, acc[1], 0, 0, 0);
        }
        if (pf) {
            int nb = b ^ 1;
            *(s16x8*)&As[nb][srow * ASTR + cg8] = ra0;
            *(s16x8*)&As[nb][(16 + srow) * ASTR + cg8] = ra1;
            *(s16x8*)&Ws[nb][srow * ASTR + cg8] = rw0;
            *(s16x8*)&Ws[nb][(16 + srow) * ASTR + cg8] = rw1;
        }
        __syncthreads();
    }

#pragma unroll
    for (int nt = 0; nt < 2; ++nt) {
        int n = n0 + 16 * nt + c;
        float bv = bias[n];
#pragma unroll
        for (int r = 0; r < 4; ++r) {
            int m = m0 + 16 * w + 4 * g + r;
            float v = acc[nt][r] + bv + res[(size_t)m * N + n];
            outf[(size_t)m * N + n] = v;
        }
    }
}

// ---------------------------------------------------------------------------
// Wo GEMM with fused 4-split merge in the A-staging. Tile 32x32, 128 threads.
// ---------------------------------------------------------------------------
__global__ __launch_bounds__(128) void gemm_wo(const ushort_t* __restrict__ Opart,
                                               const float2* __restrict__ ml,
                                               const ushort_t* __restrict__ W,
                                               const float* __restrict__ bias,
                                               const float* __restrict__ res,
                                               float* __restrict__ outf) {
    const int K = 256, N = 256;
    __shared__ __align__(16) ushort_t As[2][32 * ASTR];
    __shared__ __align__(16) ushort_t Ws[2][32 * ASTR];

    const int t = threadIdx.x;
    const int w = t >> 6, l = t & 63;
    const int c = l & 15, g = l >> 4;
    const int m0 = blockIdx.y * 32, n0 = blockIdx.x * 32;
    const int srow = t >> 3;
    const int cg8 = (t & 7) * 8;

    auto loadA = [&](int row, int kcol) -> s16x8 {
        int head = kcol >> 5;
        float2 a0 = ml[((size_t)0 * RTOT + row) * 8 + head];
        float2 a1 = ml[((size_t)1 * RTOT + row) * 8 + head];
        float2 a2 = ml[((size_t)2 * RTOT + row) * 8 + head];
        float2 a3 = ml[((size_t)3 * RTOT + row) * 8 + head];
        float M = fmaxf(fmaxf(a0.x, a1.x), fmaxf(a2.x, a3.x));
        float w1 = __expf(a0.x - M), w2 = __expf(a1.x - M);
        float w3 = __expf(a2.x - M), w4 = __expf(a3.x - M);
        float inv = 1.f / (w1 * a0.y + w2 * a1.y + w3 * a2.y + w4 * a3.y);
        const size_t str = (size_t)RTOT * 256;
        size_t base = (size_t)row * 256 + kcol;
        s16x8 o1 = *(const s16x8*)&Opart[base];
        s16x8 o2 = *(const s16x8*)&Opart[base + str];
        s16x8 o3 = *(const s16x8*)&Opart[base + 2 * str];
        s16x8 o4 = *(const s16x8*)&Opart[base + 3 * str];
        s16x8 r;
#pragma unroll
        for (int e = 0; e < 8; ++e) {
            float v = w1 * bf2f((ushort_t)o1[e]) + w2 * bf2f((ushort_t)o2[e])
                    + w3 * bf2f((ushort_t)o3[e]) + w4 * bf2f((ushort_t)o4[e]);
            r[e] = (short)f2bf(v * inv);
        }
        return r;
    };

    const ushort_t* Wip0 = &W[(size_t)(n0 + srow) * K + cg8];
    const ushort_t* Wip1 = &W[(size_t)(n0 + 16 + srow) * K + cg8];

    s16x8 ra0 = loadA(m0 + srow, cg8);
    s16x8 ra1 = loadA(m0 + 16 + srow, cg8);
    s16x8 rw0 = *(const s16x8*)Wip0;
    s16x8 rw1 = *(const s16x8*)Wip1;
    *(s16x8*)&As[0][srow * ASTR + cg8] = ra0;
    *(s16x8*)&As[0][(16 + srow) * ASTR + cg8] = ra1;
    *(s16x8*)&Ws[0][srow * ASTR + cg8] = rw0;
    *(s16x8*)&Ws[0][(16 + srow) * ASTR + cg8] = rw1;
    __syncthreads();

    f32x4 acc[2] = {{0.f, 0.f, 0.f, 0.f}, {0.f, 0.f, 0.f, 0.f}};
    const int nsteps = 4;

    for (int ks = 0; ks < nsteps; ++ks) {
        const int b = ks & 1;
        const bool pf = (ks + 1 < nsteps);
        if (pf) {
            int ko = (ks + 1) << 6;
            ra0 = loadA(m0 + srow, ko + cg8);
            ra1 = loadA(m0 + 16 + srow, ko + cg8);
            rw0 = *(const s16x8*)(Wip0 + ko);
            rw1 = *(const s16x8*)(Wip1 + ko);
        }
#pragma unroll
        for (int kt = 0; kt < 2; ++kt) {
            s16x8 af = *(const s16x8*)&As[b][(16 * w + c) * ASTR + kt * 32 + 8 * g];
            s16x8 wf0 = *(const s16x8*)&Ws[b][c * ASTR + kt * 32 + 8 * g];
            s16x8 wf1 = *(const s16x8*)&Ws[b][(16 + c) * ASTR + kt * 32 + 8 * g];
            acc[0] = __builtin_amdgcn_mfma_f32_16x16x32_bf16(af, wf0, acc[0], 0, 0, 0);
            acc[1] = __builtin_amdgcn_mfma_f32_16x16x32_bf16(af, wf1, acc[1], 0, 0, 0);
        }
        if (pf) {
            int nb = b ^ 1;
            *(s16x8*)&As[nb][srow * ASTR + cg8] = ra0;
            *(s16x8*)&As[nb][(16 + srow) * ASTR + cg8] = ra1;
            *(s16x8*)&Ws[nb][srow * ASTR + cg8] = rw0;
            *(s16x8*)&Ws[nb][(16 + srow) * ASTR + cg8] = rw1;
        }
        __syncthreads();
    }

#pragma unroll
    for (int nt = 0; nt < 2; ++nt) {
        int n = n0 + 16 * nt + c;
        float bv = bias[n];
#pragma unroll
        for (int r = 0; r < 4; ++r) {
            int m = m0 + 16 * w + 4 * g + r;
            outf[(size_t)m * 256 + n] = acc[nt][r] + bv + res[(size_t)m * 256 + n];
        }
    }
}

// ---------------------------------------------------------------------------
// Split-KV MFMA flash attention. Reg-direct Q; double-buffered K/V, ONE
// barrier per tile; mask from TWO bitplanes (no per-element index math);
// setprio(1) around MFMA clusters. LDS 27.9 KB -> 5 blocks/CU.
// lvl2: blocks 0..1023  = qt(32) x h(8) x split(4), tps=8
// lvl3: blocks 1024..1279 = qt(8) x h(8) x split(4), tps=2
// ---------------------------------------------------------------------------
#define KS 40
#define VS 66
#define PS 72
#define OS 68

__global__ __launch_bounds__(256) void flash_split(const ushort_t* __restrict__ qkvb,
                                                   const u64* __restrict__ ubits,
                                                   ushort_t* __restrict__ Opart,
                                                   float2* __restrict__ ml) {
    __shared__ __align__(16) ushort_t ks[2][64 * KS];
    __shared__ __align__(16) ushort_t vts[2][32 * VS];
    __shared__ __align__(16) char pso[64 * PS * 2];
    ushort_t* ps = (ushort_t*)pso;
    float* os = (float*)pso;

    const int bx = blockIdx.x;
    int qt, h, split, L, rowbase;
    const u64* ub;
    if (bx < 1024) {
        qt = bx & 31; h = (bx >> 5) & 7; split = bx >> 8;
        L = 2048; rowbase = 0; ub = ubits;
    } else {
        int lo = bx - 1024;
        qt = lo & 7; h = (lo >> 3) & 7; split = lo >> 6;
        L = 512; rowbase = 2048; ub = ubits + 65536;
    }
    const int tps = (L >> 6) >> 2;
    const int ts0 = split * tps;
    const int nch = L >> 8;             // 256-chunks per row: 8 or 2

    const int t = threadIdx.x;
    const int w = t >> 6;
    const int l = t & 63;
    const int c = l & 15;
    const int g = l >> 4;

    const int srow = t >> 2;
    const int sc8 = (t & 3) * 8;
    const int q0g = rowbase + qt * 64;

    // ---- Q fragment: direct register load ----
    const int ql = qt * 64 + 16 * w + c;
    const s16x8 qf = *(const s16x8*)&qkvb[(size_t)(rowbase + ql) * 768 + h * 32 + 8 * g];
    const u64* ubq = &ub[(size_t)ql * nch * 4];

    // ---- prologue ----
    s16x8 kreg, vreg;
    {
        size_t base = (size_t)(rowbase + ts0 * 64 + srow) * 768 + h * 32 + sc8;
        s16x8 k0r = *(const s16x8*)&qkvb[base + 256];
        s16x8 v0r = *(const s16x8*)&qkvb[base + 512];
        *(s16x8*)&ks[0][srow * KS + sc8] = k0r;
#pragma unroll
        for (int i = 0; i < 8; ++i)
            vts[0][(sc8 + i) * VS + srow] = (ushort_t)v0r[i];
        if (tps > 1) {
            kreg = *(const s16x8*)&qkvb[base + 64 * 768 + 256];
            vreg = *(const s16x8*)&qkvb[base + 64 * 768 + 512];
        }
    }
    __syncthreads();

    f32x4 oacc0 = {0.f, 0.f, 0.f, 0.f};
    f32x4 oacc1 = {0.f, 0.f, 0.f, 0.f};
    float mold = -3e38f, lrun = 0.f;
    const f32x4 zc = {0.f, 0.f, 0.f, 0.f};

    u64 wl0 = 0, wl1 = 0, wl2 = 0, wl3 = 0;
    u64 wh0 = 0, wh1 = 0, wh2 = 0, wh3 = 0;
    int cur = 0;
    for (int kt = 0; kt < tps; ++kt) {
        const int nxt = cur ^ 1;
        const int gt = ts0 + kt;

        if (kt + 1 < tps) {
            *(s16x8*)&ks[nxt][srow * KS + sc8] = kreg;
#pragma unroll
            for (int i = 0; i < 8; ++i)
                vts[nxt][(sc8 + i) * VS + srow] = (ushort_t)vreg[i];
        }
        if (kt + 2 < tps) {
            size_t base = (size_t)(rowbase + (gt + 2) * 64 + srow) * 768 + h * 32 + sc8;
            kreg = *(const s16x8*)&qkvb[base + 256];
            vreg = *(const s16x8*)&qkvb[base + 512];
        }

        if ((gt & 3) == 0 || kt == 0) {
            const u64* bp = &ubq[(size_t)(gt >> 2) * 4];
            wl0 = bp[0]; wl1 = bp[1]; wl2 = bp[2]; wl3 = bp[3];
            wh0 = bp[HIPL]; wh1 = bp[HIPL + 1]; wh2 = bp[HIPL + 2]; wh3 = bp[HIPL + 3];
        }
        const unsigned shb = 16 * (gt & 3);

        // ---- S^T = K · Q^T ----
        f32x4 sacc[4];
        __builtin_amdgcn_s_setprio(1);
#pragma unroll
        for (int nt = 0; nt < 4; ++nt) {
            s16x8 kf = *(const s16x8*)&ks[cur][(16 * nt + c) * KS + 8 * g];
            sacc[nt] = __builtin_amdgcn_mfma_f32_16x16x32_bf16(kf, qf, zc, 0, 0, 0);
        }
        __builtin_amdgcn_s_setprio(0);

        // ---- mask (bitplanes) + per-lane online softmax ----
        float sv[4][4];
        float m = -3e38f;
#pragma unroll
        for (int nt = 0; nt < 4; ++nt) {
            unsigned sh = shb + 4 * nt + g;
#pragma unroll
            for (int r = 0; r < 4; ++r) {
                u64 wl = (r == 0) ? wl0 : (r == 1) ? wl1 : (r == 2) ? wl2 : wl3;
                u64 wh = (r == 0) ? wh0 : (r == 1) ? wh1 : (r == 2) ? wh2 : wh3;
                unsigned lo = (unsigned)(wl >> sh) & 1u;
                unsigned hi = (unsigned)(wh >> sh) & 1u;
                float s = sacc[nt][r] + (float)(lo + 2u * hi);
                sv[nt][r] = s;
                m = fmaxf(m, s);
            }
        }
        m = fmaxf(m, __shfl_xor(m, 16));
        m = fmaxf(m, __shfl_xor(m, 32));
        float newm = fmaxf(mold, m);
        float fac = __expf(mold - newm);
        mold = newm;

        float sum = 0.f;
#pragma unroll
        for (int nt = 0; nt < 4; ++nt) {
            float p0 = __expf(sv[nt][0] - newm);
            float p1 = __expf(sv[nt][1] - newm);
            float p2 = __expf(sv[nt][2] - newm);
            float p3 = __expf(sv[nt][3] - newm);
            sum += (p0 + p1) + (p2 + p3);
            u32x2 pk;
            pk[0] = ((unsigned)f2bf(p1) << 16) | f2bf(p0);
            pk[1] = ((unsigned)f2bf(p3) << 16) | f2bf(p2);
            *(u32x2*)&ps[(16 * w + c) * PS + 16 * nt + 4 * g] = pk;
        }
        sum += __shfl_xor(sum, 16);
        sum += __shfl_xor(sum, 32);
        lrun = lrun * fac + sum;
        oacc0 *= fac;
        oacc1 *= fac;

        // ---- O^T += V^T · P^T ----
        __builtin_amdgcn_s_setprio(1);
#pragma unroll
        for (int kc = 0; kc < 2; ++kc) {
            s16x8 pfr = *(const s16x8*)&ps[(16 * w + c) * PS + 32 * kc + 8 * g];
            s16x8 vf0 = *(const s16x8*)&vts[cur][c * VS + 32 * kc + 8 * g];
            s16x8 vf1 = *(const s16x8*)&vts[cur][(16 + c) * VS + 32 * kc + 8 * g];
            oacc0 = __builtin_amdgcn_mfma_f32_16x16x32_bf16(vf0, pfr, oacc0, 0, 0, 0);
            oacc1 = __builtin_amdgcn_mfma_f32_16x16x32_bf16(vf1, pfr, oacc1, 0, 0, 0);
        }
        __builtin_amdgcn_s_setprio(0);

        __syncthreads();
        cur = nxt;
    }

    if (g == 0) {
        int q = q0g + 16 * w + c;
        ml[((size_t)split * RTOT + q) * 8 + h] = make_float2(mold, lrun);
    }

    // unnormalized partial O (bf16) via LDS transpose (os aliases ps)
#pragma unroll
    for (int r = 0; r < 4; ++r) {
        os[(4 * g + r) * OS + 16 * w + c] = oacc0[r];
        os[(16 + 4 * g + r) * OS + 16 * w + c] = oacc1[r];
    }
    __syncthreads();
    {
        int r = t >> 2, d0 = (t & 3) * 8;
        s16x8 pk;
#pragma unroll
        for (int i = 0; i < 8; ++i) pk[i] = (short)f2bf(os[(d0 + i) * OS + r]);
        *(s16x8*)&Opart[((size_t)split * RTOT + q0g + r) * 256 + h * 32 + d0] = pk;
    }
}

// LayerNorm over C=256, one block per row; writes f32 + bf16
__global__ __launch_bounds__(256) void ln1_kernel(const float* __restrict__ in,
                                                  const float* __restrict__ g,
                                                  const float* __restrict__ b,
                                                  float* __restrict__ outf,
                                                  ushort_t* __restrict__ outb) {
    __shared__ float red[256];
    int row = blockIdx.x, t = threadIdx.x;
    float v = in[(size_t)row * 256 + t];
    red[t] = v;
    __syncthreads();
    for (int s = 128; s > 0; s >>= 1) {
        if (t < s) red[t] += red[t + s];
        __syncthreads();
    }
    float mean = red[0] * (1.f / 256.f);
    __syncthreads();
    float d = v - mean;
    red[t] = d * d;
    __syncthreads();
    for (int s = 128; s > 0; s >>= 1) {
        if (t < s) red[t] += red[t + s];
        __syncthreads();
    }
    float var = red[0] * (1.f / 256.f);
    float r = d * rsqrtf(var + 1e-5f) * g[t] + b[t];
    outf[(size_t)row * 256 + t] = r;
    outb[(size_t)row * 256 + t] = f2bf(r);
}

// LayerNorm + NCHW scatter to the two output tensors
__global__ __launch_bounds__(256) void ln2_out(const float* __restrict__ in,
                                               const float* __restrict__ g,
                                               const float* __restrict__ b,
                                               float* __restrict__ out2,
                                               float* __restrict__ out3) {
    __shared__ float red[256];
    int row = blockIdx.x, t = threadIdx.x;
    float v = in[(size_t)row * 256 + t];
    red[t] = v;
    __syncthreads();
    for (int s = 128; s > 0; s >>= 1) {
        if (t < s) red[t] += red[t + s];
        __syncthreads();
    }
    float mean = red[0] * (1.f / 256.f);
    __syncthreads();
    float d = v - mean;
    red[t] = d * d;
    __syncthreads();
    for (int s = 128; s > 0; s >>= 1) {
        if (t < s) red[t] += red[t + s];
        __syncthreads();
    }
    float var = red[0] * (1.f / 256.f);
    float r = d * rsqrtf(var + 1e-5f) * g[t] + b[t];
    if (row < 2048) {
        int n = row >> 10, hw = row & 1023;
        out2[((size_t)(n * 256 + t) << 10) + hw] = r;
    } else {
        int rl = row - 2048;
        int n = rl >> 8, hw = rl & 255;
        out3[((size_t)(n * 256 + t) << 8) + hw] = r;
    }
}

// ---------------------------------------------------------------------------

extern "C" void kernel_launch(void* const* d_in, const int* in_sizes, int n_in,
                              void* d_out, int out_size, void* d_ws, size_t ws_size,
                              hipStream_t stream) {
    const float* f0 = (const float*)d_in[0];
    const float* f1 = (const float*)d_in[1];
    const float* f2 = (const float*)d_in[2];
    const float* f3 = (const float*)d_in[3];
    const float* u2 = (const float*)d_in[4];
    const float* u3 = (const float*)d_in[5];
    const float* Wqkv = (const float*)d_in[6];
    const float* bqkv = (const float*)d_in[7];
    const float* Wo   = (const float*)d_in[8];
    const float* bo   = (const float*)d_in[9];
    const float* g1   = (const float*)d_in[10];
    const float* b1   = (const float*)d_in[11];
    const float* Wfc1 = (const float*)d_in[12];
    const float* bfc1 = (const float*)d_in[13];
    const float* Wfc2 = (const float*)d_in[14];
    const float* bfc2 = (const float*)d_in[15];
    const float* g2   = (const float*)d_in[16];
    const float* b2   = (const float*)d_in[17];

    float* out = (float*)d_out;
    float* ws = (float*)d_ws;

    // bf16 weights
    ushort_t* wqkv = (ushort_t*)ws;             // 196608 us
    ushort_t* wo   = (ushort_t*)(ws + 98304);   // 65536 us
    ushort_t* wfc1 = (ushort_t*)(ws + 131072);  // 262144 us
    ushort_t* wfc2 = (ushort_t*)(ws + 262144);  // 262144 us

    // scratch (floats)
    float* sc = ws + 393216;
    float*    src_f32 = sc;                          // [0, 655360)
    ushort_t* qkvb    = (ushort_t*)(sc + 655360);    // 2560*768 us -> ends 1638400
    ushort_t* src_bf  = (ushort_t*)(sc + 1638400);   // -> 1966080
    float*    t1      = sc + 1966080;                // 655360
    float*    x_f32   = sc + 2621440;                // 655360 (ubits alias:
    u64*      ubits   = (u64*)x_f32;                 //   2*69632 u64 = 278528 f < 655360)
    ushort_t* x_bf    = (ushort_t*)(sc + 3276800);   // 2560*256 us
    float2*   ml      = (float2*)(sc + 3604480);     // 4*2560*8 f2
    ushort_t* Opart   = (ushort_t*)(sc + 3768320);   // 4*2560*256 us
    ushort_t* h_bf    = Opart;                       // alias post-wo

    prep<<<9280, 256, 0, stream>>>(f0, f1, out,
                                   Wqkv, Wo, Wfc1, Wfc2, wqkv, wo, wfc1, wfc2,
                                   u2, u3, ubits, f2, f3, src_f32, src_bf);

    gemm64<3><<<dim3(12, 40), 256, 0, stream>>>(
        src_bf, wqkv, bqkv, qkvb, RTOT, 768, 256);
    flash_split<<<1280, 256, 0, stream>>>(qkvb, ubits, Opart, ml);
    gemm_wo<<<dim3(8, 80), 128, 0, stream>>>(Opart, ml, wo, bo, src_f32, t1);
    ln1_kernel<<<2560, 256, 0, stream>>>(t1, g1, b1, x_f32, x_bf);
    gemm64<1><<<dim3(16, 40), 256, 0, stream>>>(
        x_bf, wfc1, bfc1, h_bf, RTOT, 1024, 256);
    gemm_fc2<<<dim3(8, 80), 128, 0, stream>>>(
        h_bf, wfc2, bfc2, x_f32, t1, RTOT, 256, 1024);
    ln2_out<<<2560, 256, 0, stream>>>(t1, g2, b2, out + 4096000, out + 4620288);
}

// Round 18
// 87.337 us; speedup vs baseline: 1.0515x; 1.0091x over previous
//
#include <hip/hip_runtime.h>
#include <hip/hip_bf16.h>
#include <cstddef>

// ---------------------------------------------------------------------------
// sparse_attn: transformer encoder block on levels 2 & 3.
// Round 18: R17 base + defer-max (RESCALE_THRESHOLD=8) with lazy per-lane
// sum accumulation (single end-of-loop reduce). Bitplane mask + setprio kept.
// Rows 0..2047 = level2 (S=1024), 2048..2559 = level3 (S=256). R=2560.
// ---------------------------------------------------------------------------

typedef __attribute__((ext_vector_type(8))) short s16x8;
typedef __attribute__((ext_vector_type(4))) short s16x4;
typedef __attribute__((ext_vector_type(4))) float f32x4;
typedef __attribute__((ext_vector_type(2))) unsigned int u32x2;
typedef unsigned short ushort_t;
typedef unsigned long long u64;

#define RTOT 2560
#define HIPL 69632   // u64 offset of the hi bitplane

__device__ inline unsigned short f2bf(float x) {
    union { __hip_bfloat16 h; unsigned short u; } cv;
    cv.h = __float2bfloat16(x);
    return cv.u;
}
__device__ inline float bf2f(unsigned short u) {
    union { unsigned int i; float f; } cv;
    cv.i = ((unsigned int)u) << 16;
    return cv.f;
}

// ---------------------------------------------------------------------------
// prep (9280 blocks):
//   0..159     : f2/f3 NCHW -> [2560,256] fp32+bf16 (64x64 LDS tile, first)
//   160..4159  : f0/f1 pass-through copy (f32x4)
//   4160..4927 : weights fp32->bf16
//   4928..9279 : mask VALUE planes: val = rand + pos + frame (0..3);
//                lo bits at ub[..], hi bits at ub[HIPL + ..].
// ---------------------------------------------------------------------------
__global__ __launch_bounds__(256) void prep(const float* __restrict__ f0,
                                            const float* __restrict__ f1,
                                            float* __restrict__ outp,
                                            const float* __restrict__ wqkv,
                                            const float* __restrict__ wo,
                                            const float* __restrict__ wfc1,
                                            const float* __restrict__ wfc2,
                                            ushort_t* __restrict__ o1,
                                            ushort_t* __restrict__ o2,
                                            ushort_t* __restrict__ o3,
                                            ushort_t* __restrict__ o4,
                                            const float* __restrict__ u2,
                                            const float* __restrict__ u3,
                                            u64* __restrict__ ub,
                                            const float* __restrict__ f2,
                                            const float* __restrict__ f3,
                                            float* __restrict__ srcf,
                                            ushort_t* __restrict__ srcb) {
    __shared__ float tl[64][65];
    int bid = blockIdx.x;
    int t = threadIdx.x;
    if (bid < 160) {
        int b = bid;
        const float* src; int S, rowb, n, ct, ht;
        if (b < 128) {
            n = b >> 6; int rem = b & 63; ct = rem >> 4; ht = rem & 15;
            src = f2; S = 1024; rowb = 0;
        } else {
            int b2 = b - 128;
            n = b2 >> 4; int rem = b2 & 15; ct = rem >> 2; ht = rem & 3;
            src = f3; S = 256; rowb = 2048;
        }
        int c0 = ct * 64, hw0 = ht * 64;
        int i = t >> 6, lane = t & 63;
#pragma unroll
        for (int jj = 0; jj < 16; ++jj) {
            int cl = i * 16 + jj;
            tl[lane][cl] = src[(size_t)(n * 256 + c0 + cl) * S + hw0 + lane];
        }
        __syncthreads();
#pragma unroll
        for (int jj = 0; jj < 16; ++jj) {
            int hl = i * 16 + jj;
            int row = rowb + n * S + hw0 + hl;
            float v = tl[hl][lane];
            srcf[(size_t)row * 256 + c0 + lane] = v;
            srcb[(size_t)row * 256 + c0 + lane] = f2bf(v);
        }
    } else if (bid < 4160) {
        int idx = (bid - 160) * 256 + t;
        f32x4 v = (idx < 819200) ? ((const f32x4*)f0)[idx]
                                 : ((const f32x4*)f1)[idx - 819200];
        ((f32x4*)outp)[idx] = v;
    } else if (bid < 4928) {
        int i = (bid - 4160) * 256 + t;
        const float* src; ushort_t* dst; int li;
        if (i < 49152)       { src = wqkv; dst = o1; li = i; }
        else if (i < 65536)  { src = wo;   dst = o2; li = i - 49152; }
        else if (i < 131072) { src = wfc1; dst = o3; li = i - 65536; }
        else                 { src = wfc2; dst = o4; li = i - 131072; }
        f32x4 v = ((const f32x4*)src)[li];
        s16x4 r;
        r[0] = (short)f2bf(v[0]); r[1] = (short)f2bf(v[1]);
        r[2] = (short)f2bf(v[2]); r[3] = (short)f2bf(v[3]);
        ((s16x4*)dst)[li] = r;
    } else {
        int gw = ((bid - 4928) * 256 + t) >> 6;   // chunk 0..17407
        int lane = t & 63;
        const float* p;
        u64* dstLo;
        int q, kb, smask, sshift;
        if (gw < 16384) {
            int row = gw >> 3, ch = gw & 7;
            p = &u2[(size_t)row * 2048 + ch * 256 + lane * 4];
            dstLo = &ub[(size_t)gw * 4];
            q = row; kb = ch * 256 + lane * 4; smask = 1023; sshift = 10;
        } else {
            int lw = gw - 16384;
            int row = lw >> 1, ch = lw & 1;
            p = &u3[(size_t)row * 512 + ch * 256 + lane * 4];
            dstLo = &ub[65536 + (size_t)lw * 4];
            q = row; kb = ch * 256 + lane * 4; smask = 255; sshift = 8;
        }
        u64* dstHi = dstLo + HIPL;
        f32x4 v = *(const f32x4*)p;
        int qp = q & smask, qf = q >> sshift;
        u64 bl[4], bh[4];
#pragma unroll
        for (int j = 0; j < 4; ++j) {
            int k = kb + j;
            int val = (v[j] >= 0.1f ? 1 : 0)
                    + ((k & smask) == qp ? 1 : 0)
                    + ((k >> sshift) == qf ? 1 : 0);
            bl[j] = __ballot((val & 1) != 0);
            bh[j] = __ballot((val & 2) != 0);
        }
        if (lane < 4) {
            u64 x = (lane == 0) ? bl[0] : (lane == 1) ? bl[1]
                  : (lane == 2) ? bl[2] : bl[3];
            dstLo[lane] = x;
        } else if (lane < 8) {
            int j = lane - 4;
            u64 x = (j == 0) ? bh[0] : (j == 1) ? bh[1]
                  : (j == 2) ? bh[2] : bh[3];
            dstHi[j] = x;
        }
    }
}

#define ASTR 72

// ---------------------------------------------------------------------------
// bf16 MFMA GEMM, tile 64x64, 256 threads (4 waves). For qkv / fc1.
// ---------------------------------------------------------------------------
template <int EPI>
__global__ __launch_bounds__(256) void gemm64(const ushort_t* __restrict__ A,
                                              const ushort_t* __restrict__ W,
                                              const float* __restrict__ bias,
                                              ushort_t* __restrict__ outb,
                                              int M, int N, int K) {
    __shared__ __align__(16) ushort_t As[2][64 * ASTR];
    __shared__ __align__(16) ushort_t Ws[2][64 * ASTR];

    const int t = threadIdx.x;
    const int w = t >> 6, l = t & 63;
    const int c = l & 15, g = l >> 4;
    const int mh = w >> 1, nh = w & 1;
    const int m0 = blockIdx.y * 64, n0 = blockIdx.x * 64;
    const int srow = t >> 3;
    const int cg8 = (t & 7) * 8;

    const ushort_t* Aip0 = &A[(size_t)(m0 + srow) * K + cg8];
    const ushort_t* Aip1 = &A[(size_t)(m0 + 32 + srow) * K + cg8];
    const ushort_t* Wip0 = &W[(size_t)(n0 + srow) * K + cg8];
    const ushort_t* Wip1 = &W[(size_t)(n0 + 32 + srow) * K + cg8];

    s16x8 ra0 = *(const s16x8*)Aip0;
    s16x8 ra1 = *(const s16x8*)Aip1;
    s16x8 rw0 = *(const s16x8*)Wip0;
    s16x8 rw1 = *(const s16x8*)Wip1;
    *(s16x8*)&As[0][srow * ASTR + cg8] = ra0;
    *(s16x8*)&As[0][(32 + srow) * ASTR + cg8] = ra1;
    *(s16x8*)&Ws[0][srow * ASTR + cg8] = rw0;
    *(s16x8*)&Ws[0][(32 + srow) * ASTR + cg8] = rw1;
    __syncthreads();

    f32x4 acc[2][2] = {{{0.f,0.f,0.f,0.f},{0.f,0.f,0.f,0.f}},
                       {{0.f,0.f,0.f,0.f},{0.f,0.f,0.f,0.f}}};
    const int nsteps = K >> 6;

    for (int ks = 0; ks < nsteps; ++ks) {
        const int b = ks & 1;
        const bool pf = (ks + 1 < nsteps);
        if (pf) {
            int ko = (ks + 1) << 6;
            ra0 = *(const s16x8*)(Aip0 + ko);
            ra1 = *(const s16x8*)(Aip1 + ko);
            rw0 = *(const s16x8*)(Wip0 + ko);
            rw1 = *(const s16x8*)(Wip1 + ko);
        }
#pragma unroll
        for (int sl = 0; sl < 2; ++sl) {
            s16x8 af0 = *(const s16x8*)&As[b][(32 * mh + c) * ASTR + sl * 32 + 8 * g];
            s16x8 af1 = *(const s16x8*)&As[b][(32 * mh + 16 + c) * ASTR + sl * 32 + 8 * g];
            s16x8 wf0 = *(const s16x8*)&Ws[b][(32 * nh + c) * ASTR + sl * 32 + 8 * g];
            s16x8 wf1 = *(const s16x8*)&Ws[b][(32 * nh + 16 + c) * ASTR + sl * 32 + 8 * g];
            acc[0][0] = __builtin_amdgcn_mfma_f32_16x16x32_bf16(af0, wf0, acc[0][0], 0, 0, 0);
            acc[0][1] = __builtin_amdgcn_mfma_f32_16x16x32_bf16(af0, wf1, acc[0][1], 0, 0, 0);
            acc[1][0] = __builtin_amdgcn_mfma_f32_16x16x32_bf16(af1, wf0, acc[1][0], 0, 0, 0);
            acc[1][1] = __builtin_amdgcn_mfma_f32_16x16x32_bf16(af1, wf1, acc[1][1], 0, 0, 0);
        }
        if (pf) {
            int nb = b ^ 1;
            *(s16x8*)&As[nb][srow * ASTR + cg8] = ra0;
            *(s16x8*)&As[nb][(32 + srow) * ASTR + cg8] = ra1;
            *(s16x8*)&Ws[nb][srow * ASTR + cg8] = rw0;
            *(s16x8*)&Ws[nb][(32 + srow) * ASTR + cg8] = rw1;
        }
        __syncthreads();
    }

#pragma unroll
    for (int i = 0; i < 2; ++i)
#pragma unroll
    for (int j = 0; j < 2; ++j) {
        int n = n0 + 32 * nh + 16 * j + c;
        float bv = bias[n];
        float sc = 1.f;
        if (EPI == 3) sc = (n < 256) ? 0.17677669529663687f : 1.f;
#pragma unroll
        for (int r = 0; r < 4; ++r) {
            int m = m0 + 32 * mh + 16 * i + 4 * g + r;
            float v = acc[i][j][r] + bv;
            if (EPI == 1) v = fmaxf(v, 0.f);
            if (EPI == 3) v *= sc;
            outb[(size_t)m * N + n] = f2bf(v);
        }
    }
}

// ---------------------------------------------------------------------------
// bf16 MFMA GEMM, tile 32x32, 128 threads (2 waves). fc2: K=1024, res, f32 out.
// ---------------------------------------------------------------------------
__global__ __launch_bounds__(128) void gemm_fc2(const ushort_t* __restrict__ A,
                                                const ushort_t* __restrict__ W,
                                                const float* __restrict__ bias,
                                                const float* __restrict__ res,
                                                float* __restrict__ outf,
                                                int M, int N, int K) {
    __shared__ __align__(16) ushort_t As[2][32 * ASTR];
    __shared__ __align__(16) ushort_t Ws[2][32 * ASTR];

    const int t = threadIdx.x;
    const int w = t >> 6, l = t & 63;
    const int c = l & 15, g = l >> 4;
    const int m0 = blockIdx.y * 32, n0 = blockIdx.x * 32;
    const int srow = t >> 3;
    const int cg8 = (t & 7) * 8;

    const ushort_t* Aip0 = &A[(size_t)(m0 + srow) * K + cg8];
    const ushort_t* Aip1 = &A[(size_t)(m0 + 16 + srow) * K + cg8];
    const ushort_t* Wip0 = &W[(size_t)(n0 + srow) * K + cg8];
    const ushort_t* Wip1 = &W[(size_t)(n0 + 16 + srow) * K + cg8];

    s16x8 ra0 = *(const s16x8*)Aip0;
    s16x8 ra1 = *(const s16x8*)Aip1;
    s16x8 rw0 = *(const s16x8*)Wip0;
    s16x8 rw1 = *(const s16x8*)Wip1;
    *(s16x8*)&As[0][srow * ASTR + cg8] = ra0;
    *(s16x8*)&As[0][(16 + srow) * ASTR + cg8] = ra1;
    *(s16x8*)&Ws[0][srow * ASTR + cg8] = rw0;
    *(s16x8*)&Ws[0][(16 + srow) * ASTR + cg8] = rw1;
    __syncthreads();

    f32x4 acc[2] = {{0.f, 0.f, 0.f, 0.f}, {0.f, 0.f, 0.f, 0.f}};
    const int nsteps = K >> 6;

    for (int ks = 0; ks < nsteps; ++ks) {
        const int b = ks & 1;
        const bool pf = (ks + 1 < nsteps);
        if (pf) {
            int ko = (ks + 1) << 6;
            ra0 = *(const s16x8*)(Aip0 + ko);
            ra1 = *(const s16x8*)(Aip1 + ko);
            rw0 = *(const s16x8*)(Wip0 + ko);
            rw1 = *(const s16x8*)(Wip1 + ko);
        }
#pragma unroll
        for (int kt = 0; kt < 2; ++kt) {
            s16x8 af = *(const s16x8*)&As[b][(16 * w + c) * ASTR + kt * 32 + 8 * g];
            s16x8 wf0 = *(const s16x8*)&Ws[b][c * ASTR + kt * 32 + 8 * g];
            s16x8 wf1 = *(const s16x8*)&Ws[b][(16 + c) * ASTR + kt * 32 + 8 * g];
            acc[0] = __builtin_amdgcn_mfma_f32_16x16x32_bf16(af, wf0, acc[0], 0, 0, 0);
            acc[1] = __builtin_amdgcn_mfma_f32_16x16x32_bf16(af, wf1, acc[1], 0, 0, 0);
        }
        if (pf) {
            int nb = b ^ 1;
            *(s16x8*)&As[nb][srow * ASTR + cg8] = ra0;
            *(s16x8*)&As[nb][(16 + srow) * ASTR + cg8] = ra1;
            *(s16x8*)&Ws[nb][srow * ASTR + cg8] = rw0;
            *(s16x8*)&Ws[nb][(16 + srow) * ASTR + cg8] = rw1;
        }
        __syncthreads();
    }

#pragma unroll
    for (int nt = 0; nt < 2; ++nt) {
        int n = n0 + 16 * nt + c;
        float bv = bias[n];
#pragma unroll
        for (int r = 0; r < 4; ++r) {
            int m = m0 + 16 * w + 4 * g + r;
            float v = acc[nt][r] + bv + res[(size_t)m * N + n];
            outf[(size_t)m * N + n] = v;
        }
    }
}

// ---------------------------------------------------------------------------
// Wo GEMM with fused 4-split merge in the A-staging. Tile 32x32, 128 threads.
// ---------------------------------------------------------------------------
__global__ __launch_bounds__(128) void gemm_wo(const ushort_t* __restrict__ Opart,
                                               const float2* __restrict__ ml,
                                               const ushort_t* __restrict__ W,
                                               const float* __restrict__ bias,
                                               const float* __restrict__ res,
                                               float* __restrict__ outf) {
    const int K = 256, N = 256;
    __shared__ __align__(16) ushort_t As[2][32 * ASTR];
    __shared__ __align__(16) ushort_t Ws[2][32 * ASTR];

    const int t = threadIdx.x;
    const int w = t >> 6, l = t & 63;
    const int c = l & 15, g = l >> 4;
    const int m0 = blockIdx.y * 32, n0 = blockIdx.x * 32;
    const int srow = t >> 3;
    const int cg8 = (t & 7) * 8;

    auto loadA = [&](int row, int kcol) -> s16x8 {
        int head = kcol >> 5;
        float2 a0 = ml[((size_t)0 * RTOT + row) * 8 + head];
        float2 a1 = ml[((size_t)1 * RTOT + row) * 8 + head];
        float2 a2 = ml[((size_t)2 * RTOT + row) * 8 + head];
        float2 a3 = ml[((size_t)3 * RTOT + row) * 8 + head];
        float M = fmaxf(fmaxf(a0.x, a1.x), fmaxf(a2.x, a3.x));
        float w1 = __expf(a0.x - M), w2 = __expf(a1.x - M);
        float w3 = __expf(a2.x - M), w4 = __expf(a3.x - M);
        float inv = 1.f / (w1 * a0.y + w2 * a1.y + w3 * a2.y + w4 * a3.y);
        const size_t str = (size_t)RTOT * 256;
        size_t base = (size_t)row * 256 + kcol;
        s16x8 o1 = *(const s16x8*)&Opart[base];
        s16x8 o2 = *(const s16x8*)&Opart[base + str];
        s16x8 o3 = *(const s16x8*)&Opart[base + 2 * str];
        s16x8 o4 = *(const s16x8*)&Opart[base + 3 * str];
        s16x8 r;
#pragma unroll
        for (int e = 0; e < 8; ++e) {
            float v = w1 * bf2f((ushort_t)o1[e]) + w2 * bf2f((ushort_t)o2[e])
                    + w3 * bf2f((ushort_t)o3[e]) + w4 * bf2f((ushort_t)o4[e]);
            r[e] = (short)f2bf(v * inv);
        }
        return r;
    };

    const ushort_t* Wip0 = &W[(size_t)(n0 + srow) * K + cg8];
    const ushort_t* Wip1 = &W[(size_t)(n0 + 16 + srow) * K + cg8];

    s16x8 ra0 = loadA(m0 + srow, cg8);
    s16x8 ra1 = loadA(m0 + 16 + srow, cg8);
    s16x8 rw0 = *(const s16x8*)Wip0;
    s16x8 rw1 = *(const s16x8*)Wip1;
    *(s16x8*)&As[0][srow * ASTR + cg8] = ra0;
    *(s16x8*)&As[0][(16 + srow) * ASTR + cg8] = ra1;
    *(s16x8*)&Ws[0][srow * ASTR + cg8] = rw0;
    *(s16x8*)&Ws[0][(16 + srow) * ASTR + cg8] = rw1;
    __syncthreads();

    f32x4 acc[2] = {{0.f, 0.f, 0.f, 0.f}, {0.f, 0.f, 0.f, 0.f}};
    const int nsteps = 4;

    for (int ks = 0; ks < nsteps; ++ks) {
        const int b = ks & 1;
        const bool pf = (ks + 1 < nsteps);
        if (pf) {
            int ko = (ks + 1) << 6;
            ra0 = loadA(m0 + srow, ko + cg8);
            ra1 = loadA(m0 + 16 + srow, ko + cg8);
            rw0 = *(const s16x8*)(Wip0 + ko);
            rw1 = *(const s16x8*)(Wip1 + ko);
        }
#pragma unroll
        for (int kt = 0; kt < 2; ++kt) {
            s16x8 af = *(const s16x8*)&As[b][(16 * w + c) * ASTR + kt * 32 + 8 * g];
            s16x8 wf0 = *(const s16x8*)&Ws[b][c * ASTR + kt * 32 + 8 * g];
            s16x8 wf1 = *(const s16x8*)&Ws[b][(16 + c) * ASTR + kt * 32 + 8 * g];
            acc[0] = __builtin_amdgcn_mfma_f32_16x16x32_bf16(af, wf0, acc[0], 0, 0, 0);
            acc[1] = __builtin_amdgcn_mfma_f32_16x16x32_bf16(af, wf1, acc[1], 0, 0, 0);
        }
        if (pf) {
            int nb = b ^ 1;
            *(s16x8*)&As[nb][srow * ASTR + cg8] = ra0;
            *(s16x8*)&As[nb][(16 + srow) * ASTR + cg8] = ra1;
            *(s16x8*)&Ws[nb][srow * ASTR + cg8] = rw0;
            *(s16x8*)&Ws[nb][(16 + srow) * ASTR + cg8] = rw1;
        }
        __syncthreads();
    }

#pragma unroll
    for (int nt = 0; nt < 2; ++nt) {
        int n = n0 + 16 * nt + c;
        float bv = bias[n];
#pragma unroll
        for (int r = 0; r < 4; ++r) {
            int m = m0 + 16 * w + 4 * g + r;
            outf[(size_t)m * 256 + n] = acc[nt][r] + bv + res[(size_t)m * 256 + n];
        }
    }
}

// ---------------------------------------------------------------------------
// Split-KV MFMA flash attention. Reg-direct Q; double-buffered K/V, ONE
// barrier per tile; bitplane mask; setprio around MFMA; defer-max with
// RESCALE_THRESHOLD=8 and lazy per-lane sum (single end reduce).
// lvl2: blocks 0..1023  = qt(32) x h(8) x split(4), tps=8
// lvl3: blocks 1024..1279 = qt(8) x h(8) x split(4), tps=2
// ---------------------------------------------------------------------------
#define KS 40
#define VS 66
#define PS 72
#define OS 68

__global__ __launch_bounds__(256) void flash_split(const ushort_t* __restrict__ qkvb,
                                                   const u64* __restrict__ ubits,
                                                   ushort_t* __restrict__ Opart,
                                                   float2* __restrict__ ml) {
    __shared__ __align__(16) ushort_t ks[2][64 * KS];
    __shared__ __align__(16) ushort_t vts[2][32 * VS];
    __shared__ __align__(16) char pso[64 * PS * 2];
    ushort_t* ps = (ushort_t*)pso;
    float* os = (float*)pso;

    const int bx = blockIdx.x;
    int qt, h, split, L, rowbase;
    const u64* ub;
    if (bx < 1024) {
        qt = bx & 31; h = (bx >> 5) & 7; split = bx >> 8;
        L = 2048; rowbase = 0; ub = ubits;
    } else {
        int lo = bx - 1024;
        qt = lo & 7; h = (lo >> 3) & 7; split = lo >> 6;
        L = 512; rowbase = 2048; ub = ubits + 65536;
    }
    const int tps = (L >> 6) >> 2;
    const int ts0 = split * tps;
    const int nch = L >> 8;

    const int t = threadIdx.x;
    const int w = t >> 6;
    const int l = t & 63;
    const int c = l & 15;
    const int g = l >> 4;

    const int srow = t >> 2;
    const int sc8 = (t & 3) * 8;
    const int q0g = rowbase + qt * 64;

    const int ql = qt * 64 + 16 * w + c;
    const s16x8 qf = *(const s16x8*)&qkvb[(size_t)(rowbase + ql) * 768 + h * 32 + 8 * g];
    const u64* ubq = &ub[(size_t)ql * nch * 4];

    s16x8 kreg, vreg;
    {
        size_t base = (size_t)(rowbase + ts0 * 64 + srow) * 768 + h * 32 + sc8;
        s16x8 k0r = *(const s16x8*)&qkvb[base + 256];
        s16x8 v0r = *(const s16x8*)&qkvb[base + 512];
        *(s16x8*)&ks[0][srow * KS + sc8] = k0r;
#pragma unroll
        for (int i = 0; i < 8; ++i)
            vts[0][(sc8 + i) * VS + srow] = (ushort_t)v0r[i];
        if (tps > 1) {
            kreg = *(const s16x8*)&qkvb[base + 64 * 768 + 256];
            vreg = *(const s16x8*)&qkvb[base + 64 * 768 + 512];
        }
    }
    __syncthreads();

    f32x4 oacc0 = {0.f, 0.f, 0.f, 0.f};
    f32x4 oacc1 = {0.f, 0.f, 0.f, 0.f};
    float mold = -3e38f;
    float lsum = 0.f;                   // per-lane partial Σ exp(s - mold)
    const f32x4 zc = {0.f, 0.f, 0.f, 0.f};

    u64 wl0 = 0, wl1 = 0, wl2 = 0, wl3 = 0;
    u64 wh0 = 0, wh1 = 0, wh2 = 0, wh3 = 0;
    int cur = 0;
    for (int kt = 0; kt < tps; ++kt) {
        const int nxt = cur ^ 1;
        const int gt = ts0 + kt;

        if (kt + 1 < tps) {
            *(s16x8*)&ks[nxt][srow * KS + sc8] = kreg;
#pragma unroll
            for (int i = 0; i < 8; ++i)
                vts[nxt][(sc8 + i) * VS + srow] = (ushort_t)vreg[i];
        }
        if (kt + 2 < tps) {
            size_t base = (size_t)(rowbase + (gt + 2) * 64 + srow) * 768 + h * 32 + sc8;
            kreg = *(const s16x8*)&qkvb[base + 256];
            vreg = *(const s16x8*)&qkvb[base + 512];
        }

        if ((gt & 3) == 0 || kt == 0) {
            const u64* bp = &ubq[(size_t)(gt >> 2) * 4];
            wl0 = bp[0]; wl1 = bp[1]; wl2 = bp[2]; wl3 = bp[3];
            wh0 = bp[HIPL]; wh1 = bp[HIPL + 1]; wh2 = bp[HIPL + 2]; wh3 = bp[HIPL + 3];
        }
        const unsigned shb = 16 * (gt & 3);

        // ---- S^T = K · Q^T ----
        f32x4 sacc[4];
        __builtin_amdgcn_s_setprio(1);
#pragma unroll
        for (int nt = 0; nt < 4; ++nt) {
            s16x8 kf = *(const s16x8*)&ks[cur][(16 * nt + c) * KS + 8 * g];
            sacc[nt] = __builtin_amdgcn_mfma_f32_16x16x32_bf16(kf, qf, zc, 0, 0, 0);
        }
        __builtin_amdgcn_s_setprio(0);

        // ---- mask (bitplanes) + defer-max online softmax ----
        float sv[4][4];
        float pmax = -3e38f;
#pragma unroll
        for (int nt = 0; nt < 4; ++nt) {
            unsigned sh = shb + 4 * nt + g;
#pragma unroll
            for (int r = 0; r < 4; ++r) {
                u64 wl = (r == 0) ? wl0 : (r == 1) ? wl1 : (r == 2) ? wl2 : wl3;
                u64 wh = (r == 0) ? wh0 : (r == 1) ? wh1 : (r == 2) ? wh2 : wh3;
                unsigned lo = (unsigned)(wl >> sh) & 1u;
                unsigned hi = (unsigned)(wh >> sh) & 1u;
                float s = sacc[nt][r] + (float)(lo + 2u * hi);
                sv[nt][r] = s;
                pmax = fmaxf(pmax, s);
            }
        }
        if (!__all(pmax <= mold + 8.f)) {
            float m = pmax;
            m = fmaxf(m, __shfl_xor(m, 16));
            m = fmaxf(m, __shfl_xor(m, 32));
            float newm = fmaxf(mold, m);
            float fac = __expf(mold - newm);
            mold = newm;
            lsum *= fac;
            oacc0 *= fac;
            oacc1 *= fac;
        }

        float sum = 0.f;
#pragma unroll
        for (int nt = 0; nt < 4; ++nt) {
            float p0 = __expf(sv[nt][0] - mold);
            float p1 = __expf(sv[nt][1] - mold);
            float p2 = __expf(sv[nt][2] - mold);
            float p3 = __expf(sv[nt][3] - mold);
            sum += (p0 + p1) + (p2 + p3);
            u32x2 pk;
            pk[0] = ((unsigned)f2bf(p1) << 16) | f2bf(p0);
            pk[1] = ((unsigned)f2bf(p3) << 16) | f2bf(p2);
            *(u32x2*)&ps[(16 * w + c) * PS + 16 * nt + 4 * g] = pk;
        }
        lsum += sum;

        // ---- O^T += V^T · P^T ----
        __builtin_amdgcn_s_setprio(1);
#pragma unroll
        for (int kc = 0; kc < 2; ++kc) {
            s16x8 pfr = *(const s16x8*)&ps[(16 * w + c) * PS + 32 * kc + 8 * g];
            s16x8 vf0 = *(const s16x8*)&vts[cur][c * VS + 32 * kc + 8 * g];
            s16x8 vf1 = *(const s16x8*)&vts[cur][(16 + c) * VS + 32 * kc + 8 * g];
            oacc0 = __builtin_amdgcn_mfma_f32_16x16x32_bf16(vf0, pfr, oacc0, 0, 0, 0);
            oacc1 = __builtin_amdgcn_mfma_f32_16x16x32_bf16(vf1, pfr, oacc1, 0, 0, 0);
        }
        __builtin_amdgcn_s_setprio(0);

        __syncthreads();
        cur = nxt;
    }

    // final sum reduce (once)
    float lrun = lsum;
    lrun += __shfl_xor(lrun, 16);
    lrun += __shfl_xor(lrun, 32);

    if (g == 0) {
        int q = q0g + 16 * w + c;
        ml[((size_t)split * RTOT + q) * 8 + h] = make_float2(mold, lrun);
    }

    // unnormalized partial O (bf16) via LDS transpose (os aliases ps)
#pragma unroll
    for (int r = 0; r < 4; ++r) {
        os[(4 * g + r) * OS + 16 * w + c] = oacc0[r];
        os[(16 + 4 * g + r) * OS + 16 * w + c] = oacc1[r];
    }
    __syncthreads();
    {
        int r = t >> 2, d0 = (t & 3) * 8;
        s16x8 pk;
#pragma unroll
        for (int i = 0; i < 8; ++i) pk[i] = (short)f2bf(os[(d0 + i) * OS + r]);
        *(s16x8*)&Opart[((size_t)split * RTOT + q0g + r) * 256 + h * 32 + d0] = pk;
    }
}

// LayerNorm over C=256, one block per row; writes f32 + bf16
__global__ __launch_bounds__(256) void ln1_kernel(const float* __restrict__ in,
                                                  const float* __restrict__ g,
                                                  const float* __restrict__ b,
                                                  float* __restrict__ outf,
                                                  ushort_t* __restrict__ outb) {
    __shared__ float red[256];
    int row = blockIdx.x, t = threadIdx.x;
    float v = in[(size_t)row * 256 + t];
    red[t] = v;
    __syncthreads();
    for (int s = 128; s > 0; s >>= 1) {
        if (t < s) red[t] += red[t + s];
        __syncthreads();
    }
    float mean = red[0] * (1.f / 256.f);
    __syncthreads();
    float d = v - mean;
    red[t] = d * d;
    __syncthreads();
    for (int s = 128; s > 0; s >>= 1) {
        if (t < s) red[t] += red[t + s];
        __syncthreads();
    }
    float var = red[0] * (1.f / 256.f);
    float r = d * rsqrtf(var + 1e-5f) * g[t] + b[t];
    outf[(size_t)row * 256 + t] = r;
    outb[(size_t)row * 256 + t] = f2bf(r);
}

// LayerNorm + NCHW scatter to the two output tensors
__global__ __launch_bounds__(256) void ln2_out(const float* __restrict__ in,
                                               const float* __restrict__ g,
                                               const float* __restrict__ b,
                                               float* __restrict__ out2,
                                               float* __restrict__ out3) {
    __shared__ float red[256];
    int row = blockIdx.x, t = threadIdx.x;
    float v = in[(size_t)row * 256 + t];
    red[t] = v;
    __syncthreads();
    for (int s = 128; s > 0; s >>= 1) {
        if (t < s) red[t] += red[t + s];
        __syncthreads();
    }
    float mean = red[0] * (1.f / 256.f);
    __syncthreads();
    float d = v - mean;
    red[t] = d * d;
    __syncthreads();
    for (int s = 128; s > 0; s >>= 1) {
        if (t < s) red[t] += red[t + s];
        __syncthreads();
    }
    float var = red[0] * (1.f / 256.f);
    float r = d * rsqrtf(var + 1e-5f) * g[t] + b[t];
    if (row < 2048) {
        int n = row >> 10, hw = row & 1023;
        out2[((size_t)(n * 256 + t) << 10) + hw] = r;
    } else {
        int rl = row - 2048;
        int n = rl >> 8, hw = rl & 255;
        out3[((size_t)(n * 256 + t) << 8) + hw] = r;
    }
}

// ---------------------------------------------------------------------------

extern "C" void kernel_launch(void* const* d_in, const int* in_sizes, int n_in,
                              void* d_out, int out_size, void* d_ws, size_t ws_size,
                              hipStream_t stream) {
    const float* f0 = (const float*)d_in[0];
    const float* f1 = (const float*)d_in[1];
    const float* f2 = (const float*)d_in[2];
    const float* f3 = (const float*)d_in[3];
    const float* u2 = (const float*)d_in[4];
    const float* u3 = (const float*)d_in[5];
    const float* Wqkv = (const float*)d_in[6];
    const float* bqkv = (const float*)d_in[7];
    const float* Wo   = (const float*)d_in[8];
    const float* bo   = (const float*)d_in[9];
    const float* g1   = (const float*)d_in[10];
    const float* b1   = (const float*)d_in[11];
    const float* Wfc1 = (const float*)d_in[12];
    const float* bfc1 = (const float*)d_in[13];
    const float* Wfc2 = (const float*)d_in[14];
    const float* bfc2 = (const float*)d_in[15];
    const float* g2   = (const float*)d_in[16];
    const float* b2   = (const float*)d_in[17];

    float* out = (float*)d_out;
    float* ws = (float*)d_ws;

    // bf16 weights
    ushort_t* wqkv = (ushort_t*)ws;             // 196608 us
    ushort_t* wo   = (ushort_t*)(ws + 98304);   // 65536 us
    ushort_t* wfc1 = (ushort_t*)(ws + 131072);  // 262144 us
    ushort_t* wfc2 = (ushort_t*)(ws + 262144);  // 262144 us

    // scratch (floats)
    float* sc = ws + 393216;
    float*    src_f32 = sc;                          // [0, 655360)
    ushort_t* qkvb    = (ushort_t*)(sc + 655360);    // 2560*768 us -> ends 1638400
    ushort_t* src_bf  = (ushort_t*)(sc + 1638400);   // -> 1966080
    float*    t1      = sc + 1966080;                // 655360
    float*    x_f32   = sc + 2621440;                // 655360 (ubits alias:
    u64*      ubits   = (u64*)x_f32;                 //   2*69632 u64 = 278528 f)
    ushort_t* x_bf    = (ushort_t*)(sc + 3276800);   // 2560*256 us
    float2*   ml      = (float2*)(sc + 3604480);     // 4*2560*8 f2
    ushort_t* Opart   = (ushort_t*)(sc + 3768320);   // 4*2560*256 us
    ushort_t* h_bf    = Opart;                       // alias post-wo

    prep<<<9280, 256, 0, stream>>>(f0, f1, out,
                                   Wqkv, Wo, Wfc1, Wfc2, wqkv, wo, wfc1, wfc2,
                                   u2, u3, ubits, f2, f3, src_f32, src_bf);

    gemm64<3><<<dim3(12, 40), 256, 0, stream>>>(
        src_bf, wqkv, bqkv, qkvb, RTOT, 768, 256);
    flash_split<<<1280, 256, 0, stream>>>(qkvb, ubits, Opart, ml);
    gemm_wo<<<dim3(8, 80), 128, 0, stream>>>(Opart, ml, wo, bo, src_f32, t1);
    ln1_kernel<<<2560, 256, 0, stream>>>(t1, g1, b1, x_f32, x_bf);
    gemm64<1><<<dim3(16, 40), 256, 0, stream>>>(
        x_bf, wfc1, bfc1, h_bf, RTOT, 1024, 256);
    gemm_fc2<<<dim3(8, 80), 128, 0, stream>>>(
        h_bf, wfc2, bfc2, x_f32, t1, RTOT, 256, 1024);
    ln2_out<<<2560, 256, 0, stream>>>(t1, g2, b2, out + 4096000, out + 4620288);
}

// Round 19
// 86.351 us; speedup vs baseline: 1.0635x; 1.0114x over previous
//
#include <hip/hip_runtime.h>
#include <hip/hip_bf16.h>
#include <cstddef>

// ---------------------------------------------------------------------------
// sparse_attn: transformer encoder block on levels 2 & 3.
// Round 19: R18 + all-bf16 intermediate dataflow (residuals, wo/fc2 outputs,
// LN inputs) — ~14 MB less intermediate traffic. Math stays fp32 in-register.
// Rows 0..2047 = level2 (S=1024), 2048..2559 = level3 (S=256). R=2560.
// ---------------------------------------------------------------------------

typedef __attribute__((ext_vector_type(8))) short s16x8;
typedef __attribute__((ext_vector_type(4))) short s16x4;
typedef __attribute__((ext_vector_type(4))) float f32x4;
typedef __attribute__((ext_vector_type(2))) unsigned int u32x2;
typedef unsigned short ushort_t;
typedef unsigned long long u64;

#define RTOT 2560
#define HIPL 69632   // u64 offset of the hi bitplane

__device__ inline unsigned short f2bf(float x) {
    union { __hip_bfloat16 h; unsigned short u; } cv;
    cv.h = __float2bfloat16(x);
    return cv.u;
}
__device__ inline float bf2f(unsigned short u) {
    union { unsigned int i; float f; } cv;
    cv.i = ((unsigned int)u) << 16;
    return cv.f;
}

// ---------------------------------------------------------------------------
// prep (9280 blocks):
//   0..159     : f2/f3 NCHW -> [2560,256] bf16 (64x64 LDS tile, first)
//   160..4159  : f0/f1 pass-through copy (f32x4)
//   4160..4927 : weights fp32->bf16
//   4928..9279 : mask VALUE planes (0..3): lo bits ub[..], hi bits ub[HIPL+..]
// ---------------------------------------------------------------------------
__global__ __launch_bounds__(256) void prep(const float* __restrict__ f0,
                                            const float* __restrict__ f1,
                                            float* __restrict__ outp,
                                            const float* __restrict__ wqkv,
                                            const float* __restrict__ wo,
                                            const float* __restrict__ wfc1,
                                            const float* __restrict__ wfc2,
                                            ushort_t* __restrict__ o1,
                                            ushort_t* __restrict__ o2,
                                            ushort_t* __restrict__ o3,
                                            ushort_t* __restrict__ o4,
                                            const float* __restrict__ u2,
                                            const float* __restrict__ u3,
                                            u64* __restrict__ ub,
                                            const float* __restrict__ f2,
                                            const float* __restrict__ f3,
                                            ushort_t* __restrict__ srcb) {
    __shared__ float tl[64][65];
    int bid = blockIdx.x;
    int t = threadIdx.x;
    if (bid < 160) {
        int b = bid;
        const float* src; int S, rowb, n, ct, ht;
        if (b < 128) {
            n = b >> 6; int rem = b & 63; ct = rem >> 4; ht = rem & 15;
            src = f2; S = 1024; rowb = 0;
        } else {
            int b2 = b - 128;
            n = b2 >> 4; int rem = b2 & 15; ct = rem >> 2; ht = rem & 3;
            src = f3; S = 256; rowb = 2048;
        }
        int c0 = ct * 64, hw0 = ht * 64;
        int i = t >> 6, lane = t & 63;
#pragma unroll
        for (int jj = 0; jj < 16; ++jj) {
            int cl = i * 16 + jj;
            tl[lane][cl] = src[(size_t)(n * 256 + c0 + cl) * S + hw0 + lane];
        }
        __syncthreads();
#pragma unroll
        for (int jj = 0; jj < 16; ++jj) {
            int hl = i * 16 + jj;
            int row = rowb + n * S + hw0 + hl;
            srcb[(size_t)row * 256 + c0 + lane] = f2bf(tl[hl][lane]);
        }
    } else if (bid < 4160) {
        int idx = (bid - 160) * 256 + t;
        f32x4 v = (idx < 819200) ? ((const f32x4*)f0)[idx]
                                 : ((const f32x4*)f1)[idx - 819200];
        ((f32x4*)outp)[idx] = v;
    } else if (bid < 4928) {
        int i = (bid - 4160) * 256 + t;
        const float* src; ushort_t* dst; int li;
        if (i < 49152)       { src = wqkv; dst = o1; li = i; }
        else if (i < 65536)  { src = wo;   dst = o2; li = i - 49152; }
        else if (i < 131072) { src = wfc1; dst = o3; li = i - 65536; }
        else                 { src = wfc2; dst = o4; li = i - 131072; }
        f32x4 v = ((const f32x4*)src)[li];
        s16x4 r;
        r[0] = (short)f2bf(v[0]); r[1] = (short)f2bf(v[1]);
        r[2] = (short)f2bf(v[2]); r[3] = (short)f2bf(v[3]);
        ((s16x4*)dst)[li] = r;
    } else {
        int gw = ((bid - 4928) * 256 + t) >> 6;   // chunk 0..17407
        int lane = t & 63;
        const float* p;
        u64* dstLo;
        int q, kb, smask, sshift;
        if (gw < 16384) {
            int row = gw >> 3, ch = gw & 7;
            p = &u2[(size_t)row * 2048 + ch * 256 + lane * 4];
            dstLo = &ub[(size_t)gw * 4];
            q = row; kb = ch * 256 + lane * 4; smask = 1023; sshift = 10;
        } else {
            int lw = gw - 16384;
            int row = lw >> 1, ch = lw & 1;
            p = &u3[(size_t)row * 512 + ch * 256 + lane * 4];
            dstLo = &ub[65536 + (size_t)lw * 4];
            q = row; kb = ch * 256 + lane * 4; smask = 255; sshift = 8;
        }
        u64* dstHi = dstLo + HIPL;
        f32x4 v = *(const f32x4*)p;
        int qp = q & smask, qf = q >> sshift;
        u64 bl[4], bh[4];
#pragma unroll
        for (int j = 0; j < 4; ++j) {
            int k = kb + j;
            int val = (v[j] >= 0.1f ? 1 : 0)
                    + ((k & smask) == qp ? 1 : 0)
                    + ((k >> sshift) == qf ? 1 : 0);
            bl[j] = __ballot((val & 1) != 0);
            bh[j] = __ballot((val & 2) != 0);
        }
        if (lane < 4) {
            u64 x = (lane == 0) ? bl[0] : (lane == 1) ? bl[1]
                  : (lane == 2) ? bl[2] : bl[3];
            dstLo[lane] = x;
        } else if (lane < 8) {
            int j = lane - 4;
            u64 x = (j == 0) ? bh[0] : (j == 1) ? bh[1]
                  : (j == 2) ? bh[2] : bh[3];
            dstHi[j] = x;
        }
    }
}

#define ASTR 72

// ---------------------------------------------------------------------------
// bf16 MFMA GEMM, tile 64x64, 256 threads (4 waves). For qkv / fc1.
// EPI: 1=bias+relu, 3=bias then q-scale (n<256). Output bf16.
// ---------------------------------------------------------------------------
template <int EPI>
__global__ __launch_bounds__(256) void gemm64(const ushort_t* __restrict__ A,
                                              const ushort_t* __restrict__ W,
                                              const float* __restrict__ bias,
                                              ushort_t* __restrict__ outb,
                                              int M, int N, int K) {
    __shared__ __align__(16) ushort_t As[2][64 * ASTR];
    __shared__ __align__(16) ushort_t Ws[2][64 * ASTR];

    const int t = threadIdx.x;
    const int w = t >> 6, l = t & 63;
    const int c = l & 15, g = l >> 4;
    const int mh = w >> 1, nh = w & 1;
    const int m0 = blockIdx.y * 64, n0 = blockIdx.x * 64;
    const int srow = t >> 3;
    const int cg8 = (t & 7) * 8;

    const ushort_t* Aip0 = &A[(size_t)(m0 + srow) * K + cg8];
    const ushort_t* Aip1 = &A[(size_t)(m0 + 32 + srow) * K + cg8];
    const ushort_t* Wip0 = &W[(size_t)(n0 + srow) * K + cg8];
    const ushort_t* Wip1 = &W[(size_t)(n0 + 32 + srow) * K + cg8];

    s16x8 ra0 = *(const s16x8*)Aip0;
    s16x8 ra1 = *(const s16x8*)Aip1;
    s16x8 rw0 = *(const s16x8*)Wip0;
    s16x8 rw1 = *(const s16x8*)Wip1;
    *(s16x8*)&As[0][srow * ASTR + cg8] = ra0;
    *(s16x8*)&As[0][(32 + srow) * ASTR + cg8] = ra1;
    *(s16x8*)&Ws[0][srow * ASTR + cg8] = rw0;
    *(s16x8*)&Ws[0][(32 + srow) * ASTR + cg8] = rw1;
    __syncthreads();

    f32x4 acc[2][2] = {{{0.f,0.f,0.f,0.f},{0.f,0.f,0.f,0.f}},
                       {{0.f,0.f,0.f,0.f},{0.f,0.f,0.f,0.f}}};
    const int nsteps = K >> 6;

    for (int ks = 0; ks < nsteps; ++ks) {
        const int b = ks & 1;
        const bool pf = (ks + 1 < nsteps);
        if (pf) {
            int ko = (ks + 1) << 6;
            ra0 = *(const s16x8*)(Aip0 + ko);
            ra1 = *(const s16x8*)(Aip1 + ko);
            rw0 = *(const s16x8*)(Wip0 + ko);
            rw1 = *(const s16x8*)(Wip1 + ko);
        }
#pragma unroll
        for (int sl = 0; sl < 2; ++sl) {
            s16x8 af0 = *(const s16x8*)&As[b][(32 * mh + c) * ASTR + sl * 32 + 8 * g];
            s16x8 af1 = *(const s16x8*)&As[b][(32 * mh + 16 + c) * ASTR + sl * 32 + 8 * g];
            s16x8 wf0 = *(const s16x8*)&Ws[b][(32 * nh + c) * ASTR + sl * 32 + 8 * g];
            s16x8 wf1 = *(const s16x8*)&Ws[b][(32 * nh + 16 + c) * ASTR + sl * 32 + 8 * g];
            acc[0][0] = __builtin_amdgcn_mfma_f32_16x16x32_bf16(af0, wf0, acc[0][0], 0, 0, 0);
            acc[0][1] = __builtin_amdgcn_mfma_f32_16x16x32_bf16(af0, wf1, acc[0][1], 0, 0, 0);
            acc[1][0] = __builtin_amdgcn_mfma_f32_16x16x32_bf16(af1, wf0, acc[1][0], 0, 0, 0);
            acc[1][1] = __builtin_amdgcn_mfma_f32_16x16x32_bf16(af1, wf1, acc[1][1], 0, 0, 0);
        }
        if (pf) {
            int nb = b ^ 1;
            *(s16x8*)&As[nb][srow * ASTR + cg8] = ra0;
            *(s16x8*)&As[nb][(32 + srow) * ASTR + cg8] = ra1;
            *(s16x8*)&Ws[nb][srow * ASTR + cg8] = rw0;
            *(s16x8*)&Ws[nb][(32 + srow) * ASTR + cg8] = rw1;
        }
        __syncthreads();
    }

#pragma unroll
    for (int i = 0; i < 2; ++i)
#pragma unroll
    for (int j = 0; j < 2; ++j) {
        int n = n0 + 32 * nh + 16 * j + c;
        float bv = bias[n];
        float sc = 1.f;
        if (EPI == 3) sc = (n < 256) ? 0.17677669529663687f : 1.f;
#pragma unroll
        for (int r = 0; r < 4; ++r) {
            int m = m0 + 32 * mh + 16 * i + 4 * g + r;
            float v = acc[i][j][r] + bv;
            if (EPI == 1) v = fmaxf(v, 0.f);
            if (EPI == 3) v *= sc;
            outb[(size_t)m * N + n] = f2bf(v);
        }
    }
}

// ---------------------------------------------------------------------------
// bf16 MFMA GEMM, tile 32x32, 128 threads. fc2: K=1024, bf16 res, bf16 out.
// ---------------------------------------------------------------------------
__global__ __launch_bounds__(128) void gemm_fc2(const ushort_t* __restrict__ A,
                                                const ushort_t* __restrict__ W,
                                                const float* __restrict__ bias,
                                                const ushort_t* __restrict__ res,
                                                ushort_t* __restrict__ outb,
                                                int M, int N, int K) {
    __shared__ __align__(16) ushort_t As[2][32 * ASTR];
    __shared__ __align__(16) ushort_t Ws[2][32 * ASTR];

    const int t = threadIdx.x;
    const int w = t >> 6, l = t & 63;
    const int c = l & 15, g = l >> 4;
    const int m0 = blockIdx.y * 32, n0 = blockIdx.x * 32;
    const int srow = t >> 3;
    const int cg8 = (t & 7) * 8;

    const ushort_t* Aip0 = &A[(size_t)(m0 + srow) * K + cg8];
    const ushort_t* Aip1 = &A[(size_t)(m0 + 16 + srow) * K + cg8];
    const ushort_t* Wip0 = &W[(size_t)(n0 + srow) * K + cg8];
    const ushort_t* Wip1 = &W[(size_t)(n0 + 16 + srow) * K + cg8];

    s16x8 ra0 = *(const s16x8*)Aip0;
    s16x8 ra1 = *(const s16x8*)Aip1;
    s16x8 rw0 = *(const s16x8*)Wip0;
    s16x8 rw1 = *(const s16x8*)Wip1;
    *(s16x8*)&As[0][srow * ASTR + cg8] = ra0;
    *(s16x8*)&As[0][(16 + srow) * ASTR + cg8] = ra1;
    *(s16x8*)&Ws[0][srow * ASTR + cg8] = rw0;
    *(s16x8*)&Ws[0][(16 + srow) * ASTR + cg8] = rw1;
    __syncthreads();

    f32x4 acc[2] = {{0.f, 0.f, 0.f, 0.f}, {0.f, 0.f, 0.f, 0.f}};
    const int nsteps = K >> 6;

    for (int ks = 0; ks < nsteps; ++ks) {
        const int b = ks & 1;
        const bool pf = (ks + 1 < nsteps);
        if (pf) {
            int ko = (ks + 1) << 6;
            ra0 = *(const s16x8*)(Aip0 + ko);
            ra1 = *(const s16x8*)(Aip1 + ko);
            rw0 = *(const s16x8*)(Wip0 + ko);
            rw1 = *(const s16x8*)(Wip1 + ko);
        }
#pragma unroll
        for (int kt = 0; kt < 2; ++kt) {
            s16x8 af = *(const s16x8*)&As[b][(16 * w + c) * ASTR + kt * 32 + 8 * g];
            s16x8 wf0 = *(const s16x8*)&Ws[b][c * ASTR + kt * 32 + 8 * g];
            s16x8 wf1 = *(const s16x8*)&Ws[b][(16 + c) * ASTR + kt * 32 + 8 * g];
            acc[0] = __builtin_amdgcn_mfma_f32_16x16x32_bf16(af, wf0, acc[0], 0, 0, 0);
            acc[1] = __builtin_amdgcn_mfma_f32_16x16x32_bf16(af, wf1, acc[1], 0, 0, 0);
        }
        if (pf) {
            int nb = b ^ 1;
            *(s16x8*)&As[nb][srow * ASTR + cg8] = ra0;
            *(s16x8*)&As[nb][(16 + srow) * ASTR + cg8] = ra1;
            *(s16x8*)&Ws[nb][srow * ASTR + cg8] = rw0;
            *(s16x8*)&Ws[nb][(16 + srow) * ASTR + cg8] = rw1;
        }
        __syncthreads();
    }

#pragma unroll
    for (int nt = 0; nt < 2; ++nt) {
        int n = n0 + 16 * nt + c;
        float bv = bias[n];
#pragma unroll
        for (int r = 0; r < 4; ++r) {
            int m = m0 + 16 * w + 4 * g + r;
            float v = acc[nt][r] + bv + bf2f(res[(size_t)m * N + n]);
            outb[(size_t)m * N + n] = f2bf(v);
        }
    }
}

// ---------------------------------------------------------------------------
// Wo GEMM with fused 4-split merge. Tile 32x32, 128 threads. bf16 res/out.
// ---------------------------------------------------------------------------
__global__ __launch_bounds__(128) void gemm_wo(const ushort_t* __restrict__ Opart,
                                               const float2* __restrict__ ml,
                                               const ushort_t* __restrict__ W,
                                               const float* __restrict__ bias,
                                               const ushort_t* __restrict__ res,
                                               ushort_t* __restrict__ outb) {
    const int K = 256, N = 256;
    __shared__ __align__(16) ushort_t As[2][32 * ASTR];
    __shared__ __align__(16) ushort_t Ws[2][32 * ASTR];

    const int t = threadIdx.x;
    const int w = t >> 6, l = t & 63;
    const int c = l & 15, g = l >> 4;
    const int m0 = blockIdx.y * 32, n0 = blockIdx.x * 32;
    const int srow = t >> 3;
    const int cg8 = (t & 7) * 8;

    auto loadA = [&](int row, int kcol) -> s16x8 {
        int head = kcol >> 5;
        float2 a0 = ml[((size_t)0 * RTOT + row) * 8 + head];
        float2 a1 = ml[((size_t)1 * RTOT + row) * 8 + head];
        float2 a2 = ml[((size_t)2 * RTOT + row) * 8 + head];
        float2 a3 = ml[((size_t)3 * RTOT + row) * 8 + head];
        float M = fmaxf(fmaxf(a0.x, a1.x), fmaxf(a2.x, a3.x));
        float w1 = __expf(a0.x - M), w2 = __expf(a1.x - M);
        float w3 = __expf(a2.x - M), w4 = __expf(a3.x - M);
        float inv = 1.f / (w1 * a0.y + w2 * a1.y + w3 * a2.y + w4 * a3.y);
        const size_t str = (size_t)RTOT * 256;
        size_t base = (size_t)row * 256 + kcol;
        s16x8 o1 = *(const s16x8*)&Opart[base];
        s16x8 o2 = *(const s16x8*)&Opart[base + str];
        s16x8 o3 = *(const s16x8*)&Opart[base + 2 * str];
        s16x8 o4 = *(const s16x8*)&Opart[base + 3 * str];
        s16x8 r;
#pragma unroll
        for (int e = 0; e < 8; ++e) {
            float v = w1 * bf2f((ushort_t)o1[e]) + w2 * bf2f((ushort_t)o2[e])
                    + w3 * bf2f((ushort_t)o3[e]) + w4 * bf2f((ushort_t)o4[e]);
            r[e] = (short)f2bf(v * inv);
        }
        return r;
    };

    const ushort_t* Wip0 = &W[(size_t)(n0 + srow) * K + cg8];
    const ushort_t* Wip1 = &W[(size_t)(n0 + 16 + srow) * K + cg8];

    s16x8 ra0 = loadA(m0 + srow, cg8);
    s16x8 ra1 = loadA(m0 + 16 + srow, cg8);
    s16x8 rw0 = *(const s16x8*)Wip0;
    s16x8 rw1 = *(const s16x8*)Wip1;
    *(s16x8*)&As[0][srow * ASTR + cg8] = ra0;
    *(s16x8*)&As[0][(16 + srow) * ASTR + cg8] = ra1;
    *(s16x8*)&Ws[0][srow * ASTR + cg8] = rw0;
    *(s16x8*)&Ws[0][(16 + srow) * ASTR + cg8] = rw1;
    __syncthreads();

    f32x4 acc[2] = {{0.f, 0.f, 0.f, 0.f}, {0.f, 0.f, 0.f, 0.f}};
    const int nsteps = 4;

    for (int ks = 0; ks < nsteps; ++ks) {
        const int b = ks & 1;
        const bool pf = (ks + 1 < nsteps);
        if (pf) {
            int ko = (ks + 1) << 6;
            ra0 = loadA(m0 + srow, ko + cg8);
            ra1 = loadA(m0 + 16 + srow, ko + cg8);
            rw0 = *(const s16x8*)(Wip0 + ko);
            rw1 = *(const s16x8*)(Wip1 + ko);
        }
#pragma unroll
        for (int kt = 0; kt < 2; ++kt) {
            s16x8 af = *(const s16x8*)&As[b][(16 * w + c) * ASTR + kt * 32 + 8 * g];
            s16x8 wf0 = *(const s16x8*)&Ws[b][c * ASTR + kt * 32 + 8 * g];
            s16x8 wf1 = *(const s16x8*)&Ws[b][(16 + c) * ASTR + kt * 32 + 8 * g];
            acc[0] = __builtin_amdgcn_mfma_f32_16x16x32_bf16(af, wf0, acc[0], 0, 0, 0);
            acc[1] = __builtin_amdgcn_mfma_f32_16x16x32_bf16(af, wf1, acc[1], 0, 0, 0);
        }
        if (pf) {
            int nb = b ^ 1;
            *(s16x8*)&As[nb][srow * ASTR + cg8] = ra0;
            *(s16x8*)&As[nb][(16 + srow) * ASTR + cg8] = ra1;
            *(s16x8*)&Ws[nb][srow * ASTR + cg8] = rw0;
            *(s16x8*)&Ws[nb][(16 + srow) * ASTR + cg8] = rw1;
        }
        __syncthreads();
    }

#pragma unroll
    for (int nt = 0; nt < 2; ++nt) {
        int n = n0 + 16 * nt + c;
        float bv = bias[n];
#pragma unroll
        for (int r = 0; r < 4; ++r) {
            int m = m0 + 16 * w + 4 * g + r;
            float v = acc[nt][r] + bv + bf2f(res[(size_t)m * 256 + n]);
            outb[(size_t)m * 256 + n] = f2bf(v);
        }
    }
}

// ---------------------------------------------------------------------------
// Split-KV MFMA flash attention (R18 form: reg-direct Q, double-buffered K/V,
// one barrier/tile, bitplane mask, setprio, defer-max + lazy sum).
// lvl2: blocks 0..1023  = qt(32) x h(8) x split(4), tps=8
// lvl3: blocks 1024..1279 = qt(8) x h(8) x split(4), tps=2
// ---------------------------------------------------------------------------
#define KS 40
#define VS 66
#define PS 72
#define OS 68

__global__ __launch_bounds__(256) void flash_split(const ushort_t* __restrict__ qkvb,
                                                   const u64* __restrict__ ubits,
                                                   ushort_t* __restrict__ Opart,
                                                   float2* __restrict__ ml) {
    __shared__ __align__(16) ushort_t ks[2][64 * KS];
    __shared__ __align__(16) ushort_t vts[2][32 * VS];
    __shared__ __align__(16) char pso[64 * PS * 2];
    ushort_t* ps = (ushort_t*)pso;
    float* os = (float*)pso;

    const int bx = blockIdx.x;
    int qt, h, split, L, rowbase;
    const u64* ub;
    if (bx < 1024) {
        qt = bx & 31; h = (bx >> 5) & 7; split = bx >> 8;
        L = 2048; rowbase = 0; ub = ubits;
    } else {
        int lo = bx - 1024;
        qt = lo & 7; h = (lo >> 3) & 7; split = lo >> 6;
        L = 512; rowbase = 2048; ub = ubits + 65536;
    }
    const int tps = (L >> 6) >> 2;
    const int ts0 = split * tps;
    const int nch = L >> 8;

    const int t = threadIdx.x;
    const int w = t >> 6;
    const int l = t & 63;
    const int c = l & 15;
    const int g = l >> 4;

    const int srow = t >> 2;
    const int sc8 = (t & 3) * 8;
    const int q0g = rowbase + qt * 64;

    const int ql = qt * 64 + 16 * w + c;
    const s16x8 qf = *(const s16x8*)&qkvb[(size_t)(rowbase + ql) * 768 + h * 32 + 8 * g];
    const u64* ubq = &ub[(size_t)ql * nch * 4];

    s16x8 kreg, vreg;
    {
        size_t base = (size_t)(rowbase + ts0 * 64 + srow) * 768 + h * 32 + sc8;
        s16x8 k0r = *(const s16x8*)&qkvb[base + 256];
        s16x8 v0r = *(const s16x8*)&qkvb[base + 512];
        *(s16x8*)&ks[0][srow * KS + sc8] = k0r;
#pragma unroll
        for (int i = 0; i < 8; ++i)
            vts[0][(sc8 + i) * VS + srow] = (ushort_t)v0r[i];
        if (tps > 1) {
            kreg = *(const s16x8*)&qkvb[base + 64 * 768 + 256];
            vreg = *(const s16x8*)&qkvb[base + 64 * 768 + 512];
        }
    }
    __syncthreads();

    f32x4 oacc0 = {0.f, 0.f, 0.f, 0.f};
    f32x4 oacc1 = {0.f, 0.f, 0.f, 0.f};
    float mold = -3e38f;
    float lsum = 0.f;
    const f32x4 zc = {0.f, 0.f, 0.f, 0.f};

    u64 wl0 = 0, wl1 = 0, wl2 = 0, wl3 = 0;
    u64 wh0 = 0, wh1 = 0, wh2 = 0, wh3 = 0;
    int cur = 0;
    for (int kt = 0; kt < tps; ++kt) {
        const int nxt = cur ^ 1;
        const int gt = ts0 + kt;

        if (kt + 1 < tps) {
            *(s16x8*)&ks[nxt][srow * KS + sc8] = kreg;
#pragma unroll
            for (int i = 0; i < 8; ++i)
                vts[nxt][(sc8 + i) * VS + srow] = (ushort_t)vreg[i];
        }
        if (kt + 2 < tps) {
            size_t base = (size_t)(rowbase + (gt + 2) * 64 + srow) * 768 + h * 32 + sc8;
            kreg = *(const s16x8*)&qkvb[base + 256];
            vreg = *(const s16x8*)&qkvb[base + 512];
        }

        if ((gt & 3) == 0 || kt == 0) {
            const u64* bp = &ubq[(size_t)(gt >> 2) * 4];
            wl0 = bp[0]; wl1 = bp[1]; wl2 = bp[2]; wl3 = bp[3];
            wh0 = bp[HIPL]; wh1 = bp[HIPL + 1]; wh2 = bp[HIPL + 2]; wh3 = bp[HIPL + 3];
        }
        const unsigned shb = 16 * (gt & 3);

        f32x4 sacc[4];
        __builtin_amdgcn_s_setprio(1);
#pragma unroll
        for (int nt = 0; nt < 4; ++nt) {
            s16x8 kf = *(const s16x8*)&ks[cur][(16 * nt + c) * KS + 8 * g];
            sacc[nt] = __builtin_amdgcn_mfma_f32_16x16x32_bf16(kf, qf, zc, 0, 0, 0);
        }
        __builtin_amdgcn_s_setprio(0);

        float sv[4][4];
        float pmax = -3e38f;
#pragma unroll
        for (int nt = 0; nt < 4; ++nt) {
            unsigned sh = shb + 4 * nt + g;
#pragma unroll
            for (int r = 0; r < 4; ++r) {
                u64 wl = (r == 0) ? wl0 : (r == 1) ? wl1 : (r == 2) ? wl2 : wl3;
                u64 wh = (r == 0) ? wh0 : (r == 1) ? wh1 : (r == 2) ? wh2 : wh3;
                unsigned lo = (unsigned)(wl >> sh) & 1u;
                unsigned hi = (unsigned)(wh >> sh) & 1u;
                float s = sacc[nt][r] + (float)(lo + 2u * hi);
                sv[nt][r] = s;
                pmax = fmaxf(pmax, s);
            }
        }
        if (!__all(pmax <= mold + 8.f)) {
            float m = pmax;
            m = fmaxf(m, __shfl_xor(m, 16));
            m = fmaxf(m, __shfl_xor(m, 32));
            float newm = fmaxf(mold, m);
            float fac = __expf(mold - newm);
            mold = newm;
            lsum *= fac;
            oacc0 *= fac;
            oacc1 *= fac;
        }

        float sum = 0.f;
#pragma unroll
        for (int nt = 0; nt < 4; ++nt) {
            float p0 = __expf(sv[nt][0] - mold);
            float p1 = __expf(sv[nt][1] - mold);
            float p2 = __expf(sv[nt][2] - mold);
            float p3 = __expf(sv[nt][3] - mold);
            sum += (p0 + p1) + (p2 + p3);
            u32x2 pk;
            pk[0] = ((unsigned)f2bf(p1) << 16) | f2bf(p0);
            pk[1] = ((unsigned)f2bf(p3) << 16) | f2bf(p2);
            *(u32x2*)&ps[(16 * w + c) * PS + 16 * nt + 4 * g] = pk;
        }
        lsum += sum;

        __builtin_amdgcn_s_setprio(1);
#pragma unroll
        for (int kc = 0; kc < 2; ++kc) {
            s16x8 pfr = *(const s16x8*)&ps[(16 * w + c) * PS + 32 * kc + 8 * g];
            s16x8 vf0 = *(const s16x8*)&vts[cur][c * VS + 32 * kc + 8 * g];
            s16x8 vf1 = *(const s16x8*)&vts[cur][(16 + c) * VS + 32 * kc + 8 * g];
            oacc0 = __builtin_amdgcn_mfma_f32_16x16x32_bf16(vf0, pfr, oacc0, 0, 0, 0);
            oacc1 = __builtin_amdgcn_mfma_f32_16x16x32_bf16(vf1, pfr, oacc1, 0, 0, 0);
        }
        __builtin_amdgcn_s_setprio(0);

        __syncthreads();
        cur = nxt;
    }

    float lrun = lsum;
    lrun += __shfl_xor(lrun, 16);
    lrun += __shfl_xor(lrun, 32);

    if (g == 0) {
        int q = q0g + 16 * w + c;
        ml[((size_t)split * RTOT + q) * 8 + h] = make_float2(mold, lrun);
    }

#pragma unroll
    for (int r = 0; r < 4; ++r) {
        os[(4 * g + r) * OS + 16 * w + c] = oacc0[r];
        os[(16 + 4 * g + r) * OS + 16 * w + c] = oacc1[r];
    }
    __syncthreads();
    {
        int r = t >> 2, d0 = (t & 3) * 8;
        s16x8 pk;
#pragma unroll
        for (int i = 0; i < 8; ++i) pk[i] = (short)f2bf(os[(d0 + i) * OS + r]);
        *(s16x8*)&Opart[((size_t)split * RTOT + q0g + r) * 256 + h * 32 + d0] = pk;
    }
}

// LayerNorm over C=256 (bf16 in), one block per row; writes bf16
__global__ __launch_bounds__(256) void ln1_kernel(const ushort_t* __restrict__ in,
                                                  const float* __restrict__ g,
                                                  const float* __restrict__ b,
                                                  ushort_t* __restrict__ outb) {
    __shared__ float red[256];
    int row = blockIdx.x, t = threadIdx.x;
    size_t idx = (size_t)row * 256 + t;
    float v = bf2f(in[idx]);
    red[t] = v;
    __syncthreads();
    for (int s = 128; s > 0; s >>= 1) {
        if (t < s) red[t] += red[t + s];
        __syncthreads();
    }
    float mean = red[0] * (1.f / 256.f);
    __syncthreads();
    float d = v - mean;
    red[t] = d * d;
    __syncthreads();
    for (int s = 128; s > 0; s >>= 1) {
        if (t < s) red[t] += red[t + s];
        __syncthreads();
    }
    float var = red[0] * (1.f / 256.f);
    float r = d * rsqrtf(var + 1e-5f) * g[t] + b[t];
    outb[idx] = f2bf(r);
}

// LayerNorm (bf16 in) + NCHW scatter to the two output tensors
__global__ __launch_bounds__(256) void ln2_out(const ushort_t* __restrict__ in,
                                               const float* __restrict__ g,
                                               const float* __restrict__ b,
                                               float* __restrict__ out2,
                                               float* __restrict__ out3) {
    __shared__ float red[256];
    int row = blockIdx.x, t = threadIdx.x;
    size_t idx = (size_t)row * 256 + t;
    float v = bf2f(in[idx]);
    red[t] = v;
    __syncthreads();
    for (int s = 128; s > 0; s >>= 1) {
        if (t < s) red[t] += red[t + s];
        __syncthreads();
    }
    float mean = red[0] * (1.f / 256.f);
    __syncthreads();
    float d = v - mean;
    red[t] = d * d;
    __syncthreads();
    for (int s = 128; s > 0; s >>= 1) {
        if (t < s) red[t] += red[t + s];
        __syncthreads();
    }
    float var = red[0] * (1.f / 256.f);
    float r = d * rsqrtf(var + 1e-5f) * g[t] + b[t];
    if (row < 2048) {
        int n = row >> 10, hw = row & 1023;
        out2[((size_t)(n * 256 + t) << 10) + hw] = r;
    } else {
        int rl = row - 2048;
        int n = rl >> 8, hw = rl & 255;
        out3[((size_t)(n * 256 + t) << 8) + hw] = r;
    }
}

// ---------------------------------------------------------------------------

extern "C" void kernel_launch(void* const* d_in, const int* in_sizes, int n_in,
                              void* d_out, int out_size, void* d_ws, size_t ws_size,
                              hipStream_t stream) {
    const float* f0 = (const float*)d_in[0];
    const float* f1 = (const float*)d_in[1];
    const float* f2 = (const float*)d_in[2];
    const float* f3 = (const float*)d_in[3];
    const float* u2 = (const float*)d_in[4];
    const float* u3 = (const float*)d_in[5];
    const float* Wqkv = (const float*)d_in[6];
    const float* bqkv = (const float*)d_in[7];
    const float* Wo   = (const float*)d_in[8];
    const float* bo   = (const float*)d_in[9];
    const float* g1   = (const float*)d_in[10];
    const float* b1   = (const float*)d_in[11];
    const float* Wfc1 = (const float*)d_in[12];
    const float* bfc1 = (const float*)d_in[13];
    const float* Wfc2 = (const float*)d_in[14];
    const float* bfc2 = (const float*)d_in[15];
    const float* g2   = (const float*)d_in[16];
    const float* b2   = (const float*)d_in[17];

    float* out = (float*)d_out;
    float* ws = (float*)d_ws;

    // bf16 weights
    ushort_t* wqkv = (ushort_t*)ws;             // 196608 us
    ushort_t* wo   = (ushort_t*)(ws + 98304);   // 65536 us
    ushort_t* wfc1 = (ushort_t*)(ws + 131072);  // 262144 us
    ushort_t* wfc2 = (ushort_t*)(ws + 262144);  // 262144 us

    // scratch (floats), all intermediates bf16
    float* sc = ws + 393216;
    ushort_t* src_bf = (ushort_t*)sc;                // 655360 us -> f 327680
    ushort_t* qkvb   = (ushort_t*)(sc + 327680);     // 2560*768 us -> f 1310720
    ushort_t* t1b    = (ushort_t*)(sc + 1310720);    // 655360 us -> f 1638400
    ushort_t* x_bf   = (ushort_t*)(sc + 1638400);    // -> f 1966080
    ushort_t* t2b    = (ushort_t*)(sc + 1966080);    // -> f 2293760
    u64*      ubits  = (u64*)(sc + 2293760);         // 2*69632 u64 -> f 2572288
    float2*   ml     = (float2*)(sc + 2572288);      // 4*2560*8 f2 -> f 2736128
    ushort_t* Opart  = (ushort_t*)(sc + 2736128);    // 4*2560*256 us -> f 4046848
    ushort_t* h_bf   = Opart;                        // alias post-wo

    prep<<<9280, 256, 0, stream>>>(f0, f1, out,
                                   Wqkv, Wo, Wfc1, Wfc2, wqkv, wo, wfc1, wfc2,
                                   u2, u3, ubits, f2, f3, src_bf);

    gemm64<3><<<dim3(12, 40), 256, 0, stream>>>(
        src_bf, wqkv, bqkv, qkvb, RTOT, 768, 256);
    flash_split<<<1280, 256, 0, stream>>>(qkvb, ubits, Opart, ml);
    gemm_wo<<<dim3(8, 80), 128, 0, stream>>>(Opart, ml, wo, bo, src_bf, t1b);
    ln1_kernel<<<2560, 256, 0, stream>>>(t1b, g1, b1, x_bf);
    gemm64<1><<<dim3(16, 40), 256, 0, stream>>>(
        x_bf, wfc1, bfc1, h_bf, RTOT, 1024, 256);
    gemm_fc2<<<dim3(8, 80), 128, 0, stream>>>(
        h_bf, wfc2, bfc2, x_bf, t2b, RTOT, 256, 1024);
    ln2_out<<<2560, 256, 0, stream>>>(t2b, g2, b2, out + 4096000, out + 4620288);
}

// Round 21
// 82.099 us; speedup vs baseline: 1.1186x; 1.0518x over previous
//
#include <hip/hip_runtime.h>
#include <hip/hip_bf16.h>
#include <cstddef>
#include <cmath>

// ---------------------------------------------------------------------------
// sparse_attn: transformer encoder block on levels 2 & 3.
// Round 21 (= R20 fixed): coalesced LDS-tiled LN2 scatter + wave-per-row LNs +
// exp2-domain softmax (plain exp2f -> native v_exp_f32).
// Rows 0..2047 = level2 (S=1024), 2048..2559 = level3 (S=256). R=2560.
// ---------------------------------------------------------------------------

typedef __attribute__((ext_vector_type(8))) short s16x8;
typedef __attribute__((ext_vector_type(4))) short s16x4;
typedef __attribute__((ext_vector_type(4))) float f32x4;
typedef __attribute__((ext_vector_type(2))) unsigned int u32x2;
typedef unsigned short ushort_t;
typedef unsigned long long u64;

#define RTOT 2560
#define HIPL 69632   // u64 offset of the hi bitplane
#define LOG2E 1.4426950408889634f

__device__ inline unsigned short f2bf(float x) {
    union { __hip_bfloat16 h; unsigned short u; } cv;
    cv.h = __float2bfloat16(x);
    return cv.u;
}
__device__ inline float bf2f(unsigned short u) {
    union { unsigned int i; float f; } cv;
    cv.i = ((unsigned int)u) << 16;
    return cv.f;
}
__device__ inline float fexp2(float x) { return exp2f(x); }

// ---------------------------------------------------------------------------
// prep (9280 blocks):
//   0..159     : f2/f3 NCHW -> [2560,256] bf16 (64x64 LDS tile, first)
//   160..4159  : f0/f1 pass-through copy (f32x4)
//   4160..4927 : weights fp32->bf16
//   4928..9279 : mask VALUE planes (0..3): lo bits ub[..], hi bits ub[HIPL+..]
// ---------------------------------------------------------------------------
__global__ __launch_bounds__(256) void prep(const float* __restrict__ f0,
                                            const float* __restrict__ f1,
                                            float* __restrict__ outp,
                                            const float* __restrict__ wqkv,
                                            const float* __restrict__ wo,
                                            const float* __restrict__ wfc1,
                                            const float* __restrict__ wfc2,
                                            ushort_t* __restrict__ o1,
                                            ushort_t* __restrict__ o2,
                                            ushort_t* __restrict__ o3,
                                            ushort_t* __restrict__ o4,
                                            const float* __restrict__ u2,
                                            const float* __restrict__ u3,
                                            u64* __restrict__ ub,
                                            const float* __restrict__ f2,
                                            const float* __restrict__ f3,
                                            ushort_t* __restrict__ srcb) {
    __shared__ float tl[64][65];
    int bid = blockIdx.x;
    int t = threadIdx.x;
    if (bid < 160) {
        int b = bid;
        const float* src; int S, rowb, n, ct, ht;
        if (b < 128) {
            n = b >> 6; int rem = b & 63; ct = rem >> 4; ht = rem & 15;
            src = f2; S = 1024; rowb = 0;
        } else {
            int b2 = b - 128;
            n = b2 >> 4; int rem = b2 & 15; ct = rem >> 2; ht = rem & 3;
            src = f3; S = 256; rowb = 2048;
        }
        int c0 = ct * 64, hw0 = ht * 64;
        int i = t >> 6, lane = t & 63;
#pragma unroll
        for (int jj = 0; jj < 16; ++jj) {
            int cl = i * 16 + jj;
            tl[lane][cl] = src[(size_t)(n * 256 + c0 + cl) * S + hw0 + lane];
        }
        __syncthreads();
#pragma unroll
        for (int jj = 0; jj < 16; ++jj) {
            int hl = i * 16 + jj;
            int row = rowb + n * S + hw0 + hl;
            srcb[(size_t)row * 256 + c0 + lane] = f2bf(tl[hl][lane]);
        }
    } else if (bid < 4160) {
        int idx = (bid - 160) * 256 + t;
        f32x4 v = (idx < 819200) ? ((const f32x4*)f0)[idx]
                                 : ((const f32x4*)f1)[idx - 819200];
        ((f32x4*)outp)[idx] = v;
    } else if (bid < 4928) {
        int i = (bid - 4160) * 256 + t;
        const float* src; ushort_t* dst; int li;
        if (i < 49152)       { src = wqkv; dst = o1; li = i; }
        else if (i < 65536)  { src = wo;   dst = o2; li = i - 49152; }
        else if (i < 131072) { src = wfc1; dst = o3; li = i - 65536; }
        else                 { src = wfc2; dst = o4; li = i - 131072; }
        f32x4 v = ((const f32x4*)src)[li];
        s16x4 r;
        r[0] = (short)f2bf(v[0]); r[1] = (short)f2bf(v[1]);
        r[2] = (short)f2bf(v[2]); r[3] = (short)f2bf(v[3]);
        ((s16x4*)dst)[li] = r;
    } else {
        int gw = ((bid - 4928) * 256 + t) >> 6;   // chunk 0..17407
        int lane = t & 63;
        const float* p;
        u64* dstLo;
        int q, kb, smask, sshift;
        if (gw < 16384) {
            int row = gw >> 3, ch = gw & 7;
            p = &u2[(size_t)row * 2048 + ch * 256 + lane * 4];
            dstLo = &ub[(size_t)gw * 4];
            q = row; kb = ch * 256 + lane * 4; smask = 1023; sshift = 10;
        } else {
            int lw = gw - 16384;
            int row = lw >> 1, ch = lw & 1;
            p = &u3[(size_t)row * 512 + ch * 256 + lane * 4];
            dstLo = &ub[65536 + (size_t)lw * 4];
            q = row; kb = ch * 256 + lane * 4; smask = 255; sshift = 8;
        }
        u64* dstHi = dstLo + HIPL;
        f32x4 v = *(const f32x4*)p;
        int qp = q & smask, qf = q >> sshift;
        u64 bl[4], bh[4];
#pragma unroll
        for (int j = 0; j < 4; ++j) {
            int k = kb + j;
            int val = (v[j] >= 0.1f ? 1 : 0)
                    + ((k & smask) == qp ? 1 : 0)
                    + ((k >> sshift) == qf ? 1 : 0);
            bl[j] = __ballot((val & 1) != 0);
            bh[j] = __ballot((val & 2) != 0);
        }
        if (lane < 4) {
            u64 x = (lane == 0) ? bl[0] : (lane == 1) ? bl[1]
                  : (lane == 2) ? bl[2] : bl[3];
            dstLo[lane] = x;
        } else if (lane < 8) {
            int j = lane - 4;
            u64 x = (j == 0) ? bh[0] : (j == 1) ? bh[1]
                  : (j == 2) ? bh[2] : bh[3];
            dstHi[j] = x;
        }
    }
}

#define ASTR 72

// ---------------------------------------------------------------------------
// bf16 MFMA GEMM, tile 64x64, 256 threads (4 waves). For qkv / fc1.
// EPI: 1=bias+relu, 3=bias then q-scale-log2e (n<256). Output bf16.
// ---------------------------------------------------------------------------
template <int EPI>
__global__ __launch_bounds__(256) void gemm64(const ushort_t* __restrict__ A,
                                              const ushort_t* __restrict__ W,
                                              const float* __restrict__ bias,
                                              ushort_t* __restrict__ outb,
                                              int M, int N, int K) {
    __shared__ __align__(16) ushort_t As[2][64 * ASTR];
    __shared__ __align__(16) ushort_t Ws[2][64 * ASTR];

    const int t = threadIdx.x;
    const int w = t >> 6, l = t & 63;
    const int c = l & 15, g = l >> 4;
    const int mh = w >> 1, nh = w & 1;
    const int m0 = blockIdx.y * 64, n0 = blockIdx.x * 64;
    const int srow = t >> 3;
    const int cg8 = (t & 7) * 8;

    const ushort_t* Aip0 = &A[(size_t)(m0 + srow) * K + cg8];
    const ushort_t* Aip1 = &A[(size_t)(m0 + 32 + srow) * K + cg8];
    const ushort_t* Wip0 = &W[(size_t)(n0 + srow) * K + cg8];
    const ushort_t* Wip1 = &W[(size_t)(n0 + 32 + srow) * K + cg8];

    s16x8 ra0 = *(const s16x8*)Aip0;
    s16x8 ra1 = *(const s16x8*)Aip1;
    s16x8 rw0 = *(const s16x8*)Wip0;
    s16x8 rw1 = *(const s16x8*)Wip1;
    *(s16x8*)&As[0][srow * ASTR + cg8] = ra0;
    *(s16x8*)&As[0][(32 + srow) * ASTR + cg8] = ra1;
    *(s16x8*)&Ws[0][srow * ASTR + cg8] = rw0;
    *(s16x8*)&Ws[0][(32 + srow) * ASTR + cg8] = rw1;
    __syncthreads();

    f32x4 acc[2][2] = {{{0.f,0.f,0.f,0.f},{0.f,0.f,0.f,0.f}},
                       {{0.f,0.f,0.f,0.f},{0.f,0.f,0.f,0.f}}};
    const int nsteps = K >> 6;

    for (int ks = 0; ks < nsteps; ++ks) {
        const int b = ks & 1;
        const bool pf = (ks + 1 < nsteps);
        if (pf) {
            int ko = (ks + 1) << 6;
            ra0 = *(const s16x8*)(Aip0 + ko);
            ra1 = *(const s16x8*)(Aip1 + ko);
            rw0 = *(const s16x8*)(Wip0 + ko);
            rw1 = *(const s16x8*)(Wip1 + ko);
        }
#pragma unroll
        for (int sl = 0; sl < 2; ++sl) {
            s16x8 af0 = *(const s16x8*)&As[b][(32 * mh + c) * ASTR + sl * 32 + 8 * g];
            s16x8 af1 = *(const s16x8*)&As[b][(32 * mh + 16 + c) * ASTR + sl * 32 + 8 * g];
            s16x8 wf0 = *(const s16x8*)&Ws[b][(32 * nh + c) * ASTR + sl * 32 + 8 * g];
            s16x8 wf1 = *(const s16x8*)&Ws[b][(32 * nh + 16 + c) * ASTR + sl * 32 + 8 * g];
            acc[0][0] = __builtin_amdgcn_mfma_f32_16x16x32_bf16(af0, wf0, acc[0][0], 0, 0, 0);
            acc[0][1] = __builtin_amdgcn_mfma_f32_16x16x32_bf16(af0, wf1, acc[0][1], 0, 0, 0);
            acc[1][0] = __builtin_amdgcn_mfma_f32_16x16x32_bf16(af1, wf0, acc[1][0], 0, 0, 0);
            acc[1][1] = __builtin_amdgcn_mfma_f32_16x16x32_bf16(af1, wf1, acc[1][1], 0, 0, 0);
        }
        if (pf) {
            int nb = b ^ 1;
            *(s16x8*)&As[nb][srow * ASTR + cg8] = ra0;
            *(s16x8*)&As[nb][(32 + srow) * ASTR + cg8] = ra1;
            *(s16x8*)&Ws[nb][srow * ASTR + cg8] = rw0;
            *(s16x8*)&Ws[nb][(32 + srow) * ASTR + cg8] = rw1;
        }
        __syncthreads();
    }

#pragma unroll
    for (int i = 0; i < 2; ++i)
#pragma unroll
    for (int j = 0; j < 2; ++j) {
        int n = n0 + 32 * nh + 16 * j + c;
        float bv = bias[n];
        float sc = 1.f;
        if (EPI == 3) sc = (n < 256) ? 0.17677669529663687f * LOG2E : 1.f;
#pragma unroll
        for (int r = 0; r < 4; ++r) {
            int m = m0 + 32 * mh + 16 * i + 4 * g + r;
            float v = acc[i][j][r] + bv;
            if (EPI == 1) v = fmaxf(v, 0.f);
            if (EPI == 3) v *= sc;
            outb[(size_t)m * N + n] = f2bf(v);
        }
    }
}

// ---------------------------------------------------------------------------
// bf16 MFMA GEMM, tile 32x32, 128 threads. fc2: K=1024, bf16 res, bf16 out.
// ---------------------------------------------------------------------------
__global__ __launch_bounds__(128) void gemm_fc2(const ushort_t* __restrict__ A,
                                                const ushort_t* __restrict__ W,
                                                const float* __restrict__ bias,
                                                const ushort_t* __restrict__ res,
                                                ushort_t* __restrict__ outb,
                                                int M, int N, int K) {
    __shared__ __align__(16) ushort_t As[2][32 * ASTR];
    __shared__ __align__(16) ushort_t Ws[2][32 * ASTR];

    const int t = threadIdx.x;
    const int w = t >> 6, l = t & 63;
    const int c = l & 15, g = l >> 4;
    const int m0 = blockIdx.y * 32, n0 = blockIdx.x * 32;
    const int srow = t >> 3;
    const int cg8 = (t & 7) * 8;

    const ushort_t* Aip0 = &A[(size_t)(m0 + srow) * K + cg8];
    const ushort_t* Aip1 = &A[(size_t)(m0 + 16 + srow) * K + cg8];
    const ushort_t* Wip0 = &W[(size_t)(n0 + srow) * K + cg8];
    const ushort_t* Wip1 = &W[(size_t)(n0 + 16 + srow) * K + cg8];

    s16x8 ra0 = *(const s16x8*)Aip0;
    s16x8 ra1 = *(const s16x8*)Aip1;
    s16x8 rw0 = *(const s16x8*)Wip0;
    s16x8 rw1 = *(const s16x8*)Wip1;
    *(s16x8*)&As[0][srow * ASTR + cg8] = ra0;
    *(s16x8*)&As[0][(16 + srow) * ASTR + cg8] = ra1;
    *(s16x8*)&Ws[0][srow * ASTR + cg8] = rw0;
    *(s16x8*)&Ws[0][(16 + srow) * ASTR + cg8] = rw1;
    __syncthreads();

    f32x4 acc[2] = {{0.f, 0.f, 0.f, 0.f}, {0.f, 0.f, 0.f, 0.f}};
    const int nsteps = K >> 6;

    for (int ks = 0; ks < nsteps; ++ks) {
        const int b = ks & 1;
        const bool pf = (ks + 1 < nsteps);
        if (pf) {
            int ko = (ks + 1) << 6;
            ra0 = *(const s16x8*)(Aip0 + ko);
            ra1 = *(const s16x8*)(Aip1 + ko);
            rw0 = *(const s16x8*)(Wip0 + ko);
            rw1 = *(const s16x8*)(Wip1 + ko);
        }
#pragma unroll
        for (int kt = 0; kt < 2; ++kt) {
            s16x8 af = *(const s16x8*)&As[b][(16 * w + c) * ASTR + kt * 32 + 8 * g];
            s16x8 wf0 = *(const s16x8*)&Ws[b][c * ASTR + kt * 32 + 8 * g];
            s16x8 wf1 = *(const s16x8*)&Ws[b][(16 + c) * ASTR + kt * 32 + 8 * g];
            acc[0] = __builtin_amdgcn_mfma_f32_16x16x32_bf16(af, wf0, acc[0], 0, 0, 0);
            acc[1] = __builtin_amdgcn_mfma_f32_16x16x32_bf16(af, wf1, acc[1], 0, 0, 0);
        }
        if (pf) {
            int nb = b ^ 1;
            *(s16x8*)&As[nb][srow * ASTR + cg8] = ra0;
            *(s16x8*)&As[nb][(16 + srow) * ASTR + cg8] = ra1;
            *(s16x8*)&Ws[nb][srow * ASTR + cg8] = rw0;
            *(s16x8*)&Ws[nb][(16 + srow) * ASTR + cg8] = rw1;
        }
        __syncthreads();
    }

#pragma unroll
    for (int nt = 0; nt < 2; ++nt) {
        int n = n0 + 16 * nt + c;
        float bv = bias[n];
#pragma unroll
        for (int r = 0; r < 4; ++r) {
            int m = m0 + 16 * w + 4 * g + r;
            float v = acc[nt][r] + bv + bf2f(res[(size_t)m * N + n]);
            outb[(size_t)m * N + n] = f2bf(v);
        }
    }
}

// ---------------------------------------------------------------------------
// Wo GEMM with fused 4-split merge (exp2 domain). Tile 32x32, 128 threads.
// ---------------------------------------------------------------------------
__global__ __launch_bounds__(128) void gemm_wo(const ushort_t* __restrict__ Opart,
                                               const float2* __restrict__ ml,
                                               const ushort_t* __restrict__ W,
                                               const float* __restrict__ bias,
                                               const ushort_t* __restrict__ res,
                                               ushort_t* __restrict__ outb) {
    const int K = 256, N = 256;
    __shared__ __align__(16) ushort_t As[2][32 * ASTR];
    __shared__ __align__(16) ushort_t Ws[2][32 * ASTR];

    const int t = threadIdx.x;
    const int w = t >> 6, l = t & 63;
    const int c = l & 15, g = l >> 4;
    const int m0 = blockIdx.y * 32, n0 = blockIdx.x * 32;
    const int srow = t >> 3;
    const int cg8 = (t & 7) * 8;

    auto loadA = [&](int row, int kcol) -> s16x8 {
        int head = kcol >> 5;
        float2 a0 = ml[((size_t)0 * RTOT + row) * 8 + head];
        float2 a1 = ml[((size_t)1 * RTOT + row) * 8 + head];
        float2 a2 = ml[((size_t)2 * RTOT + row) * 8 + head];
        float2 a3 = ml[((size_t)3 * RTOT + row) * 8 + head];
        float M = fmaxf(fmaxf(a0.x, a1.x), fmaxf(a2.x, a3.x));
        float w1 = fexp2(a0.x - M), w2 = fexp2(a1.x - M);
        float w3 = fexp2(a2.x - M), w4 = fexp2(a3.x - M);
        float inv = 1.f / (w1 * a0.y + w2 * a1.y + w3 * a2.y + w4 * a3.y);
        const size_t str = (size_t)RTOT * 256;
        size_t base = (size_t)row * 256 + kcol;
        s16x8 o1 = *(const s16x8*)&Opart[base];
        s16x8 o2 = *(const s16x8*)&Opart[base + str];
        s16x8 o3 = *(const s16x8*)&Opart[base + 2 * str];
        s16x8 o4 = *(const s16x8*)&Opart[base + 3 * str];
        s16x8 r;
#pragma unroll
        for (int e = 0; e < 8; ++e) {
            float v = w1 * bf2f((ushort_t)o1[e]) + w2 * bf2f((ushort_t)o2[e])
                    + w3 * bf2f((ushort_t)o3[e]) + w4 * bf2f((ushort_t)o4[e]);
            r[e] = (short)f2bf(v * inv);
        }
        return r;
    };

    const ushort_t* Wip0 = &W[(size_t)(n0 + srow) * K + cg8];
    const ushort_t* Wip1 = &W[(size_t)(n0 + 16 + srow) * K + cg8];

    s16x8 ra0 = loadA(m0 + srow, cg8);
    s16x8 ra1 = loadA(m0 + 16 + srow, cg8);
    s16x8 rw0 = *(const s16x8*)Wip0;
    s16x8 rw1 = *(const s16x8*)Wip1;
    *(s16x8*)&As[0][srow * ASTR + cg8] = ra0;
    *(s16x8*)&As[0][(16 + srow) * ASTR + cg8] = ra1;
    *(s16x8*)&Ws[0][srow * ASTR + cg8] = rw0;
    *(s16x8*)&Ws[0][(16 + srow) * ASTR + cg8] = rw1;
    __syncthreads();

    f32x4 acc[2] = {{0.f, 0.f, 0.f, 0.f}, {0.f, 0.f, 0.f, 0.f}};
    const int nsteps = 4;

    for (int ks = 0; ks < nsteps; ++ks) {
        const int b = ks & 1;
        const bool pf = (ks + 1 < nsteps);
        if (pf) {
            int ko = (ks + 1) << 6;
            ra0 = loadA(m0 + srow, ko + cg8);
            ra1 = loadA(m0 + 16 + srow, ko + cg8);
            rw0 = *(const s16x8*)(Wip0 + ko);
            rw1 = *(const s16x8*)(Wip1 + ko);
        }
#pragma unroll
        for (int kt = 0; kt < 2; ++kt) {
            s16x8 af = *(const s16x8*)&As[b][(16 * w + c) * ASTR + kt * 32 + 8 * g];
            s16x8 wf0 = *(const s16x8*)&Ws[b][c * ASTR + kt * 32 + 8 * g];
            s16x8 wf1 = *(const s16x8*)&Ws[b][(16 + c) * ASTR + kt * 32 + 8 * g];
            acc[0] = __builtin_amdgcn_mfma_f32_16x16x32_bf16(af, wf0, acc[0], 0, 0, 0);
            acc[1] = __builtin_amdgcn_mfma_f32_16x16x32_bf16(af, wf1, acc[1], 0, 0, 0);
        }
        if (pf) {
            int nb = b ^ 1;
            *(s16x8*)&As[nb][srow * ASTR + cg8] = ra0;
            *(s16x8*)&As[nb][(16 + srow) * ASTR + cg8] = ra1;
            *(s16x8*)&Ws[nb][srow * ASTR + cg8] = rw0;
            *(s16x8*)&Ws[nb][(16 + srow) * ASTR + cg8] = rw1;
        }
        __syncthreads();
    }

#pragma unroll
    for (int nt = 0; nt < 2; ++nt) {
        int n = n0 + 16 * nt + c;
        float bv = bias[n];
#pragma unroll
        for (int r = 0; r < 4; ++r) {
            int m = m0 + 16 * w + 4 * g + r;
            float v = acc[nt][r] + bv + bf2f(res[(size_t)m * 256 + n]);
            outb[(size_t)m * 256 + n] = f2bf(v);
        }
    }
}

// ---------------------------------------------------------------------------
// Split-KV MFMA flash attention (exp2 domain).
// lvl2: blocks 0..1023  = qt(32) x h(8) x split(4), tps=8
// lvl3: blocks 1024..1279 = qt(8) x h(8) x split(4), tps=2
// ---------------------------------------------------------------------------
#define KS 40
#define VS 66
#define PS 72
#define OS 68

__global__ __launch_bounds__(256) void flash_split(const ushort_t* __restrict__ qkvb,
                                                   const u64* __restrict__ ubits,
                                                   ushort_t* __restrict__ Opart,
                                                   float2* __restrict__ ml) {
    __shared__ __align__(16) ushort_t ks[2][64 * KS];
    __shared__ __align__(16) ushort_t vts[2][32 * VS];
    __shared__ __align__(16) char pso[64 * PS * 2];
    ushort_t* ps = (ushort_t*)pso;
    float* os = (float*)pso;

    const int bx = blockIdx.x;
    int qt, h, split, L, rowbase;
    const u64* ub;
    if (bx < 1024) {
        qt = bx & 31; h = (bx >> 5) & 7; split = bx >> 8;
        L = 2048; rowbase = 0; ub = ubits;
    } else {
        int lo = bx - 1024;
        qt = lo & 7; h = (lo >> 3) & 7; split = lo >> 6;
        L = 512; rowbase = 2048; ub = ubits + 65536;
    }
    const int tps = (L >> 6) >> 2;
    const int ts0 = split * tps;
    const int nch = L >> 8;

    const int t = threadIdx.x;
    const int w = t >> 6;
    const int l = t & 63;
    const int c = l & 15;
    const int g = l >> 4;

    const int srow = t >> 2;
    const int sc8 = (t & 3) * 8;
    const int q0g = rowbase + qt * 64;

    const int ql = qt * 64 + 16 * w + c;
    const s16x8 qf = *(const s16x8*)&qkvb[(size_t)(rowbase + ql) * 768 + h * 32 + 8 * g];
    const u64* ubq = &ub[(size_t)ql * nch * 4];

    s16x8 kreg, vreg;
    {
        size_t base = (size_t)(rowbase + ts0 * 64 + srow) * 768 + h * 32 + sc8;
        s16x8 k0r = *(const s16x8*)&qkvb[base + 256];
        s16x8 v0r = *(const s16x8*)&qkvb[base + 512];
        *(s16x8*)&ks[0][srow * KS + sc8] = k0r;
#pragma unroll
        for (int i = 0; i < 8; ++i)
            vts[0][(sc8 + i) * VS + srow] = (ushort_t)v0r[i];
        if (tps > 1) {
            kreg = *(const s16x8*)&qkvb[base + 64 * 768 + 256];
            vreg = *(const s16x8*)&qkvb[base + 64 * 768 + 512];
        }
    }
    __syncthreads();

    f32x4 oacc0 = {0.f, 0.f, 0.f, 0.f};
    f32x4 oacc1 = {0.f, 0.f, 0.f, 0.f};
    float mold = -3e38f;
    float lsum = 0.f;
    const f32x4 zc = {0.f, 0.f, 0.f, 0.f};

    u64 wl0 = 0, wl1 = 0, wl2 = 0, wl3 = 0;
    u64 wh0 = 0, wh1 = 0, wh2 = 0, wh3 = 0;
    int cur = 0;
    for (int kt = 0; kt < tps; ++kt) {
        const int nxt = cur ^ 1;
        const int gt = ts0 + kt;

        if (kt + 1 < tps) {
            *(s16x8*)&ks[nxt][srow * KS + sc8] = kreg;
#pragma unroll
            for (int i = 0; i < 8; ++i)
                vts[nxt][(sc8 + i) * VS + srow] = (ushort_t)vreg[i];
        }
        if (kt + 2 < tps) {
            size_t base = (size_t)(rowbase + (gt + 2) * 64 + srow) * 768 + h * 32 + sc8;
            kreg = *(const s16x8*)&qkvb[base + 256];
            vreg = *(const s16x8*)&qkvb[base + 512];
        }

        if ((gt & 3) == 0 || kt == 0) {
            const u64* bp = &ubq[(size_t)(gt >> 2) * 4];
            wl0 = bp[0]; wl1 = bp[1]; wl2 = bp[2]; wl3 = bp[3];
            wh0 = bp[HIPL]; wh1 = bp[HIPL + 1]; wh2 = bp[HIPL + 2]; wh3 = bp[HIPL + 3];
        }
        const unsigned shb = 16 * (gt & 3);

        f32x4 sacc[4];
        __builtin_amdgcn_s_setprio(1);
#pragma unroll
        for (int nt = 0; nt < 4; ++nt) {
            s16x8 kf = *(const s16x8*)&ks[cur][(16 * nt + c) * KS + 8 * g];
            sacc[nt] = __builtin_amdgcn_mfma_f32_16x16x32_bf16(kf, qf, zc, 0, 0, 0);
        }
        __builtin_amdgcn_s_setprio(0);

        float sv[4][4];
        float pmax = -3e38f;
#pragma unroll
        for (int nt = 0; nt < 4; ++nt) {
            unsigned sh = shb + 4 * nt + g;
#pragma unroll
            for (int r = 0; r < 4; ++r) {
                u64 wl = (r == 0) ? wl0 : (r == 1) ? wl1 : (r == 2) ? wl2 : wl3;
                u64 wh = (r == 0) ? wh0 : (r == 1) ? wh1 : (r == 2) ? wh2 : wh3;
                unsigned lo = (unsigned)(wl >> sh) & 1u;
                unsigned hi = (unsigned)(wh >> sh) & 1u;
                float s = fmaf((float)(lo + 2u * hi), LOG2E, sacc[nt][r]);
                sv[nt][r] = s;
                pmax = fmaxf(pmax, s);
            }
        }
        if (!__all(pmax <= mold + 11.5415f)) {
            float m = pmax;
            m = fmaxf(m, __shfl_xor(m, 16));
            m = fmaxf(m, __shfl_xor(m, 32));
            float newm = fmaxf(mold, m);
            float fac = fexp2(mold - newm);
            mold = newm;
            lsum *= fac;
            oacc0 *= fac;
            oacc1 *= fac;
        }

        float sum = 0.f;
#pragma unroll
        for (int nt = 0; nt < 4; ++nt) {
            float p0 = fexp2(sv[nt][0] - mold);
            float p1 = fexp2(sv[nt][1] - mold);
            float p2 = fexp2(sv[nt][2] - mold);
            float p3 = fexp2(sv[nt][3] - mold);
            sum += (p0 + p1) + (p2 + p3);
            u32x2 pk;
            pk[0] = ((unsigned)f2bf(p1) << 16) | f2bf(p0);
            pk[1] = ((unsigned)f2bf(p3) << 16) | f2bf(p2);
            *(u32x2*)&ps[(16 * w + c) * PS + 16 * nt + 4 * g] = pk;
        }
        lsum += sum;

        __builtin_amdgcn_s_setprio(1);
#pragma unroll
        for (int kc = 0; kc < 2; ++kc) {
            s16x8 pfr = *(const s16x8*)&ps[(16 * w + c) * PS + 32 * kc + 8 * g];
            s16x8 vf0 = *(const s16x8*)&vts[cur][c * VS + 32 * kc + 8 * g];
            s16x8 vf1 = *(const s16x8*)&vts[cur][(16 + c) * VS + 32 * kc + 8 * g];
            oacc0 = __builtin_amdgcn_mfma_f32_16x16x32_bf16(vf0, pfr, oacc0, 0, 0, 0);
            oacc1 = __builtin_amdgcn_mfma_f32_16x16x32_bf16(vf1, pfr, oacc1, 0, 0, 0);
        }
        __builtin_amdgcn_s_setprio(0);

        __syncthreads();
        cur = nxt;
    }

    float lrun = lsum;
    lrun += __shfl_xor(lrun, 16);
    lrun += __shfl_xor(lrun, 32);

    if (g == 0) {
        int q = q0g + 16 * w + c;
        ml[((size_t)split * RTOT + q) * 8 + h] = make_float2(mold, lrun);
    }

#pragma unroll
    for (int r = 0; r < 4; ++r) {
        os[(4 * g + r) * OS + 16 * w + c] = oacc0[r];
        os[(16 + 4 * g + r) * OS + 16 * w + c] = oacc1[r];
    }
    __syncthreads();
    {
        int r = t >> 2, d0 = (t & 3) * 8;
        s16x8 pk;
#pragma unroll
        for (int i = 0; i < 8; ++i) pk[i] = (short)f2bf(os[(d0 + i) * OS + r]);
        *(s16x8*)&Opart[((size_t)split * RTOT + q0g + r) * 256 + h * 32 + d0] = pk;
    }
}

// ---------------------------------------------------------------------------
// LN1: barrier-free, one wave per row (640 blocks x 4 waves). bf16 in/out.
// ---------------------------------------------------------------------------
__global__ __launch_bounds__(256) void ln1_kernel(const ushort_t* __restrict__ in,
                                                  const float* __restrict__ g,
                                                  const float* __restrict__ b,
                                                  ushort_t* __restrict__ outb) {
    int t = threadIdx.x;
    int row = blockIdx.x * 4 + (t >> 6);
    int lane = t & 63;
    size_t base = (size_t)row * 256 + lane * 4;
    s16x4 x = *(const s16x4*)&in[base];
    float v[4];
    float s1 = 0.f, s2 = 0.f;
#pragma unroll
    for (int e = 0; e < 4; ++e) {
        v[e] = bf2f((ushort_t)x[e]);
        s1 += v[e];
        s2 += v[e] * v[e];
    }
#pragma unroll
    for (int d = 1; d < 64; d <<= 1) {
        s1 += __shfl_xor(s1, d);
        s2 += __shfl_xor(s2, d);
    }
    float mean = s1 * (1.f / 256.f);
    float var = s2 * (1.f / 256.f) - mean * mean;
    float rstd = rsqrtf(var + 1e-5f);
    s16x4 r;
#pragma unroll
    for (int e = 0; e < 4; ++e) {
        int n = lane * 4 + e;
        r[e] = (short)f2bf((v[e] - mean) * rstd * g[n] + b[n]);
    }
    *(s16x4*)&outb[base] = r;
}

// ---------------------------------------------------------------------------
// LN2 stats: one wave per row -> stats[row] = (mean, rstd).
// ---------------------------------------------------------------------------
__global__ __launch_bounds__(256) void ln2_stats(const ushort_t* __restrict__ in,
                                                 float2* __restrict__ stats) {
    int t = threadIdx.x;
    int row = blockIdx.x * 4 + (t >> 6);
    int lane = t & 63;
    s16x4 x = *(const s16x4*)&in[(size_t)row * 256 + lane * 4];
    float s1 = 0.f, s2 = 0.f;
#pragma unroll
    for (int e = 0; e < 4; ++e) {
        float v = bf2f((ushort_t)x[e]);
        s1 += v;
        s2 += v * v;
    }
#pragma unroll
    for (int d = 1; d < 64; d <<= 1) {
        s1 += __shfl_xor(s1, d);
        s2 += __shfl_xor(s2, d);
    }
    if (lane == 0) {
        float mean = s1 * (1.f / 256.f);
        float var = s2 * (1.f / 256.f) - mean * mean;
        stats[row] = make_float2(mean, rsqrtf(var + 1e-5f));
    }
}

// ---------------------------------------------------------------------------
// LN2 apply + NCHW scatter, 64x64 LDS-tiled (coalesced both sides, 160 blocks).
// ---------------------------------------------------------------------------
__global__ __launch_bounds__(256) void ln2_scatter(const ushort_t* __restrict__ in,
                                                   const float2* __restrict__ stats,
                                                   const float* __restrict__ g,
                                                   const float* __restrict__ b,
                                                   float* __restrict__ out2,
                                                   float* __restrict__ out3) {
    __shared__ float tl[64][65];
    int bid = blockIdx.x;
    int t = threadIdx.x;
    float* dst; int S, rowb, n, ct, ht;
    if (bid < 128) {
        n = bid >> 6; int rem = bid & 63; ct = rem >> 4; ht = rem & 15;
        dst = out2; S = 1024; rowb = 0;
    } else {
        int b2 = bid - 128;
        n = b2 >> 4; int rem = b2 & 15; ct = rem >> 2; ht = rem & 3;
        dst = out3; S = 256; rowb = 2048;
    }
    int c0 = ct * 64, hw0 = ht * 64;
    int i = t >> 6, lane = t & 63;
    float gv = g[c0 + lane], bv = b[c0 + lane];
#pragma unroll
    for (int jj = 0; jj < 16; ++jj) {
        int hl = i * 16 + jj;
        int row = rowb + n * S + hw0 + hl;
        float2 st = stats[row];
        float v = bf2f(in[(size_t)row * 256 + c0 + lane]);
        tl[hl][lane] = (v - st.x) * st.y * gv + bv;
    }
    __syncthreads();
#pragma unroll
    for (int jj = 0; jj < 16; ++jj) {
        int cl = i * 16 + jj;
        dst[(size_t)(n * 256 + c0 + cl) * S + hw0 + lane] = tl[lane][cl];
    }
}

// ---------------------------------------------------------------------------

extern "C" void kernel_launch(void* const* d_in, const int* in_sizes, int n_in,
                              void* d_out, int out_size, void* d_ws, size_t ws_size,
                              hipStream_t stream) {
    const float* f0 = (const float*)d_in[0];
    const float* f1 = (const float*)d_in[1];
    const float* f2 = (const float*)d_in[2];
    const float* f3 = (const float*)d_in[3];
    const float* u2 = (const float*)d_in[4];
    const float* u3 = (const float*)d_in[5];
    const float* Wqkv = (const float*)d_in[6];
    const float* bqkv = (const float*)d_in[7];
    const float* Wo   = (const float*)d_in[8];
    const float* bo   = (const float*)d_in[9];
    const float* g1   = (const float*)d_in[10];
    const float* b1   = (const float*)d_in[11];
    const float* Wfc1 = (const float*)d_in[12];
    const float* bfc1 = (const float*)d_in[13];
    const float* Wfc2 = (const float*)d_in[14];
    const float* bfc2 = (const float*)d_in[15];
    const float* g2   = (const float*)d_in[16];
    const float* b2   = (const float*)d_in[17];

    float* out = (float*)d_out;
    float* ws = (float*)d_ws;

    // bf16 weights
    ushort_t* wqkv = (ushort_t*)ws;             // 196608 us
    ushort_t* wo   = (ushort_t*)(ws + 98304);   // 65536 us
    ushort_t* wfc1 = (ushort_t*)(ws + 131072);  // 262144 us
    ushort_t* wfc2 = (ushort_t*)(ws + 262144);  // 262144 us

    // scratch (floats), all intermediates bf16
    float* sc = ws + 393216;
    ushort_t* src_bf = (ushort_t*)sc;                // 655360 us -> f 327680
    ushort_t* qkvb   = (ushort_t*)(sc + 327680);     // 2560*768 us -> f 1310720
    ushort_t* t1b    = (ushort_t*)(sc + 1310720);    // -> f 1638400
    ushort_t* x_bf   = (ushort_t*)(sc + 1638400);    // -> f 1966080
    ushort_t* t2b    = (ushort_t*)(sc + 1966080);    // -> f 2293760
    u64*      ubits  = (u64*)(sc + 2293760);         // 2*69632 u64 -> f 2572288
    float2*   ml     = (float2*)(sc + 2572288);      // 4*2560*8 f2 -> f 2736128
    float2*   st2    = (float2*)(sc + 2736128);      // 2560 f2 -> f 2741248
    ushort_t* Opart  = (ushort_t*)(sc + 2741248);    // 4*2560*256 us -> f 4051968
    ushort_t* h_bf   = Opart;                        // alias post-wo

    prep<<<9280, 256, 0, stream>>>(f0, f1, out,
                                   Wqkv, Wo, Wfc1, Wfc2, wqkv, wo, wfc1, wfc2,
                                   u2, u3, ubits, f2, f3, src_bf);

    gemm64<3><<<dim3(12, 40), 256, 0, stream>>>(
        src_bf, wqkv, bqkv, qkvb, RTOT, 768, 256);
    flash_split<<<1280, 256, 0, stream>>>(qkvb, ubits, Opart, ml);
    gemm_wo<<<dim3(8, 80), 128, 0, stream>>>(Opart, ml, wo, bo, src_bf, t1b);
    ln1_kernel<<<640, 256, 0, stream>>>(t1b, g1, b1, x_bf);
    gemm64<1><<<dim3(16, 40), 256, 0, stream>>>(
        x_bf, wfc1, bfc1, h_bf, RTOT, 1024, 256);
    gemm_fc2<<<dim3(8, 80), 128, 0, stream>>>(
        h_bf, wfc2, bfc2, x_bf, t2b, RTOT, 256, 1024);
    ln2_stats<<<640, 256, 0, stream>>>(t2b, st2);
    ln2_scatter<<<160, 256, 0, stream>>>(t2b, st2, g2, b2,
                                         out + 4096000, out + 4620288);
}

// Round 22
// 78.583 us; speedup vs baseline: 1.1687x; 1.0447x over previous
//
#include <hip/hip_runtime.h>
#include <hip/hip_bf16.h>
#include <cstddef>
#include <cmath>

// ---------------------------------------------------------------------------
// sparse_attn: transformer encoder block on levels 2 & 3.
// Round 22: R21 + f0/f1 pass-through copy moved INTO flash_split's grid
// (blocks 1280..5279) — copy bandwidth overlaps latency-bound attention.
// Rows 0..2047 = level2 (S=1024), 2048..2559 = level3 (S=256). R=2560.
// ---------------------------------------------------------------------------

typedef __attribute__((ext_vector_type(8))) short s16x8;
typedef __attribute__((ext_vector_type(4))) short s16x4;
typedef __attribute__((ext_vector_type(4))) float f32x4;
typedef __attribute__((ext_vector_type(2))) unsigned int u32x2;
typedef unsigned short ushort_t;
typedef unsigned long long u64;

#define RTOT 2560
#define HIPL 69632   // u64 offset of the hi bitplane
#define LOG2E 1.4426950408889634f

__device__ inline unsigned short f2bf(float x) {
    union { __hip_bfloat16 h; unsigned short u; } cv;
    cv.h = __float2bfloat16(x);
    return cv.u;
}
__device__ inline float bf2f(unsigned short u) {
    union { unsigned int i; float f; } cv;
    cv.i = ((unsigned int)u) << 16;
    return cv.f;
}
__device__ inline float fexp2(float x) { return exp2f(x); }

// ---------------------------------------------------------------------------
// prep (5280 blocks):
//   0..159     : f2/f3 NCHW -> [2560,256] bf16 (64x64 LDS tile, first)
//   160..927   : weights fp32->bf16
//   928..5279  : mask VALUE planes (0..3): lo bits ub[..], hi bits ub[HIPL+..]
// ---------------------------------------------------------------------------
__global__ __launch_bounds__(256) void prep(const float* __restrict__ wqkv,
                                            const float* __restrict__ wo,
                                            const float* __restrict__ wfc1,
                                            const float* __restrict__ wfc2,
                                            ushort_t* __restrict__ o1,
                                            ushort_t* __restrict__ o2,
                                            ushort_t* __restrict__ o3,
                                            ushort_t* __restrict__ o4,
                                            const float* __restrict__ u2,
                                            const float* __restrict__ u3,
                                            u64* __restrict__ ub,
                                            const float* __restrict__ f2,
                                            const float* __restrict__ f3,
                                            ushort_t* __restrict__ srcb) {
    __shared__ float tl[64][65];
    int bid = blockIdx.x;
    int t = threadIdx.x;
    if (bid < 160) {
        int b = bid;
        const float* src; int S, rowb, n, ct, ht;
        if (b < 128) {
            n = b >> 6; int rem = b & 63; ct = rem >> 4; ht = rem & 15;
            src = f2; S = 1024; rowb = 0;
        } else {
            int b2 = b - 128;
            n = b2 >> 4; int rem = b2 & 15; ct = rem >> 2; ht = rem & 3;
            src = f3; S = 256; rowb = 2048;
        }
        int c0 = ct * 64, hw0 = ht * 64;
        int i = t >> 6, lane = t & 63;
#pragma unroll
        for (int jj = 0; jj < 16; ++jj) {
            int cl = i * 16 + jj;
            tl[lane][cl] = src[(size_t)(n * 256 + c0 + cl) * S + hw0 + lane];
        }
        __syncthreads();
#pragma unroll
        for (int jj = 0; jj < 16; ++jj) {
            int hl = i * 16 + jj;
            int row = rowb + n * S + hw0 + hl;
            srcb[(size_t)row * 256 + c0 + lane] = f2bf(tl[hl][lane]);
        }
    } else if (bid < 928) {
        int i = (bid - 160) * 256 + t;
        const float* src; ushort_t* dst; int li;
        if (i < 49152)       { src = wqkv; dst = o1; li = i; }
        else if (i < 65536)  { src = wo;   dst = o2; li = i - 49152; }
        else if (i < 131072) { src = wfc1; dst = o3; li = i - 65536; }
        else                 { src = wfc2; dst = o4; li = i - 131072; }
        f32x4 v = ((const f32x4*)src)[li];
        s16x4 r;
        r[0] = (short)f2bf(v[0]); r[1] = (short)f2bf(v[1]);
        r[2] = (short)f2bf(v[2]); r[3] = (short)f2bf(v[3]);
        ((s16x4*)dst)[li] = r;
    } else {
        int gw = ((bid - 928) * 256 + t) >> 6;   // chunk 0..17407
        int lane = t & 63;
        const float* p;
        u64* dstLo;
        int q, kb, smask, sshift;
        if (gw < 16384) {
            int row = gw >> 3, ch = gw & 7;
            p = &u2[(size_t)row * 2048 + ch * 256 + lane * 4];
            dstLo = &ub[(size_t)gw * 4];
            q = row; kb = ch * 256 + lane * 4; smask = 1023; sshift = 10;
        } else {
            int lw = gw - 16384;
            int row = lw >> 1, ch = lw & 1;
            p = &u3[(size_t)row * 512 + ch * 256 + lane * 4];
            dstLo = &ub[65536 + (size_t)lw * 4];
            q = row; kb = ch * 256 + lane * 4; smask = 255; sshift = 8;
        }
        u64* dstHi = dstLo + HIPL;
        f32x4 v = *(const f32x4*)p;
        int qp = q & smask, qf = q >> sshift;
        u64 bl[4], bh[4];
#pragma unroll
        for (int j = 0; j < 4; ++j) {
            int k = kb + j;
            int val = (v[j] >= 0.1f ? 1 : 0)
                    + ((k & smask) == qp ? 1 : 0)
                    + ((k >> sshift) == qf ? 1 : 0);
            bl[j] = __ballot((val & 1) != 0);
            bh[j] = __ballot((val & 2) != 0);
        }
        if (lane < 4) {
            u64 x = (lane == 0) ? bl[0] : (lane == 1) ? bl[1]
                  : (lane == 2) ? bl[2] : bl[3];
            dstLo[lane] = x;
        } else if (lane < 8) {
            int j = lane - 4;
            u64 x = (j == 0) ? bh[0] : (j == 1) ? bh[1]
                  : (j == 2) ? bh[2] : bh[3];
            dstHi[j] = x;
        }
    }
}

#define ASTR 72

// ---------------------------------------------------------------------------
// bf16 MFMA GEMM, tile 64x64, 256 threads (4 waves). For qkv / fc1.
// EPI: 1=bias+relu, 3=bias then q-scale-log2e (n<256). Output bf16.
// ---------------------------------------------------------------------------
template <int EPI>
__global__ __launch_bounds__(256) void gemm64(const ushort_t* __restrict__ A,
                                              const ushort_t* __restrict__ W,
                                              const float* __restrict__ bias,
                                              ushort_t* __restrict__ outb,
                                              int M, int N, int K) {
    __shared__ __align__(16) ushort_t As[2][64 * ASTR];
    __shared__ __align__(16) ushort_t Ws[2][64 * ASTR];

    const int t = threadIdx.x;
    const int w = t >> 6, l = t & 63;
    const int c = l & 15, g = l >> 4;
    const int mh = w >> 1, nh = w & 1;
    const int m0 = blockIdx.y * 64, n0 = blockIdx.x * 64;
    const int srow = t >> 3;
    const int cg8 = (t & 7) * 8;

    const ushort_t* Aip0 = &A[(size_t)(m0 + srow) * K + cg8];
    const ushort_t* Aip1 = &A[(size_t)(m0 + 32 + srow) * K + cg8];
    const ushort_t* Wip0 = &W[(size_t)(n0 + srow) * K + cg8];
    const ushort_t* Wip1 = &W[(size_t)(n0 + 32 + srow) * K + cg8];

    s16x8 ra0 = *(const s16x8*)Aip0;
    s16x8 ra1 = *(const s16x8*)Aip1;
    s16x8 rw0 = *(const s16x8*)Wip0;
    s16x8 rw1 = *(const s16x8*)Wip1;
    *(s16x8*)&As[0][srow * ASTR + cg8] = ra0;
    *(s16x8*)&As[0][(32 + srow) * ASTR + cg8] = ra1;
    *(s16x8*)&Ws[0][srow * ASTR + cg8] = rw0;
    *(s16x8*)&Ws[0][(32 + srow) * ASTR + cg8] = rw1;
    __syncthreads();

    f32x4 acc[2][2] = {{{0.f,0.f,0.f,0.f},{0.f,0.f,0.f,0.f}},
                       {{0.f,0.f,0.f,0.f},{0.f,0.f,0.f,0.f}}};
    const int nsteps = K >> 6;

    for (int ks = 0; ks < nsteps; ++ks) {
        const int b = ks & 1;
        const bool pf = (ks + 1 < nsteps);
        if (pf) {
            int ko = (ks + 1) << 6;
            ra0 = *(const s16x8*)(Aip0 + ko);
            ra1 = *(const s16x8*)(Aip1 + ko);
            rw0 = *(const s16x8*)(Wip0 + ko);
            rw1 = *(const s16x8*)(Wip1 + ko);
        }
#pragma unroll
        for (int sl = 0; sl < 2; ++sl) {
            s16x8 af0 = *(const s16x8*)&As[b][(32 * mh + c) * ASTR + sl * 32 + 8 * g];
            s16x8 af1 = *(const s16x8*)&As[b][(32 * mh + 16 + c) * ASTR + sl * 32 + 8 * g];
            s16x8 wf0 = *(const s16x8*)&Ws[b][(32 * nh + c) * ASTR + sl * 32 + 8 * g];
            s16x8 wf1 = *(const s16x8*)&Ws[b][(32 * nh + 16 + c) * ASTR + sl * 32 + 8 * g];
            acc[0][0] = __builtin_amdgcn_mfma_f32_16x16x32_bf16(af0, wf0, acc[0][0], 0, 0, 0);
            acc[0][1] = __builtin_amdgcn_mfma_f32_16x16x32_bf16(af0, wf1, acc[0][1], 0, 0, 0);
            acc[1][0] = __builtin_amdgcn_mfma_f32_16x16x32_bf16(af1, wf0, acc[1][0], 0, 0, 0);
            acc[1][1] = __builtin_amdgcn_mfma_f32_16x16x32_bf16(af1, wf1, acc[1][1], 0, 0, 0);
        }
        if (pf) {
            int nb = b ^ 1;
            *(s16x8*)&As[nb][srow * ASTR + cg8] = ra0;
            *(s16x8*)&As[nb][(32 + srow) * ASTR + cg8] = ra1;
            *(s16x8*)&Ws[nb][srow * ASTR + cg8] = rw0;
            *(s16x8*)&Ws[nb][(32 + srow) * ASTR + cg8] = rw1;
        }
        __syncthreads();
    }

#pragma unroll
    for (int i = 0; i < 2; ++i)
#pragma unroll
    for (int j = 0; j < 2; ++j) {
        int n = n0 + 32 * nh + 16 * j + c;
        float bv = bias[n];
        float sc = 1.f;
        if (EPI == 3) sc = (n < 256) ? 0.17677669529663687f * LOG2E : 1.f;
#pragma unroll
        for (int r = 0; r < 4; ++r) {
            int m = m0 + 32 * mh + 16 * i + 4 * g + r;
            float v = acc[i][j][r] + bv;
            if (EPI == 1) v = fmaxf(v, 0.f);
            if (EPI == 3) v *= sc;
            outb[(size_t)m * N + n] = f2bf(v);
        }
    }
}

// ---------------------------------------------------------------------------
// bf16 MFMA GEMM, tile 32x32, 128 threads. fc2: K=1024, bf16 res, bf16 out.
// ---------------------------------------------------------------------------
__global__ __launch_bounds__(128) void gemm_fc2(const ushort_t* __restrict__ A,
                                                const ushort_t* __restrict__ W,
                                                const float* __restrict__ bias,
                                                const ushort_t* __restrict__ res,
                                                ushort_t* __restrict__ outb,
                                                int M, int N, int K) {
    __shared__ __align__(16) ushort_t As[2][32 * ASTR];
    __shared__ __align__(16) ushort_t Ws[2][32 * ASTR];

    const int t = threadIdx.x;
    const int w = t >> 6, l = t & 63;
    const int c = l & 15, g = l >> 4;
    const int m0 = blockIdx.y * 32, n0 = blockIdx.x * 32;
    const int srow = t >> 3;
    const int cg8 = (t & 7) * 8;

    const ushort_t* Aip0 = &A[(size_t)(m0 + srow) * K + cg8];
    const ushort_t* Aip1 = &A[(size_t)(m0 + 16 + srow) * K + cg8];
    const ushort_t* Wip0 = &W[(size_t)(n0 + srow) * K + cg8];
    const ushort_t* Wip1 = &W[(size_t)(n0 + 16 + srow) * K + cg8];

    s16x8 ra0 = *(const s16x8*)Aip0;
    s16x8 ra1 = *(const s16x8*)Aip1;
    s16x8 rw0 = *(const s16x8*)Wip0;
    s16x8 rw1 = *(const s16x8*)Wip1;
    *(s16x8*)&As[0][srow * ASTR + cg8] = ra0;
    *(s16x8*)&As[0][(16 + srow) * ASTR + cg8] = ra1;
    *(s16x8*)&Ws[0][srow * ASTR + cg8] = rw0;
    *(s16x8*)&Ws[0][(16 + srow) * ASTR + cg8] = rw1;
    __syncthreads();

    f32x4 acc[2] = {{0.f, 0.f, 0.f, 0.f}, {0.f, 0.f, 0.f, 0.f}};
    const int nsteps = K >> 6;

    for (int ks = 0; ks < nsteps; ++ks) {
        const int b = ks & 1;
        const bool pf = (ks + 1 < nsteps);
        if (pf) {
            int ko = (ks + 1) << 6;
            ra0 = *(const s16x8*)(Aip0 + ko);
            ra1 = *(const s16x8*)(Aip1 + ko);
            rw0 = *(const s16x8*)(Wip0 + ko);
            rw1 = *(const s16x8*)(Wip1 + ko);
        }
#pragma unroll
        for (int kt = 0; kt < 2; ++kt) {
            s16x8 af = *(const s16x8*)&As[b][(16 * w + c) * ASTR + kt * 32 + 8 * g];
            s16x8 wf0 = *(const s16x8*)&Ws[b][c * ASTR + kt * 32 + 8 * g];
            s16x8 wf1 = *(const s16x8*)&Ws[b][(16 + c) * ASTR + kt * 32 + 8 * g];
            acc[0] = __builtin_amdgcn_mfma_f32_16x16x32_bf16(af, wf0, acc[0], 0, 0, 0);
            acc[1] = __builtin_amdgcn_mfma_f32_16x16x32_bf16(af, wf1, acc[1], 0, 0, 0);
        }
        if (pf) {
            int nb = b ^ 1;
            *(s16x8*)&As[nb][srow * ASTR + cg8] = ra0;
            *(s16x8*)&As[nb][(16 + srow) * ASTR + cg8] = ra1;
            *(s16x8*)&Ws[nb][srow * ASTR + cg8] = rw0;
            *(s16x8*)&Ws[nb][(16 + srow) * ASTR + cg8] = rw1;
        }
        __syncthreads();
    }

#pragma unroll
    for (int nt = 0; nt < 2; ++nt) {
        int n = n0 + 16 * nt + c;
        float bv = bias[n];
#pragma unroll
        for (int r = 0; r < 4; ++r) {
            int m = m0 + 16 * w + 4 * g + r;
            float v = acc[nt][r] + bv + bf2f(res[(size_t)m * N + n]);
            outb[(size_t)m * N + n] = f2bf(v);
        }
    }
}

// ---------------------------------------------------------------------------
// Wo GEMM with fused 4-split merge (exp2 domain). Tile 32x32, 128 threads.
// ---------------------------------------------------------------------------
__global__ __launch_bounds__(128) void gemm_wo(const ushort_t* __restrict__ Opart,
                                               const float2* __restrict__ ml,
                                               const ushort_t* __restrict__ W,
                                               const float* __restrict__ bias,
                                               const ushort_t* __restrict__ res,
                                               ushort_t* __restrict__ outb) {
    const int K = 256, N = 256;
    __shared__ __align__(16) ushort_t As[2][32 * ASTR];
    __shared__ __align__(16) ushort_t Ws[2][32 * ASTR];

    const int t = threadIdx.x;
    const int w = t >> 6, l = t & 63;
    const int c = l & 15, g = l >> 4;
    const int m0 = blockIdx.y * 32, n0 = blockIdx.x * 32;
    const int srow = t >> 3;
    const int cg8 = (t & 7) * 8;

    auto loadA = [&](int row, int kcol) -> s16x8 {
        int head = kcol >> 5;
        float2 a0 = ml[((size_t)0 * RTOT + row) * 8 + head];
        float2 a1 = ml[((size_t)1 * RTOT + row) * 8 + head];
        float2 a2 = ml[((size_t)2 * RTOT + row) * 8 + head];
        float2 a3 = ml[((size_t)3 * RTOT + row) * 8 + head];
        float M = fmaxf(fmaxf(a0.x, a1.x), fmaxf(a2.x, a3.x));
        float w1 = fexp2(a0.x - M), w2 = fexp2(a1.x - M);
        float w3 = fexp2(a2.x - M), w4 = fexp2(a3.x - M);
        float inv = 1.f / (w1 * a0.y + w2 * a1.y + w3 * a2.y + w4 * a3.y);
        const size_t str = (size_t)RTOT * 256;
        size_t base = (size_t)row * 256 + kcol;
        s16x8 o1 = *(const s16x8*)&Opart[base];
        s16x8 o2 = *(const s16x8*)&Opart[base + str];
        s16x8 o3 = *(const s16x8*)&Opart[base + 2 * str];
        s16x8 o4 = *(const s16x8*)&Opart[base + 3 * str];
        s16x8 r;
#pragma unroll
        for (int e = 0; e < 8; ++e) {
            float v = w1 * bf2f((ushort_t)o1[e]) + w2 * bf2f((ushort_t)o2[e])
                    + w3 * bf2f((ushort_t)o3[e]) + w4 * bf2f((ushort_t)o4[e]);
            r[e] = (short)f2bf(v * inv);
        }
        return r;
    };

    const ushort_t* Wip0 = &W[(size_t)(n0 + srow) * K + cg8];
    const ushort_t* Wip1 = &W[(size_t)(n0 + 16 + srow) * K + cg8];

    s16x8 ra0 = loadA(m0 + srow, cg8);
    s16x8 ra1 = loadA(m0 + 16 + srow, cg8);
    s16x8 rw0 = *(const s16x8*)Wip0;
    s16x8 rw1 = *(const s16x8*)Wip1;
    *(s16x8*)&As[0][srow * ASTR + cg8] = ra0;
    *(s16x8*)&As[0][(16 + srow) * ASTR + cg8] = ra1;
    *(s16x8*)&Ws[0][srow * ASTR + cg8] = rw0;
    *(s16x8*)&Ws[0][(16 + srow) * ASTR + cg8] = rw1;
    __syncthreads();

    f32x4 acc[2] = {{0.f, 0.f, 0.f, 0.f}, {0.f, 0.f, 0.f, 0.f}};
    const int nsteps = 4;

    for (int ks = 0; ks < nsteps; ++ks) {
        const int b = ks & 1;
        const bool pf = (ks + 1 < nsteps);
        if (pf) {
            int ko = (ks + 1) << 6;
            ra0 = loadA(m0 + srow, ko + cg8);
            ra1 = loadA(m0 + 16 + srow, ko + cg8);
            rw0 = *(const s16x8*)(Wip0 + ko);
            rw1 = *(const s16x8*)(Wip1 + ko);
        }
#pragma unroll
        for (int kt = 0; kt < 2; ++kt) {
            s16x8 af = *(const s16x8*)&As[b][(16 * w + c) * ASTR + kt * 32 + 8 * g];
            s16x8 wf0 = *(const s16x8*)&Ws[b][c * ASTR + kt * 32 + 8 * g];
            s16x8 wf1 = *(const s16x8*)&Ws[b][(16 + c) * ASTR + kt * 32 + 8 * g];
            acc[0] = __builtin_amdgcn_mfma_f32_16x16x32_bf16(af, wf0, acc[0], 0, 0, 0);
            acc[1] = __builtin_amdgcn_mfma_f32_16x16x32_bf16(af, wf1, acc[1], 0, 0, 0);
        }
        if (pf) {
            int nb = b ^ 1;
            *(s16x8*)&As[nb][srow * ASTR + cg8] = ra0;
            *(s16x8*)&As[nb][(16 + srow) * ASTR + cg8] = ra1;
            *(s16x8*)&Ws[nb][srow * ASTR + cg8] = rw0;
            *(s16x8*)&Ws[nb][(16 + srow) * ASTR + cg8] = rw1;
        }
        __syncthreads();
    }

#pragma unroll
    for (int nt = 0; nt < 2; ++nt) {
        int n = n0 + 16 * nt + c;
        float bv = bias[n];
#pragma unroll
        for (int r = 0; r < 4; ++r) {
            int m = m0 + 16 * w + 4 * g + r;
            float v = acc[nt][r] + bv + bf2f(res[(size_t)m * 256 + n]);
            outb[(size_t)m * 256 + n] = f2bf(v);
        }
    }
}

// ---------------------------------------------------------------------------
// Split-KV MFMA flash attention (exp2 domain) + overlapped f0/f1 copy.
// lvl2: blocks 0..1023  = qt(32) x h(8) x split(4), tps=8
// lvl3: blocks 1024..1279 = qt(8) x h(8) x split(4), tps=2
// copy: blocks 1280..5279 = f0/f1 pass-through (f32x4), rides free bandwidth.
// ---------------------------------------------------------------------------
#define KS 40
#define VS 66
#define PS 72
#define OS 68

__global__ __launch_bounds__(256) void flash_split(const ushort_t* __restrict__ qkvb,
                                                   const u64* __restrict__ ubits,
                                                   ushort_t* __restrict__ Opart,
                                                   float2* __restrict__ ml,
                                                   const float* __restrict__ f0,
                                                   const float* __restrict__ f1,
                                                   float* __restrict__ outp) {
    __shared__ __align__(16) ushort_t ks[2][64 * KS];
    __shared__ __align__(16) ushort_t vts[2][32 * VS];
    __shared__ __align__(16) char pso[64 * PS * 2];
    ushort_t* ps = (ushort_t*)pso;
    float* os = (float*)pso;

    const int bx = blockIdx.x;
    const int t = threadIdx.x;

    if (bx >= 1280) {
        // overlapped f0/f1 pass-through copy
        int idx = (bx - 1280) * 256 + t;     // f32x4 over 1024000
        f32x4 v = (idx < 819200) ? ((const f32x4*)f0)[idx]
                                 : ((const f32x4*)f1)[idx - 819200];
        ((f32x4*)outp)[idx] = v;
        return;
    }

    int qt, h, split, L, rowbase;
    const u64* ub;
    if (bx < 1024) {
        qt = bx & 31; h = (bx >> 5) & 7; split = bx >> 8;
        L = 2048; rowbase = 0; ub = ubits;
    } else {
        int lo = bx - 1024;
        qt = lo & 7; h = (lo >> 3) & 7; split = lo >> 6;
        L = 512; rowbase = 2048; ub = ubits + 65536;
    }
    const int tps = (L >> 6) >> 2;
    const int ts0 = split * tps;
    const int nch = L >> 8;

    const int w = t >> 6;
    const int l = t & 63;
    const int c = l & 15;
    const int g = l >> 4;

    const int srow = t >> 2;
    const int sc8 = (t & 3) * 8;
    const int q0g = rowbase + qt * 64;

    const int ql = qt * 64 + 16 * w + c;
    const s16x8 qf = *(const s16x8*)&qkvb[(size_t)(rowbase + ql) * 768 + h * 32 + 8 * g];
    const u64* ubq = &ub[(size_t)ql * nch * 4];

    s16x8 kreg, vreg;
    {
        size_t base = (size_t)(rowbase + ts0 * 64 + srow) * 768 + h * 32 + sc8;
        s16x8 k0r = *(const s16x8*)&qkvb[base + 256];
        s16x8 v0r = *(const s16x8*)&qkvb[base + 512];
        *(s16x8*)&ks[0][srow * KS + sc8] = k0r;
#pragma unroll
        for (int i = 0; i < 8; ++i)
            vts[0][(sc8 + i) * VS + srow] = (ushort_t)v0r[i];
        if (tps > 1) {
            kreg = *(const s16x8*)&qkvb[base + 64 * 768 + 256];
            vreg = *(const s16x8*)&qkvb[base + 64 * 768 + 512];
        }
    }
    __syncthreads();

    f32x4 oacc0 = {0.f, 0.f, 0.f, 0.f};
    f32x4 oacc1 = {0.f, 0.f, 0.f, 0.f};
    float mold = -3e38f;
    float lsum = 0.f;
    const f32x4 zc = {0.f, 0.f, 0.f, 0.f};

    u64 wl0 = 0, wl1 = 0, wl2 = 0, wl3 = 0;
    u64 wh0 = 0, wh1 = 0, wh2 = 0, wh3 = 0;
    int cur = 0;
    for (int kt = 0; kt < tps; ++kt) {
        const int nxt = cur ^ 1;
        const int gt = ts0 + kt;

        if (kt + 1 < tps) {
            *(s16x8*)&ks[nxt][srow * KS + sc8] = kreg;
#pragma unroll
            for (int i = 0; i < 8; ++i)
                vts[nxt][(sc8 + i) * VS + srow] = (ushort_t)vreg[i];
        }
        if (kt + 2 < tps) {
            size_t base = (size_t)(rowbase + (gt + 2) * 64 + srow) * 768 + h * 32 + sc8;
            kreg = *(const s16x8*)&qkvb[base + 256];
            vreg = *(const s16x8*)&qkvb[base + 512];
        }

        if ((gt & 3) == 0 || kt == 0) {
            const u64* bp = &ubq[(size_t)(gt >> 2) * 4];
            wl0 = bp[0]; wl1 = bp[1]; wl2 = bp[2]; wl3 = bp[3];
            wh0 = bp[HIPL]; wh1 = bp[HIPL + 1]; wh2 = bp[HIPL + 2]; wh3 = bp[HIPL + 3];
        }
        const unsigned shb = 16 * (gt & 3);

        f32x4 sacc[4];
        __builtin_amdgcn_s_setprio(1);
#pragma unroll
        for (int nt = 0; nt < 4; ++nt) {
            s16x8 kf = *(const s16x8*)&ks[cur][(16 * nt + c) * KS + 8 * g];
            sacc[nt] = __builtin_amdgcn_mfma_f32_16x16x32_bf16(kf, qf, zc, 0, 0, 0);
        }
        __builtin_amdgcn_s_setprio(0);

        float sv[4][4];
        float pmax = -3e38f;
#pragma unroll
        for (int nt = 0; nt < 4; ++nt) {
            unsigned sh = shb + 4 * nt + g;
#pragma unroll
            for (int r = 0; r < 4; ++r) {
                u64 wl = (r == 0) ? wl0 : (r == 1) ? wl1 : (r == 2) ? wl2 : wl3;
                u64 wh = (r == 0) ? wh0 : (r == 1) ? wh1 : (r == 2) ? wh2 : wh3;
                unsigned lo = (unsigned)(wl >> sh) & 1u;
                unsigned hi = (unsigned)(wh >> sh) & 1u;
                float s = fmaf((float)(lo + 2u * hi), LOG2E, sacc[nt][r]);
                sv[nt][r] = s;
                pmax = fmaxf(pmax, s);
            }
        }
        if (!__all(pmax <= mold + 11.5415f)) {
            float m = pmax;
            m = fmaxf(m, __shfl_xor(m, 16));
            m = fmaxf(m, __shfl_xor(m, 32));
            float newm = fmaxf(mold, m);
            float fac = fexp2(mold - newm);
            mold = newm;
            lsum *= fac;
            oacc0 *= fac;
            oacc1 *= fac;
        }

        float sum = 0.f;
#pragma unroll
        for (int nt = 0; nt < 4; ++nt) {
            float p0 = fexp2(sv[nt][0] - mold);
            float p1 = fexp2(sv[nt][1] - mold);
            float p2 = fexp2(sv[nt][2] - mold);
            float p3 = fexp2(sv[nt][3] - mold);
            sum += (p0 + p1) + (p2 + p3);
            u32x2 pk;
            pk[0] = ((unsigned)f2bf(p1) << 16) | f2bf(p0);
            pk[1] = ((unsigned)f2bf(p3) << 16) | f2bf(p2);
            *(u32x2*)&ps[(16 * w + c) * PS + 16 * nt + 4 * g] = pk;
        }
        lsum += sum;

        __builtin_amdgcn_s_setprio(1);
#pragma unroll
        for (int kc = 0; kc < 2; ++kc) {
            s16x8 pfr = *(const s16x8*)&ps[(16 * w + c) * PS + 32 * kc + 8 * g];
            s16x8 vf0 = *(const s16x8*)&vts[cur][c * VS + 32 * kc + 8 * g];
            s16x8 vf1 = *(const s16x8*)&vts[cur][(16 + c) * VS + 32 * kc + 8 * g];
            oacc0 = __builtin_amdgcn_mfma_f32_16x16x32_bf16(vf0, pfr, oacc0, 0, 0, 0);
            oacc1 = __builtin_amdgcn_mfma_f32_16x16x32_bf16(vf1, pfr, oacc1, 0, 0, 0);
        }
        __builtin_amdgcn_s_setprio(0);

        __syncthreads();
        cur = nxt;
    }

    float lrun = lsum;
    lrun += __shfl_xor(lrun, 16);
    lrun += __shfl_xor(lrun, 32);

    if (g == 0) {
        int q = q0g + 16 * w + c;
        ml[((size_t)split * RTOT + q) * 8 + h] = make_float2(mold, lrun);
    }

#pragma unroll
    for (int r = 0; r < 4; ++r) {
        os[(4 * g + r) * OS + 16 * w + c] = oacc0[r];
        os[(16 + 4 * g + r) * OS + 16 * w + c] = oacc1[r];
    }
    __syncthreads();
    {
        int r = t >> 2, d0 = (t & 3) * 8;
        s16x8 pk;
#pragma unroll
        for (int i = 0; i < 8; ++i) pk[i] = (short)f2bf(os[(d0 + i) * OS + r]);
        *(s16x8*)&Opart[((size_t)split * RTOT + q0g + r) * 256 + h * 32 + d0] = pk;
    }
}

// ---------------------------------------------------------------------------
// LN1: barrier-free, one wave per row (640 blocks x 4 waves). bf16 in/out.
// ---------------------------------------------------------------------------
__global__ __launch_bounds__(256) void ln1_kernel(const ushort_t* __restrict__ in,
                                                  const float* __restrict__ g,
                                                  const float* __restrict__ b,
                                                  ushort_t* __restrict__ outb) {
    int t = threadIdx.x;
    int row = blockIdx.x * 4 + (t >> 6);
    int lane = t & 63;
    size_t base = (size_t)row * 256 + lane * 4;
    s16x4 x = *(const s16x4*)&in[base];
    float v[4];
    float s1 = 0.f, s2 = 0.f;
#pragma unroll
    for (int e = 0; e < 4; ++e) {
        v[e] = bf2f((ushort_t)x[e]);
        s1 += v[e];
        s2 += v[e] * v[e];
    }
#pragma unroll
    for (int d = 1; d < 64; d <<= 1) {
        s1 += __shfl_xor(s1, d);
        s2 += __shfl_xor(s2, d);
    }
    float mean = s1 * (1.f / 256.f);
    float var = s2 * (1.f / 256.f) - mean * mean;
    float rstd = rsqrtf(var + 1e-5f);
    s16x4 r;
#pragma unroll
    for (int e = 0; e < 4; ++e) {
        int n = lane * 4 + e;
        r[e] = (short)f2bf((v[e] - mean) * rstd * g[n] + b[n]);
    }
    *(s16x4*)&outb[base] = r;
}

// ---------------------------------------------------------------------------
// LN2 stats: one wave per row -> stats[row] = (mean, rstd).
// ---------------------------------------------------------------------------
__global__ __launch_bounds__(256) void ln2_stats(const ushort_t* __restrict__ in,
                                                 float2* __restrict__ stats) {
    int t = threadIdx.x;
    int row = blockIdx.x * 4 + (t >> 6);
    int lane = t & 63;
    s16x4 x = *(const s16x4*)&in[(size_t)row * 256 + lane * 4];
    float s1 = 0.f, s2 = 0.f;
#pragma unroll
    for (int e = 0; e < 4; ++e) {
        float v = bf2f((ushort_t)x[e]);
        s1 += v;
        s2 += v * v;
    }
#pragma unroll
    for (int d = 1; d < 64; d <<= 1) {
        s1 += __shfl_xor(s1, d);
        s2 += __shfl_xor(s2, d);
    }
    if (lane == 0) {
        float mean = s1 * (1.f / 256.f);
        float var = s2 * (1.f / 256.f) - mean * mean;
        stats[row] = make_float2(mean, rsqrtf(var + 1e-5f));
    }
}

// ---------------------------------------------------------------------------
// LN2 apply + NCHW scatter, 64x64 LDS-tiled (coalesced both sides, 160 blocks).
// ---------------------------------------------------------------------------
__global__ __launch_bounds__(256) void ln2_scatter(const ushort_t* __restrict__ in,
                                                   const float2* __restrict__ stats,
                                                   const float* __restrict__ g,
                                                   const float* __restrict__ b,
                                                   float* __restrict__ out2,
                                                   float* __restrict__ out3) {
    __shared__ float tl[64][65];
    int bid = blockIdx.x;
    int t = threadIdx.x;
    float* dst; int S, rowb, n, ct, ht;
    if (bid < 128) {
        n = bid >> 6; int rem = bid & 63; ct = rem >> 4; ht = rem & 15;
        dst = out2; S = 1024; rowb = 0;
    } else {
        int b2 = bid - 128;
        n = b2 >> 4; int rem = b2 & 15; ct = rem >> 2; ht = rem & 3;
        dst = out3; S = 256; rowb = 2048;
    }
    int c0 = ct * 64, hw0 = ht * 64;
    int i = t >> 6, lane = t & 63;
    float gv = g[c0 + lane], bv = b[c0 + lane];
#pragma unroll
    for (int jj = 0; jj < 16; ++jj) {
        int hl = i * 16 + jj;
        int row = rowb + n * S + hw0 + hl;
        float2 st = stats[row];
        float v = bf2f(in[(size_t)row * 256 + c0 + lane]);
        tl[hl][lane] = (v - st.x) * st.y * gv + bv;
    }
    __syncthreads();
#pragma unroll
    for (int jj = 0; jj < 16; ++jj) {
        int cl = i * 16 + jj;
        dst[(size_t)(n * 256 + c0 + cl) * S + hw0 + lane] = tl[lane][cl];
    }
}

// ---------------------------------------------------------------------------

extern "C" void kernel_launch(void* const* d_in, const int* in_sizes, int n_in,
                              void* d_out, int out_size, void* d_ws, size_t ws_size,
                              hipStream_t stream) {
    const float* f0 = (const float*)d_in[0];
    const float* f1 = (const float*)d_in[1];
    const float* f2 = (const float*)d_in[2];
    const float* f3 = (const float*)d_in[3];
    const float* u2 = (const float*)d_in[4];
    const float* u3 = (const float*)d_in[5];
    const float* Wqkv = (const float*)d_in[6];
    const float* bqkv = (const float*)d_in[7];
    const float* Wo   = (const float*)d_in[8];
    const float* bo   = (const float*)d_in[9];
    const float* g1   = (const float*)d_in[10];
    const float* b1   = (const float*)d_in[11];
    const float* Wfc1 = (const float*)d_in[12];
    const float* bfc1 = (const float*)d_in[13];
    const float* Wfc2 = (const float*)d_in[14];
    const float* bfc2 = (const float*)d_in[15];
    const float* g2   = (const float*)d_in[16];
    const float* b2   = (const float*)d_in[17];

    float* out = (float*)d_out;
    float* ws = (float*)d_ws;

    // bf16 weights
    ushort_t* wqkv = (ushort_t*)ws;             // 196608 us
    ushort_t* wo   = (ushort_t*)(ws + 98304);   // 65536 us
    ushort_t* wfc1 = (ushort_t*)(ws + 131072);  // 262144 us
    ushort_t* wfc2 = (ushort_t*)(ws + 262144);  // 262144 us

    // scratch (floats), all intermediates bf16
    float* sc = ws + 393216;
    ushort_t* src_bf = (ushort_t*)sc;                // 655360 us -> f 327680
    ushort_t* qkvb   = (ushort_t*)(sc + 327680);     // 2560*768 us -> f 1310720
    ushort_t* t1b    = (ushort_t*)(sc + 1310720);    // -> f 1638400
    ushort_t* x_bf   = (ushort_t*)(sc + 1638400);    // -> f 1966080
    ushort_t* t2b    = (ushort_t*)(sc + 1966080);    // -> f 2293760
    u64*      ubits  = (u64*)(sc + 2293760);         // 2*69632 u64 -> f 2572288
    float2*   ml     = (float2*)(sc + 2572288);      // 4*2560*8 f2 -> f 2736128
    float2*   st2    = (float2*)(sc + 2736128);      // 2560 f2 -> f 2741248
    ushort_t* Opart  = (ushort_t*)(sc + 2741248);    // 4*2560*256 us -> f 4051968
    ushort_t* h_bf   = Opart;                        // alias post-wo

    prep<<<5280, 256, 0, stream>>>(Wqkv, Wo, Wfc1, Wfc2, wqkv, wo, wfc1, wfc2,
                                   u2, u3, ubits, f2, f3, src_bf);

    gemm64<3><<<dim3(12, 40), 256, 0, stream>>>(
        src_bf, wqkv, bqkv, qkvb, RTOT, 768, 256);
    flash_split<<<5280, 256, 0, stream>>>(qkvb, ubits, Opart, ml, f0, f1, out);
    gemm_wo<<<dim3(8, 80), 128, 0, stream>>>(Opart, ml, wo, bo, src_bf, t1b);
    ln1_kernel<<<640, 256, 0, stream>>>(t1b, g1, b1, x_bf);
    gemm64<1><<<dim3(16, 40), 256, 0, stream>>>(
        x_bf, wfc1, bfc1, h_bf, RTOT, 1024, 256);
    gemm_fc2<<<dim3(8, 80), 128, 0, stream>>>(
        h_bf, wfc2, bfc2, x_bf, t2b, RTOT, 256, 1024);
    ln2_stats<<<640, 256, 0, stream>>>(t2b, st2);
    ln2_scatter<<<160, 256, 0, stream>>>(t2b, st2, g2, b2,
                                         out + 4096000, out + 4620288);
}